// Round 1
// baseline (2175.417 us; speedup 1.0000x reference)
//
#include <hip/hip_runtime.h>
#include <hip/hip_bf16.h>
#include <math.h>

#define SEQ 1024
#define CDIM 1024
#define NHEAD 16
#define HDIM 64
#define HIDDEN 4096
#define BATCH 4
#define MROWS (BATCH*SEQ)   // 4096

// ---------------- LayerNorm: one block per row (1024 cols) ----------------
__global__ void ln_kernel(const float* __restrict__ x, const float* __restrict__ w,
                          const float* __restrict__ b, float* __restrict__ out) {
    const int row = blockIdx.x;
    const int t = threadIdx.x;               // 256 threads
    const float4* xr = (const float4*)(x + (size_t)row * CDIM);
    float4 v = xr[t];
    float s  = v.x + v.y + v.z + v.w;
    float sq = v.x*v.x + v.y*v.y + v.z*v.z + v.w*v.w;
    #pragma unroll
    for (int off = 32; off; off >>= 1) {
        s  += __shfl_down(s, off);
        sq += __shfl_down(sq, off);
    }
    __shared__ float ss[4], ssq[4];
    const int wid = t >> 6, lane = t & 63;
    if (lane == 0) { ss[wid] = s; ssq[wid] = sq; }
    __syncthreads();
    s  = ss[0] + ss[1] + ss[2] + ss[3];
    sq = ssq[0] + ssq[1] + ssq[2] + ssq[3];
    const float mu  = s * (1.0f / CDIM);
    const float var = sq * (1.0f / CDIM) - mu * mu;
    const float rs  = rsqrtf(var + 1e-5f);
    float4 wv = ((const float4*)w)[t];
    float4 bv = ((const float4*)b)[t];
    float4 o;
    o.x = (v.x - mu) * rs * wv.x + bv.x;
    o.y = (v.y - mu) * rs * wv.y + bv.y;
    o.z = (v.z - mu) * rs * wv.z + bv.z;
    o.w = (v.w - mu) * rs * wv.w + bv.w;
    ((float4*)(out + (size_t)row * CDIM))[t] = o;
}

// ------------- GEMM: C[M,N] = A[M,K] * B[N,K]^T (+bias)(+gelu)(+res) -------------
// 64x64 tile, BK=16, 256 threads, 4x4 per thread.
__device__ __forceinline__ float gelu_exact(float v) {
    return 0.5f * v * (1.0f + erff(v * 0.70710678118654752440f));
}

template<bool BIAS, bool RES, bool GELU_>
__global__ void gemm_bt(const float* __restrict__ A, const float* __restrict__ Bm,
                        const float* __restrict__ bias, const float* __restrict__ res,
                        float* __restrict__ C, int M, int N, int K) {
    __shared__ float As[16][68];
    __shared__ float Bs[16][68];
    const int t = threadIdx.x;
    const int tx = t & 15, ty = t >> 4;
    const int m0 = blockIdx.y * 64, n0 = blockIdx.x * 64;
    const int lrow = t >> 2;           // 0..63
    const int lc4  = (t & 3) * 4;      // 0,4,8,12
    const float* aptr = A + (size_t)(m0 + lrow) * K + lc4;
    const float* bptr = Bm + (size_t)(n0 + lrow) * K + lc4;
    float acc[4][4] = {};
    for (int k0 = 0; k0 < K; k0 += 16) {
        float4 av = *(const float4*)(aptr + k0);
        float4 bv = *(const float4*)(bptr + k0);
        __syncthreads();
        As[lc4+0][lrow] = av.x; As[lc4+1][lrow] = av.y;
        As[lc4+2][lrow] = av.z; As[lc4+3][lrow] = av.w;
        Bs[lc4+0][lrow] = bv.x; Bs[lc4+1][lrow] = bv.y;
        Bs[lc4+2][lrow] = bv.z; Bs[lc4+3][lrow] = bv.w;
        __syncthreads();
        #pragma unroll
        for (int kk = 0; kk < 16; ++kk) {
            float4 a4 = *(const float4*)&As[kk][ty * 4];
            float4 b4 = *(const float4*)&Bs[kk][tx * 4];
            float a[4] = {a4.x, a4.y, a4.z, a4.w};
            float b[4] = {b4.x, b4.y, b4.z, b4.w};
            #pragma unroll
            for (int i = 0; i < 4; ++i)
                #pragma unroll
                for (int j = 0; j < 4; ++j)
                    acc[i][j] += a[i] * b[j];
        }
    }
    const int col = n0 + tx * 4;
    #pragma unroll
    for (int i = 0; i < 4; ++i) {
        const int row = m0 + ty * 4 + i;
        float4 v = make_float4(acc[i][0], acc[i][1], acc[i][2], acc[i][3]);
        if (BIAS) {
            const float4 bb = *(const float4*)&bias[col];
            v.x += bb.x; v.y += bb.y; v.z += bb.z; v.w += bb.w;
        }
        if (GELU_) {
            v.x = gelu_exact(v.x); v.y = gelu_exact(v.y);
            v.z = gelu_exact(v.z); v.w = gelu_exact(v.w);
        }
        if (RES) {
            const float4 rr = *(const float4*)&res[(size_t)row * N + col];
            v.x += rr.x; v.y += rr.y; v.z += rr.z; v.w += rr.w;
        }
        *(float4*)&C[(size_t)row * N + col] = v;
    }
}

// ---------------- Attention: one block per (b,h, 8 query rows) ----------------
// qkv layout: [B, N, 3, H, D] ; out: [B, N, H*D]
__global__ void attn_kernel(const float* __restrict__ qkv, float* __restrict__ o) {
    const int bh = blockIdx.y;           // 0..63
    const int b = bh >> 4, h = bh & 15;
    const int qbase = blockIdx.x * 8;
    const int t = threadIdx.x;           // 256
    __shared__ float qs[8][64];
    __shared__ float sc[8][1024];
    __shared__ float red[8];
    __shared__ float po[8][4][64];
    const float* base = qkv + (size_t)b * SEQ * 3072 + h * 64;
    // load q (pre-scaled by 1/sqrt(D))
    for (int idx = t; idx < 512; idx += 256) {
        const int r = idx >> 6, d = idx & 63;
        qs[r][d] = base[(size_t)(qbase + r) * 3072 + d] * 0.125f;
    }
    __syncthreads();
    // scores: each thread handles 4 key rows
    const float* kbase = base + 1024;
    #pragma unroll
    for (int mi = 0; mi < 4; ++mi) {
        const int m = t + mi * 256;
        const float4* krow = (const float4*)(kbase + (size_t)m * 3072);
        float dot[8] = {0,0,0,0,0,0,0,0};
        #pragma unroll 4
        for (int i = 0; i < 16; ++i) {
            const float4 kv = krow[i];
            #pragma unroll
            for (int r = 0; r < 8; ++r) {
                const float4 qv = ((const float4*)qs[r])[i];
                dot[r] += qv.x*kv.x + qv.y*kv.y + qv.z*kv.z + qv.w*kv.w;
            }
        }
        #pragma unroll
        for (int r = 0; r < 8; ++r) sc[r][m] = dot[r];
    }
    __syncthreads();
    // softmax: 32 threads per row
    {
        const int r = t >> 5, j = t & 31;
        float mx = -1e30f;
        for (int m = j; m < 1024; m += 32) mx = fmaxf(mx, sc[r][m]);
        #pragma unroll
        for (int off = 16; off; off >>= 1) mx = fmaxf(mx, __shfl_xor(mx, off, 32));
        float sum = 0.0f;
        for (int m = j; m < 1024; m += 32) {
            const float p = __expf(sc[r][m] - mx);
            sc[r][m] = p;
            sum += p;
        }
        #pragma unroll
        for (int off = 16; off; off >>= 1) sum += __shfl_xor(sum, off, 32);
        if (j == 0) red[r] = 1.0f / sum;
    }
    __syncthreads();
    // PV: c-th quarter of keys, d-th output dim
    {
        const int c = t >> 6, d = t & 63;
        const float* vbase = base + 2048;
        float acc[8] = {0,0,0,0,0,0,0,0};
        for (int mm = 0; mm < 256; ++mm) {
            const int m = c * 256 + mm;
            const float vv = vbase[(size_t)m * 3072 + d];
            #pragma unroll
            for (int r = 0; r < 8; ++r) acc[r] += sc[r][m] * vv;
        }
        #pragma unroll
        for (int r = 0; r < 8; ++r) po[r][c][d] = acc[r];
    }
    __syncthreads();
    {
        const int c = t >> 6, d = t & 63;
        for (int rr = c; rr < 8; rr += 4) {
            const float val = (po[rr][0][d] + po[rr][1][d] + po[rr][2][d] + po[rr][3][d]) * red[rr];
            o[((size_t)(b * SEQ + qbase + rr)) * CDIM + h * 64 + d] = val;
        }
    }
}

extern "C" void kernel_launch(void* const* d_in, const int* in_sizes, int n_in,
                              void* d_out, int out_size, void* d_ws, size_t ws_size,
                              hipStream_t stream) {
    const float* x      = (const float*)d_in[0];
    const float* ln1_w  = (const float*)d_in[1];
    const float* ln1_b  = (const float*)d_in[2];
    const float* qkv_w  = (const float*)d_in[3];
    const float* proj_w = (const float*)d_in[4];
    const float* proj_b = (const float*)d_in[5];
    const float* ln2_w  = (const float*)d_in[6];
    const float* ln2_b  = (const float*)d_in[7];
    const float* fc1_w  = (const float*)d_in[8];
    const float* fc1_b  = (const float*)d_in[9];
    const float* fc2_w  = (const float*)d_in[10];
    const float* fc2_b  = (const float*)d_in[11];
    float* out = (float*)d_out;

    float* ws   = (float*)d_ws;
    float* qkv  = ws;                                  // 4096*3072 floats (48 MB)
    float* obuf = ws + (size_t)MROWS * 3 * CDIM;       // 4096*1024 floats (16 MB)
    float* mlp1 = ws;                                  // 4096*4096 floats (64 MB, reuses qkv+obuf)
    float* hbuf = ws + (size_t)MROWS * HIDDEN;         // 4096*1024 floats (16 MB)

    // 1. LN1
    ln_kernel<<<MROWS, 256, 0, stream>>>(x, ln1_w, ln1_b, hbuf);
    // 2. QKV = h @ qkv_w^T
    gemm_bt<false,false,false><<<dim3(3*CDIM/64, MROWS/64), 256, 0, stream>>>(
        hbuf, qkv_w, nullptr, nullptr, qkv, MROWS, 3*CDIM, CDIM);
    // 3. attention -> obuf [B,N,C]
    attn_kernel<<<dim3(SEQ/8, BATCH*NHEAD), 256, 0, stream>>>(qkv, obuf);
    // 4. x2 = x + obuf @ proj_w^T + proj_b   (into d_out)
    gemm_bt<true,true,false><<<dim3(CDIM/64, MROWS/64), 256, 0, stream>>>(
        obuf, proj_w, proj_b, x, out, MROWS, CDIM, CDIM);
    // 5. LN2
    ln_kernel<<<MROWS, 256, 0, stream>>>(out, ln2_w, ln2_b, hbuf);
    // 6. mlp1 = gelu(h @ fc1_w^T + fc1_b)
    gemm_bt<true,false,true><<<dim3(HIDDEN/64, MROWS/64), 256, 0, stream>>>(
        hbuf, fc1_w, fc1_b, nullptr, mlp1, MROWS, HIDDEN, CDIM);
    // 7. out = out + mlp1 @ fc2_w^T + fc2_b  (in-place residual)
    gemm_bt<true,true,false><<<dim3(CDIM/64, MROWS/64), 256, 0, stream>>>(
        mlp1, fc2_w, fc2_b, out, out, MROWS, CDIM, HIDDEN);
}

// Round 3
// 989.150 us; speedup vs baseline: 2.1993x; 2.1993x over previous
//
#include <hip/hip_runtime.h>
#include <hip/hip_bf16.h>
#include <math.h>
#include <stdint.h>

#define SEQ 1024
#define CDIM 1024
#define NHEAD 16
#define HIDDEN 4096
#define BATCH 4
#define MROWS (BATCH*SEQ)   // 4096

using bf16x8 = __attribute__((ext_vector_type(8))) short;
using f32x4  = __attribute__((ext_vector_type(4))) float;

__device__ __forceinline__ short f2bf(float f) {
    union { float f; uint32_t u; } c; c.f = f;
    const uint32_t u = c.u + 0x7FFFu + ((c.u >> 16) & 1u);
    return (short)(u >> 16);
}

__device__ __forceinline__ float gelu_exact(float v) {
    return 0.5f * v * (1.0f + erff(v * 0.70710678118654752440f));
}

// async global->LDS, 16B per lane; LDS dest is wave-uniform base + lane*16
__device__ __forceinline__ void gload_lds16(const short* g, short* lds) {
    __builtin_amdgcn_global_load_lds(
        (const __attribute__((address_space(1))) void*)(uintptr_t)g,
        (__attribute__((address_space(3))) void*)(uintptr_t)lds,
        16, 0, 0);
}

// ---------------- weight fp32 -> bf16 conversion ----------------
__global__ void cvt_bf16_kernel(const float* __restrict__ in, short* __restrict__ out) {
    const size_t i = ((size_t)blockIdx.x * 256 + threadIdx.x) * 8;
    const float4 a = *(const float4*)(in + i);
    const float4 b = *(const float4*)(in + i + 4);
    bf16x8 s;
    s[0] = f2bf(a.x); s[1] = f2bf(a.y); s[2] = f2bf(a.z); s[3] = f2bf(a.w);
    s[4] = f2bf(b.x); s[5] = f2bf(b.y); s[6] = f2bf(b.z); s[7] = f2bf(b.w);
    *(bf16x8*)(out + i) = s;
}

// ---------------- LayerNorm: one block per row, bf16 output ----------------
__global__ void ln_kernel(const float* __restrict__ x, const float* __restrict__ w,
                          const float* __restrict__ b, short* __restrict__ out) {
    const int row = blockIdx.x;
    const int t = threadIdx.x;               // 256 threads
    const float4* xr = (const float4*)(x + (size_t)row * CDIM);
    float4 v = xr[t];
    float s  = v.x + v.y + v.z + v.w;
    float sq = v.x*v.x + v.y*v.y + v.z*v.z + v.w*v.w;
    #pragma unroll
    for (int off = 32; off; off >>= 1) {
        s  += __shfl_down(s, off);
        sq += __shfl_down(sq, off);
    }
    __shared__ float ss[4], ssq[4];
    const int wid = t >> 6, lane = t & 63;
    if (lane == 0) { ss[wid] = s; ssq[wid] = sq; }
    __syncthreads();
    s  = ss[0] + ss[1] + ss[2] + ss[3];
    sq = ssq[0] + ssq[1] + ssq[2] + ssq[3];
    const float mu  = s * (1.0f / CDIM);
    const float var = sq * (1.0f / CDIM) - mu * mu;
    const float rs  = rsqrtf(var + 1e-5f);
    const float4 wv = ((const float4*)w)[t];
    const float4 bv = ((const float4*)b)[t];
    short4 o;
    o.x = f2bf((v.x - mu) * rs * wv.x + bv.x);
    o.y = f2bf((v.y - mu) * rs * wv.y + bv.y);
    o.z = f2bf((v.z - mu) * rs * wv.z + bv.z);
    o.w = f2bf((v.w - mu) * rs * wv.w + bv.w);
    *(short4*)(out + (size_t)row * CDIM + t * 4) = o;
}

// ------------- bf16 MFMA GEMM: C[M,N] = A[M,K] * B[N,K]^T (+bias)(+gelu)(+res) -----
// m97 structure: 128x128 tile, BK=32, 256 threads = 4 waves (2x2), each wave 64x64,
// 16x16x32 MFMA, global_load_lds width-16 staging, 2-barrier K-loop.
template<bool BIAS, bool RES, bool GELU_, bool OUTBF16>
__global__ __launch_bounds__(256) void mgemm(
    const short* __restrict__ A, const short* __restrict__ B,
    const float* __restrict__ bias, const float* __restrict__ res,
    void* __restrict__ Cv, int M, int N, int K)
{
    __shared__ __align__(16) short As[128 * 32];
    __shared__ __align__(16) short Bs[128 * 32];
    const int t = threadIdx.x;
    const int w = t >> 6, l = t & 63;
    const int wr = w >> 1, wc = w & 1;
    const int m0 = blockIdx.y * 128, n0 = blockIdx.x * 128;

    // staging: wave w owns rows [w*32, w*32+32) of the 128x32 tile
    const short* agp0 = A + (size_t)(m0 + w * 32 + (l >> 2)) * K + (l & 3) * 8;
    const short* agp1 = agp0 + (size_t)16 * K;
    const short* bgp0 = B + (size_t)(n0 + w * 32 + (l >> 2)) * K + (l & 3) * 8;
    const short* bgp1 = bgp0 + (size_t)16 * K;
    short* ldsA = &As[w * 1024];
    short* ldsB = &Bs[w * 1024];

    int aoff[4], boff[4];
    #pragma unroll
    for (int m = 0; m < 4; ++m) aoff[m] = (wr * 64 + m * 16 + (l & 15)) * 32 + (l >> 4) * 8;
    #pragma unroll
    for (int n = 0; n < 4; ++n) boff[n] = (wc * 64 + n * 16 + (l & 15)) * 32 + (l >> 4) * 8;

    f32x4 acc[4][4] = {};

    for (int k0 = 0; k0 < K; k0 += 32) {
        __syncthreads();
        gload_lds16(agp0 + k0, ldsA);
        gload_lds16(agp1 + k0, ldsA + 512);
        gload_lds16(bgp0 + k0, ldsB);
        gload_lds16(bgp1 + k0, ldsB + 512);
        __syncthreads();
        bf16x8 af[4], bfr[4];
        #pragma unroll
        for (int m = 0; m < 4; ++m) af[m]  = *(const bf16x8*)&As[aoff[m]];
        #pragma unroll
        for (int n = 0; n < 4; ++n) bfr[n] = *(const bf16x8*)&Bs[boff[n]];
        #pragma unroll
        for (int m = 0; m < 4; ++m)
            #pragma unroll
            for (int n = 0; n < 4; ++n)
                acc[m][n] = __builtin_amdgcn_mfma_f32_16x16x32_bf16(af[m], bfr[n], acc[m][n], 0, 0, 0);
    }

    // epilogue: C/D frag mapping col=lane&15, row=(lane>>4)*4+reg  [HW-verified]
    const int lr4 = (l >> 4) * 4, lc = l & 15;
    #pragma unroll
    for (int m = 0; m < 4; ++m) {
        #pragma unroll
        for (int n = 0; n < 4; ++n) {
            const int col = n0 + wc * 64 + n * 16 + lc;
            const float bv = BIAS ? bias[col] : 0.0f;
            #pragma unroll
            for (int r = 0; r < 4; ++r) {
                const int row = m0 + wr * 64 + m * 16 + lr4 + r;
                float v = acc[m][n][r] + bv;
                if (GELU_) v = gelu_exact(v);
                if (RES)   v += res[(size_t)row * N + col];
                if (OUTBF16) ((short*)Cv)[(size_t)row * N + col] = f2bf(v);
                else         ((float*)Cv)[(size_t)row * N + col] = v;
            }
        }
    }
}

// ---------------- Attention: fp32 compute, bf16 output ----------------
// qkv layout: [B, N, 3, H, D] f32 ; out: [B, N, H*D] bf16
__global__ void attn_kernel(const float* __restrict__ qkv, short* __restrict__ o) {
    const int bh = blockIdx.y;
    const int b = bh >> 4, h = bh & 15;
    const int qbase = blockIdx.x * 8;
    const int t = threadIdx.x;
    __shared__ float qs[8][64];
    __shared__ float sc[8][1024];
    __shared__ float red[8];
    __shared__ float po[8][4][64];
    const float* base = qkv + (size_t)b * SEQ * 3072 + h * 64;
    for (int idx = t; idx < 512; idx += 256) {
        const int r = idx >> 6, d = idx & 63;
        qs[r][d] = base[(size_t)(qbase + r) * 3072 + d] * 0.125f;
    }
    __syncthreads();
    const float* kbase = base + 1024;
    #pragma unroll
    for (int mi = 0; mi < 4; ++mi) {
        const int m = t + mi * 256;
        const float4* krow = (const float4*)(kbase + (size_t)m * 3072);
        float dot[8] = {0,0,0,0,0,0,0,0};
        #pragma unroll 4
        for (int i = 0; i < 16; ++i) {
            const float4 kv = krow[i];
            #pragma unroll
            for (int r = 0; r < 8; ++r) {
                const float4 qv = ((const float4*)qs[r])[i];
                dot[r] += qv.x*kv.x + qv.y*kv.y + qv.z*kv.z + qv.w*kv.w;
            }
        }
        #pragma unroll
        for (int r = 0; r < 8; ++r) sc[r][m] = dot[r];
    }
    __syncthreads();
    {
        const int r = t >> 5, j = t & 31;
        float mx = -1e30f;
        for (int m = j; m < 1024; m += 32) mx = fmaxf(mx, sc[r][m]);
        #pragma unroll
        for (int off = 16; off; off >>= 1) mx = fmaxf(mx, __shfl_xor(mx, off, 32));
        float sum = 0.0f;
        for (int m = j; m < 1024; m += 32) {
            const float p = __expf(sc[r][m] - mx);
            sc[r][m] = p;
            sum += p;
        }
        #pragma unroll
        for (int off = 16; off; off >>= 1) sum += __shfl_xor(sum, off, 32);
        if (j == 0) red[r] = 1.0f / sum;
    }
    __syncthreads();
    {
        const int c = t >> 6, d = t & 63;
        const float* vbase = base + 2048;
        float acc[8] = {0,0,0,0,0,0,0,0};
        for (int mm = 0; mm < 256; ++mm) {
            const int m = c * 256 + mm;
            const float vv = vbase[(size_t)m * 3072 + d];
            #pragma unroll
            for (int r = 0; r < 8; ++r) acc[r] += sc[r][m] * vv;
        }
        #pragma unroll
        for (int r = 0; r < 8; ++r) po[r][c][d] = acc[r];
    }
    __syncthreads();
    {
        const int c = t >> 6, d = t & 63;
        for (int rr = c; rr < 8; rr += 4) {
            const float val = (po[rr][0][d] + po[rr][1][d] + po[rr][2][d] + po[rr][3][d]) * red[rr];
            o[((size_t)(b * SEQ + qbase + rr)) * CDIM + h * 64 + d] = f2bf(val);
        }
    }
}

extern "C" void kernel_launch(void* const* d_in, const int* in_sizes, int n_in,
                              void* d_out, int out_size, void* d_ws, size_t ws_size,
                              hipStream_t stream) {
    const float* x      = (const float*)d_in[0];
    const float* ln1_w  = (const float*)d_in[1];
    const float* ln1_b  = (const float*)d_in[2];
    const float* qkv_w  = (const float*)d_in[3];
    const float* proj_w = (const float*)d_in[4];
    const float* proj_b = (const float*)d_in[5];
    const float* ln2_w  = (const float*)d_in[6];
    const float* ln2_b  = (const float*)d_in[7];
    const float* fc1_w  = (const float*)d_in[8];
    const float* fc1_b  = (const float*)d_in[9];
    const float* fc2_w  = (const float*)d_in[10];
    const float* fc2_b  = (const float*)d_in[11];
    float* out = (float*)d_out;

    // workspace (80 MB): [0,24M) bf16 weights | [24M,72M) qkv f32 then mlp1 bf16
    // | [72M,80M) shared bf16: hbuf(LN1) -> obuf(attn) -> hbuf(LN2)
    short* ws16  = (short*)d_ws;
    short* wqkv  = ws16;
    short* wproj = ws16 + 3145728;
    short* wfc1  = ws16 + 4194304;
    short* wfc2  = ws16 + 8388608;
    char*  wsb   = (char*)d_ws;
    float* qkv   = (float*)(wsb + (size_t)24 * 1024 * 1024);
    short* mlp1  = (short*)(wsb + (size_t)24 * 1024 * 1024);
    short* hbuf  = (short*)(wsb + (size_t)72 * 1024 * 1024);

    cvt_bf16_kernel<<<1536, 256, 0, stream>>>(qkv_w, wqkv);
    cvt_bf16_kernel<<< 512, 256, 0, stream>>>(proj_w, wproj);
    cvt_bf16_kernel<<<2048, 256, 0, stream>>>(fc1_w, wfc1);
    cvt_bf16_kernel<<<2048, 256, 0, stream>>>(fc2_w, wfc2);

    ln_kernel<<<MROWS, 256, 0, stream>>>(x, ln1_w, ln1_b, hbuf);
    mgemm<false,false,false,false><<<dim3(24, 32), 256, 0, stream>>>(
        hbuf, wqkv, nullptr, nullptr, qkv, MROWS, 3072, 1024);
    attn_kernel<<<dim3(SEQ/8, BATCH*NHEAD), 256, 0, stream>>>(qkv, hbuf);
    mgemm<true,true,false,false><<<dim3(8, 32), 256, 0, stream>>>(
        hbuf, wproj, proj_b, x, out, MROWS, 1024, 1024);
    ln_kernel<<<MROWS, 256, 0, stream>>>(out, ln2_w, ln2_b, hbuf);
    mgemm<true,false,true,true><<<dim3(32, 32), 256, 0, stream>>>(
        hbuf, wfc1, fc1_b, nullptr, mlp1, MROWS, 4096, 1024);
    mgemm<true,true,false,false><<<dim3(8, 32), 256, 0, stream>>>(
        mlp1, wfc2, fc2_b, out, out, MROWS, 1024, 4096);
}

// Round 4
// 312.733 us; speedup vs baseline: 6.9561x; 3.1629x over previous
//
#include <hip/hip_runtime.h>
#include <hip/hip_bf16.h>
#include <math.h>
#include <stdint.h>

#define SEQ 1024
#define CDIM 1024
#define NHEAD 16
#define HIDDEN 4096
#define BATCH 4
#define MROWS (BATCH*SEQ)   // 4096

using bf16x8 = __attribute__((ext_vector_type(8))) short;
using f32x4  = __attribute__((ext_vector_type(4))) float;

__device__ __forceinline__ short f2bf(float f) {
    union { float f; uint32_t u; } c; c.f = f;
    const uint32_t u = c.u + 0x7FFFu + ((c.u >> 16) & 1u);
    return (short)(u >> 16);
}

__device__ __forceinline__ float gelu_exact(float v) {
    return 0.5f * v * (1.0f + erff(v * 0.70710678118654752440f));
}

// async global->LDS, 16B per lane; LDS dest is wave-uniform base + lane*16
__device__ __forceinline__ void gload_lds16(const short* g, short* lds) {
    __builtin_amdgcn_global_load_lds(
        (const __attribute__((address_space(1))) void*)(uintptr_t)g,
        (__attribute__((address_space(3))) void*)(uintptr_t)lds,
        16, 0, 0);
}

// ---------------- weight fp32 -> bf16 conversion ----------------
__global__ void cvt_bf16_kernel(const float* __restrict__ in, short* __restrict__ out) {
    const size_t i = ((size_t)blockIdx.x * 256 + threadIdx.x) * 8;
    const float4 a = *(const float4*)(in + i);
    const float4 b = *(const float4*)(in + i + 4);
    bf16x8 s;
    s[0] = f2bf(a.x); s[1] = f2bf(a.y); s[2] = f2bf(a.z); s[3] = f2bf(a.w);
    s[4] = f2bf(b.x); s[5] = f2bf(b.y); s[6] = f2bf(b.z); s[7] = f2bf(b.w);
    *(bf16x8*)(out + i) = s;
}

// ---------------- LayerNorm: one block per row, bf16 output ----------------
__global__ void ln_kernel(const float* __restrict__ x, const float* __restrict__ w,
                          const float* __restrict__ b, short* __restrict__ out) {
    const int row = blockIdx.x;
    const int t = threadIdx.x;               // 256 threads
    const float4* xr = (const float4*)(x + (size_t)row * CDIM);
    float4 v = xr[t];
    float s  = v.x + v.y + v.z + v.w;
    float sq = v.x*v.x + v.y*v.y + v.z*v.z + v.w*v.w;
    #pragma unroll
    for (int off = 32; off; off >>= 1) {
        s  += __shfl_down(s, off);
        sq += __shfl_down(sq, off);
    }
    __shared__ float ss[4], ssq[4];
    const int wid = t >> 6, lane = t & 63;
    if (lane == 0) { ss[wid] = s; ssq[wid] = sq; }
    __syncthreads();
    s  = ss[0] + ss[1] + ss[2] + ss[3];
    sq = ssq[0] + ssq[1] + ssq[2] + ssq[3];
    const float mu  = s * (1.0f / CDIM);
    const float var = sq * (1.0f / CDIM) - mu * mu;
    const float rs  = rsqrtf(var + 1e-5f);
    const float4 wv = ((const float4*)w)[t];
    const float4 bv = ((const float4*)b)[t];
    short4 o;
    o.x = f2bf((v.x - mu) * rs * wv.x + bv.x);
    o.y = f2bf((v.y - mu) * rs * wv.y + bv.y);
    o.z = f2bf((v.z - mu) * rs * wv.z + bv.z);
    o.w = f2bf((v.w - mu) * rs * wv.w + bv.w);
    *(short4*)(out + (size_t)row * CDIM + t * 4) = o;
}

// ------------- bf16 MFMA GEMM: C[M,N] = A[M,K] * B[N,K]^T (+bias)(+gelu)(+res) -----
template<bool BIAS, bool RES, bool GELU_, bool OUTBF16>
__global__ __launch_bounds__(256) void mgemm(
    const short* __restrict__ A, const short* __restrict__ B,
    const float* __restrict__ bias, const float* __restrict__ res,
    void* __restrict__ Cv, int M, int N, int K)
{
    __shared__ __align__(16) short As[128 * 32];
    __shared__ __align__(16) short Bs[128 * 32];
    const int t = threadIdx.x;
    const int w = t >> 6, l = t & 63;
    const int wr = w >> 1, wc = w & 1;
    const int m0 = blockIdx.y * 128, n0 = blockIdx.x * 128;

    const short* agp0 = A + (size_t)(m0 + w * 32 + (l >> 2)) * K + (l & 3) * 8;
    const short* agp1 = agp0 + (size_t)16 * K;
    const short* bgp0 = B + (size_t)(n0 + w * 32 + (l >> 2)) * K + (l & 3) * 8;
    const short* bgp1 = bgp0 + (size_t)16 * K;
    short* ldsA = &As[w * 1024];
    short* ldsB = &Bs[w * 1024];

    int aoff[4], boff[4];
    #pragma unroll
    for (int m = 0; m < 4; ++m) aoff[m] = (wr * 64 + m * 16 + (l & 15)) * 32 + (l >> 4) * 8;
    #pragma unroll
    for (int n = 0; n < 4; ++n) boff[n] = (wc * 64 + n * 16 + (l & 15)) * 32 + (l >> 4) * 8;

    f32x4 acc[4][4] = {};

    for (int k0 = 0; k0 < K; k0 += 32) {
        __syncthreads();
        gload_lds16(agp0 + k0, ldsA);
        gload_lds16(agp1 + k0, ldsA + 512);
        gload_lds16(bgp0 + k0, ldsB);
        gload_lds16(bgp1 + k0, ldsB + 512);
        __syncthreads();
        bf16x8 af[4], bfr[4];
        #pragma unroll
        for (int m = 0; m < 4; ++m) af[m]  = *(const bf16x8*)&As[aoff[m]];
        #pragma unroll
        for (int n = 0; n < 4; ++n) bfr[n] = *(const bf16x8*)&Bs[boff[n]];
        #pragma unroll
        for (int m = 0; m < 4; ++m)
            #pragma unroll
            for (int n = 0; n < 4; ++n)
                acc[m][n] = __builtin_amdgcn_mfma_f32_16x16x32_bf16(af[m], bfr[n], acc[m][n], 0, 0, 0);
    }

    const int lr4 = (l >> 4) * 4, lc = l & 15;
    #pragma unroll
    for (int m = 0; m < 4; ++m) {
        #pragma unroll
        for (int n = 0; n < 4; ++n) {
            const int col = n0 + wc * 64 + n * 16 + lc;
            const float bv = BIAS ? bias[col] : 0.0f;
            #pragma unroll
            for (int r = 0; r < 4; ++r) {
                const int row = m0 + wr * 64 + m * 16 + lr4 + r;
                float v = acc[m][n][r] + bv;
                if (GELU_) v = gelu_exact(v);
                if (RES)   v += res[(size_t)row * N + col];
                if (OUTBF16) ((short*)Cv)[(size_t)row * N + col] = f2bf(v);
                else         ((float*)Cv)[(size_t)row * N + col] = v;
            }
        }
    }
}

// ------------- QKV GEMM with custom epilogue -------------
// A[4096,1024] bf16 (LN1 out), B = qkv_w bf16 [3072,1024].
// cols [0,1024): Q*0.125 -> qkvb[row][col]; cols [1024,2048): K -> qkvb[row][col];
// cols [2048,3072): V -> VT[b][h][d][n] transposed.
__global__ __launch_bounds__(256) void qkv_gemm(
    const short* __restrict__ A, const short* __restrict__ B,
    short* __restrict__ qkvb, short* __restrict__ VT, int K)
{
    __shared__ __align__(16) short As[128 * 32];
    __shared__ __align__(16) short Bs[128 * 32];
    const int t = threadIdx.x;
    const int w = t >> 6, l = t & 63;
    const int wr = w >> 1, wc = w & 1;
    const int m0 = blockIdx.y * 128, n0 = blockIdx.x * 128;

    const short* agp0 = A + (size_t)(m0 + w * 32 + (l >> 2)) * K + (l & 3) * 8;
    const short* agp1 = agp0 + (size_t)16 * K;
    const short* bgp0 = B + (size_t)(n0 + w * 32 + (l >> 2)) * K + (l & 3) * 8;
    const short* bgp1 = bgp0 + (size_t)16 * K;
    short* ldsA = &As[w * 1024];
    short* ldsB = &Bs[w * 1024];

    int aoff[4], boff[4];
    #pragma unroll
    for (int m = 0; m < 4; ++m) aoff[m] = (wr * 64 + m * 16 + (l & 15)) * 32 + (l >> 4) * 8;
    #pragma unroll
    for (int n = 0; n < 4; ++n) boff[n] = (wc * 64 + n * 16 + (l & 15)) * 32 + (l >> 4) * 8;

    f32x4 acc[4][4] = {};

    for (int k0 = 0; k0 < K; k0 += 32) {
        __syncthreads();
        gload_lds16(agp0 + k0, ldsA);
        gload_lds16(agp1 + k0, ldsA + 512);
        gload_lds16(bgp0 + k0, ldsB);
        gload_lds16(bgp1 + k0, ldsB + 512);
        __syncthreads();
        bf16x8 af[4], bfr[4];
        #pragma unroll
        for (int m = 0; m < 4; ++m) af[m]  = *(const bf16x8*)&As[aoff[m]];
        #pragma unroll
        for (int n = 0; n < 4; ++n) bfr[n] = *(const bf16x8*)&Bs[boff[n]];
        #pragma unroll
        for (int m = 0; m < 4; ++m)
            #pragma unroll
            for (int n = 0; n < 4; ++n)
                acc[m][n] = __builtin_amdgcn_mfma_f32_16x16x32_bf16(af[m], bfr[n], acc[m][n], 0, 0, 0);
    }

    const int lr4 = (l >> 4) * 4, lc = l & 15;
    if (n0 < 2048) {
        const float sc = (n0 < 1024) ? 0.125f : 1.0f;
        #pragma unroll
        for (int m = 0; m < 4; ++m) {
            #pragma unroll
            for (int n = 0; n < 4; ++n) {
                const int col = n0 + wc * 64 + n * 16 + lc;
                #pragma unroll
                for (int r = 0; r < 4; ++r) {
                    const int row = m0 + wr * 64 + m * 16 + lr4 + r;
                    qkvb[(size_t)row * 2048 + col] = f2bf(acc[m][n][r] * sc);
                }
            }
        }
    } else {
        #pragma unroll
        for (int m = 0; m < 4; ++m) {
            const int row0 = m0 + wr * 64 + m * 16 + lr4;   // 4-aligned
            const int b = row0 >> 10, nseq = row0 & 1023;
            #pragma unroll
            for (int n = 0; n < 4; ++n) {
                const int c2 = n0 - 2048 + wc * 64 + n * 16 + lc;
                const int h = c2 >> 6, d = c2 & 63;
                short4 v4;
                v4.x = f2bf(acc[m][n][0]); v4.y = f2bf(acc[m][n][1]);
                v4.z = f2bf(acc[m][n][2]); v4.w = f2bf(acc[m][n][3]);
                *(short4*)&VT[(((size_t)(b * 16 + h) * 64 + d) * 1024) + nseq] = v4;
            }
        }
    }
}

// ---------------- MFMA flash attention ----------------
// qkvb: [4096][2048] bf16 (Q scaled | K), VT: [b][h][d][n] bf16.
// Block: (q-tile 64 rows, bh). 4 waves, wave w owns q rows [w*16, w*16+16).
// KV tiles of 64, double-buffered LDS with source-side XOR swizzle.
__global__ __launch_bounds__(256) void fattn(const short* __restrict__ qkvb,
                                             const short* __restrict__ VT,
                                             short* __restrict__ o) {
    const int bh = blockIdx.y;
    const int b = bh >> 4, h = bh & 15;
    const int q0 = blockIdx.x * 64;
    const int t = threadIdx.x, w = t >> 6, l = t & 63;

    __shared__ __align__(16) short Ks[2][64 * 64];
    __shared__ __align__(16) short Vs[2][64 * 64];
    __shared__ __align__(16) short Ps[4][1024];

    // Q fragments (A-frag): rows q0+w*16+(l&15), k-chunk ks*32+(l>>4)*8
    const size_t qrow = (size_t)(b * SEQ + q0 + w * 16 + (l & 15)) * 2048 + h * 64;
    bf16x8 qf[2];
    qf[0] = *(const bf16x8*)&qkvb[qrow + (l >> 4) * 8];
    qf[1] = *(const bf16x8*)&qkvb[qrow + 32 + (l >> 4) * 8];

    const int srow = l >> 3;                     // 0..7 within an 8-row staging group
    const int sc16 = (l & 7) ^ (srow & 7);       // swizzled source col-block
    const short* Kg = qkvb + 1024 + h * 64;      // + (b*SEQ + kv)*2048
    const short* Vg = VT + (size_t)bh * 64 * 1024;  // + d*1024 + kv

    f32x4 acc[4] = {};                            // O: col d=nt2*16+(l&15), row q=(l>>4)*4+r
    float mrow[4] = {-1e30f, -1e30f, -1e30f, -1e30f};
    float lrow[4] = {0.f, 0.f, 0.f, 0.f};

    auto stage = [&](int kt, int buf) {
        const int kv0 = kt * 64;
        #pragma unroll
        for (int i = 0; i < 2; ++i) {
            const int r0 = w * 16 + i * 8;       // wave-uniform, multiple of 8
            gload_lds16(Kg + (size_t)(b * SEQ + kv0 + r0 + srow) * 2048 + sc16 * 8,
                        &Ks[buf][r0 * 64]);
            gload_lds16(Vg + (size_t)(r0 + srow) * 1024 + kv0 + sc16 * 8,
                        &Vs[buf][r0 * 64]);
        }
    };

    stage(0, 0);
    for (int kt = 0; kt < 16; ++kt) {
        const int cur = kt & 1;
        __syncthreads();                          // drains staging of tile kt
        if (kt + 1 < 16) stage(kt + 1, cur ^ 1);

        // S = Q K^T  (S col = kv = nt*16+(l&15), row q=(l>>4)*4+r)
        f32x4 sacc[4];
        #pragma unroll
        for (int nt = 0; nt < 4; ++nt) {
            f32x4 z = {};
            #pragma unroll
            for (int ks = 0; ks < 2; ++ks) {
                const int row = nt * 16 + (l & 15);
                const int c16 = (ks * 4 + (l >> 4)) ^ (row & 7);
                const bf16x8 kf = *(const bf16x8*)&Ks[cur][row * 64 + c16 * 8];
                z = __builtin_amdgcn_mfma_f32_16x16x32_bf16(qf[ks], kf, z, 0, 0, 0);
            }
            sacc[nt] = z;
        }
        // row-max over tile (16-lane shfl groups share a q row set)
        float tmax[4], tsum[4], fac[4];
        #pragma unroll
        for (int r = 0; r < 4; ++r)
            tmax[r] = fmaxf(fmaxf(sacc[0][r], sacc[1][r]), fmaxf(sacc[2][r], sacc[3][r]));
        #pragma unroll
        for (int off = 1; off <= 8; off <<= 1)
            #pragma unroll
            for (int r = 0; r < 4; ++r)
                tmax[r] = fmaxf(tmax[r], __shfl_xor(tmax[r], off));
        #pragma unroll
        for (int r = 0; r < 4; ++r) {
            const float nm = fmaxf(mrow[r], tmax[r]);
            fac[r] = __expf(mrow[r] - nm);
            mrow[r] = nm;
            tsum[r] = 0.0f;
        }
        // P = exp(S - m) -> bf16 -> per-wave LDS (swizzled), accumulate sums
        #pragma unroll
        for (int nt = 0; nt < 4; ++nt) {
            #pragma unroll
            for (int r = 0; r < 4; ++r) {
                const float p = __expf(sacc[nt][r] - mrow[r]);
                tsum[r] += p;
                const int q = (l >> 4) * 4 + r;
                const int kv = nt * 16 + (l & 15);
                union { float f; uint32_t u; } cu; cu.f = p;
                Ps[w][q * 64 + (kv ^ ((q & 7) << 3))] = (short)((cu.u + 0x8000u) >> 16);
            }
        }
        #pragma unroll
        for (int off = 1; off <= 8; off <<= 1)
            #pragma unroll
            for (int r = 0; r < 4; ++r)
                tsum[r] += __shfl_xor(tsum[r], off);
        #pragma unroll
        for (int r = 0; r < 4; ++r) lrow[r] = lrow[r] * fac[r] + tsum[r];
        #pragma unroll
        for (int nt2 = 0; nt2 < 4; ++nt2)
            #pragma unroll
            for (int r = 0; r < 4; ++r)
                acc[nt2][r] *= fac[r];
        // PV: O += P V  (A-frag from Ps, B-frag from Vs)
        #pragma unroll
        for (int ks = 0; ks < 2; ++ks) {
            const int ql = l & 15;
            const bf16x8 pa = *(const bf16x8*)&Ps[w][ql * 64 + ((ks * 32 + (l >> 4) * 8) ^ ((ql & 7) << 3))];
            #pragma unroll
            for (int nt2 = 0; nt2 < 4; ++nt2) {
                const int row = nt2 * 16 + (l & 15);
                const int c16 = (ks * 4 + (l >> 4)) ^ (row & 7);
                const bf16x8 vf = *(const bf16x8*)&Vs[cur][row * 64 + c16 * 8];
                acc[nt2] = __builtin_amdgcn_mfma_f32_16x16x32_bf16(pa, vf, acc[nt2], 0, 0, 0);
            }
        }
    }
    // normalize + write
    #pragma unroll
    for (int r = 0; r < 4; ++r) {
        const float rcp = 1.0f / lrow[r];
        const int q = q0 + w * 16 + (l >> 4) * 4 + r;
        #pragma unroll
        for (int nt2 = 0; nt2 < 4; ++nt2) {
            const int d = nt2 * 16 + (l & 15);
            o[(size_t)(b * SEQ + q) * CDIM + h * 64 + d] = f2bf(acc[nt2][r] * rcp);
        }
    }
}

extern "C" void kernel_launch(void* const* d_in, const int* in_sizes, int n_in,
                              void* d_out, int out_size, void* d_ws, size_t ws_size,
                              hipStream_t stream) {
    const float* x      = (const float*)d_in[0];
    const float* ln1_w  = (const float*)d_in[1];
    const float* ln1_b  = (const float*)d_in[2];
    const float* qkv_w  = (const float*)d_in[3];
    const float* proj_w = (const float*)d_in[4];
    const float* proj_b = (const float*)d_in[5];
    const float* ln2_w  = (const float*)d_in[6];
    const float* ln2_b  = (const float*)d_in[7];
    const float* fc1_w  = (const float*)d_in[8];
    const float* fc1_b  = (const float*)d_in[9];
    const float* fc2_w  = (const float*)d_in[10];
    const float* fc2_b  = (const float*)d_in[11];
    float* out = (float*)d_out;

    // workspace (80 MB):
    // [0,24M)  bf16 weights
    // [24M,40M) qkvb bf16 [4096][2048]   (dead after fattn)
    // [40M,48M) VT   bf16 [4][16][64][1024]  (dead after fattn)
    // [24M,56M) mlp1 bf16 (reuses qkvb/VT)
    // [72M,80M) hbuf bf16 (LN1 out -> attn out -> LN2 out)
    short* ws16  = (short*)d_ws;
    short* wqkv  = ws16;
    short* wproj = ws16 + 3145728;
    short* wfc1  = ws16 + 4194304;
    short* wfc2  = ws16 + 8388608;
    char*  wsb   = (char*)d_ws;
    short* qkvb  = (short*)(wsb + (size_t)24 * 1024 * 1024);
    short* VT    = (short*)(wsb + (size_t)40 * 1024 * 1024);
    short* mlp1  = (short*)(wsb + (size_t)24 * 1024 * 1024);
    short* hbuf  = (short*)(wsb + (size_t)72 * 1024 * 1024);

    cvt_bf16_kernel<<<1536, 256, 0, stream>>>(qkv_w, wqkv);
    cvt_bf16_kernel<<< 512, 256, 0, stream>>>(proj_w, wproj);
    cvt_bf16_kernel<<<2048, 256, 0, stream>>>(fc1_w, wfc1);
    cvt_bf16_kernel<<<2048, 256, 0, stream>>>(fc2_w, wfc2);

    ln_kernel<<<MROWS, 256, 0, stream>>>(x, ln1_w, ln1_b, hbuf);
    qkv_gemm<<<dim3(24, 32), 256, 0, stream>>>(hbuf, wqkv, qkvb, VT, 1024);
    fattn<<<dim3(SEQ / 64, BATCH * NHEAD), 256, 0, stream>>>(qkvb, VT, hbuf);
    mgemm<true,true,false,false><<<dim3(8, 32), 256, 0, stream>>>(
        hbuf, wproj, proj_b, x, out, MROWS, 1024, 1024);
    ln_kernel<<<MROWS, 256, 0, stream>>>(out, ln2_w, ln2_b, hbuf);
    mgemm<true,false,true,true><<<dim3(32, 32), 256, 0, stream>>>(
        hbuf, wfc1, fc1_b, nullptr, mlp1, MROWS, 4096, 1024);
    mgemm<true,true,false,false><<<dim3(8, 32), 256, 0, stream>>>(
        mlp1, wfc2, fc2_b, out, out, MROWS, 1024, 4096);
}

// Round 5
// 295.860 us; speedup vs baseline: 7.3529x; 1.0570x over previous
//
#include <hip/hip_runtime.h>
#include <hip/hip_bf16.h>
#include <math.h>
#include <stdint.h>

#define SEQ 1024
#define CDIM 1024
#define NHEAD 16
#define HIDDEN 4096
#define BATCH 4
#define MROWS (BATCH*SEQ)   // 4096

using bf16x8 = __attribute__((ext_vector_type(8))) short;
using f32x4  = __attribute__((ext_vector_type(4))) float;

__device__ __forceinline__ short f2bf(float f) {
    union { float f; uint32_t u; } c; c.f = f;
    const uint32_t u = c.u + 0x7FFFu + ((c.u >> 16) & 1u);
    return (short)(u >> 16);
}

__device__ __forceinline__ float gelu_exact(float v) {
    return 0.5f * v * (1.0f + erff(v * 0.70710678118654752440f));
}

// async global->LDS, 16B per lane; LDS dest is wave-uniform base + lane*16
__device__ __forceinline__ void gload_lds16(const short* g, short* lds) {
    __builtin_amdgcn_global_load_lds(
        (const __attribute__((address_space(1))) void*)(uintptr_t)g,
        (__attribute__((address_space(3))) void*)(uintptr_t)lds,
        16, 0, 0);
}

// ---------------- weight fp32 -> bf16 conversion ----------------
__global__ void cvt_bf16_kernel(const float* __restrict__ in, short* __restrict__ out) {
    const size_t i = ((size_t)blockIdx.x * 256 + threadIdx.x) * 8;
    const float4 a = *(const float4*)(in + i);
    const float4 b = *(const float4*)(in + i + 4);
    bf16x8 s;
    s[0] = f2bf(a.x); s[1] = f2bf(a.y); s[2] = f2bf(a.z); s[3] = f2bf(a.w);
    s[4] = f2bf(b.x); s[5] = f2bf(b.y); s[6] = f2bf(b.z); s[7] = f2bf(b.w);
    *(bf16x8*)(out + i) = s;
}

// ---------------- LayerNorm: one block per row, bf16 output ----------------
__global__ void ln_kernel(const float* __restrict__ x, const float* __restrict__ w,
                          const float* __restrict__ b, short* __restrict__ out) {
    const int row = blockIdx.x;
    const int t = threadIdx.x;               // 256 threads
    const float4* xr = (const float4*)(x + (size_t)row * CDIM);
    float4 v = xr[t];
    float s  = v.x + v.y + v.z + v.w;
    float sq = v.x*v.x + v.y*v.y + v.z*v.z + v.w*v.w;
    #pragma unroll
    for (int off = 32; off; off >>= 1) {
        s  += __shfl_down(s, off);
        sq += __shfl_down(sq, off);
    }
    __shared__ float ss[4], ssq[4];
    const int wid = t >> 6, lane = t & 63;
    if (lane == 0) { ss[wid] = s; ssq[wid] = sq; }
    __syncthreads();
    s  = ss[0] + ss[1] + ss[2] + ss[3];
    sq = ssq[0] + ssq[1] + ssq[2] + ssq[3];
    const float mu  = s * (1.0f / CDIM);
    const float var = sq * (1.0f / CDIM) - mu * mu;
    const float rs  = rsqrtf(var + 1e-5f);
    const float4 wv = ((const float4*)w)[t];
    const float4 bv = ((const float4*)b)[t];
    short4 o;
    o.x = f2bf((v.x - mu) * rs * wv.x + bv.x);
    o.y = f2bf((v.y - mu) * rs * wv.y + bv.y);
    o.z = f2bf((v.z - mu) * rs * wv.z + bv.z);
    o.w = f2bf((v.w - mu) * rs * wv.w + bv.w);
    *(short4*)(out + (size_t)row * CDIM + t * 4) = o;
}

// ------------- bf16 MFMA GEMM: C[M,N] = A[M,K] * B[N,K]^T (+bias)(+gelu)(+res) -----
// BM=128 fixed; BN in {128, 64}. BN=128: 4 waves 2x2, each 64x64 (4x4 frags).
// BN=64: 4 waves 4x1, each 32x64 (2x4 frags). XCD-aware swizzle (grids % 8 == 0).
template<int BN, bool BIAS, bool RES, bool GELU_, bool OUTBF16>
__global__ __launch_bounds__(256) void mgemm(
    const short* __restrict__ A, const short* __restrict__ B,
    const float* __restrict__ bias, const float* __restrict__ res,
    void* __restrict__ Cv, int M, int N, int K)
{
    constexpr int MF = (BN == 128) ? 4 : 2;   // M-frags per wave
    __shared__ __align__(16) short As[128 * 32];
    __shared__ __align__(16) short Bs[BN * 32];
    const int t = threadIdx.x;
    const int w = t >> 6, l = t & 63;

    // XCD-aware bijective swizzle
    const int gx = gridDim.x;
    const int nwg = gx * gridDim.y;
    const int lid = blockIdx.y * gx + blockIdx.x;
    const int swz = (lid & 7) * (nwg >> 3) + (lid >> 3);
    const int bx = swz % gx, by = swz / gx;
    const int m0 = by * 128, n0 = bx * BN;

    const int wrow = (BN == 128) ? (w >> 1) * 64 : w * 32;
    const int wcol = (BN == 128) ? (w & 1) * 64 : 0;

    const short* agp0 = A + (size_t)(m0 + w * 32 + (l >> 2)) * K + (l & 3) * 8;
    const short* agp1 = agp0 + (size_t)16 * K;
    short* ldsA = &As[w * 1024];
    const short* bgp0;
    const short* bgp1 = nullptr;
    short* ldsB;
    if (BN == 128) {
        bgp0 = B + (size_t)(n0 + w * 32 + (l >> 2)) * K + (l & 3) * 8;
        bgp1 = bgp0 + (size_t)16 * K;
        ldsB = &Bs[w * 1024];
    } else {
        bgp0 = B + (size_t)(n0 + w * 16 + (l >> 2)) * K + (l & 3) * 8;
        ldsB = &Bs[w * 512];
    }

    int aoff[MF], boff[4];
    #pragma unroll
    for (int m = 0; m < MF; ++m) aoff[m] = (wrow + m * 16 + (l & 15)) * 32 + (l >> 4) * 8;
    #pragma unroll
    for (int n = 0; n < 4; ++n)  boff[n] = (wcol + n * 16 + (l & 15)) * 32 + (l >> 4) * 8;

    f32x4 acc[MF][4] = {};

    for (int k0 = 0; k0 < K; k0 += 32) {
        __syncthreads();
        gload_lds16(agp0 + k0, ldsA);
        gload_lds16(agp1 + k0, ldsA + 512);
        gload_lds16(bgp0 + k0, ldsB);
        if (BN == 128) gload_lds16(bgp1 + k0, ldsB + 512);
        __syncthreads();
        bf16x8 af[MF], bfr[4];
        #pragma unroll
        for (int m = 0; m < MF; ++m) af[m]  = *(const bf16x8*)&As[aoff[m]];
        #pragma unroll
        for (int n = 0; n < 4; ++n)  bfr[n] = *(const bf16x8*)&Bs[boff[n]];
        #pragma unroll
        for (int m = 0; m < MF; ++m)
            #pragma unroll
            for (int n = 0; n < 4; ++n)
                acc[m][n] = __builtin_amdgcn_mfma_f32_16x16x32_bf16(af[m], bfr[n], acc[m][n], 0, 0, 0);
    }

    const int lr4 = (l >> 4) * 4, lc = l & 15;
    #pragma unroll
    for (int m = 0; m < MF; ++m) {
        #pragma unroll
        for (int n = 0; n < 4; ++n) {
            const int col = n0 + wcol + n * 16 + lc;
            const float bv = BIAS ? bias[col] : 0.0f;
            #pragma unroll
            for (int r = 0; r < 4; ++r) {
                const int row = m0 + wrow + m * 16 + lr4 + r;
                float v = acc[m][n][r] + bv;
                if (GELU_) v = gelu_exact(v);
                if (RES)   v += res[(size_t)row * N + col];
                if (OUTBF16) ((short*)Cv)[(size_t)row * N + col] = f2bf(v);
                else         ((float*)Cv)[(size_t)row * N + col] = v;
            }
        }
    }
}

// ------------- QKV GEMM with custom epilogue -------------
// cols [0,1024): Q*0.125 -> qkvb; [1024,2048): K -> qkvb; [2048,3072): V -> VT.
__global__ __launch_bounds__(256) void qkv_gemm(
    const short* __restrict__ A, const short* __restrict__ B,
    short* __restrict__ qkvb, short* __restrict__ VT, int K)
{
    __shared__ __align__(16) short As[128 * 32];
    __shared__ __align__(16) short Bs[128 * 32];
    const int t = threadIdx.x;
    const int w = t >> 6, l = t & 63;
    const int wr = w >> 1, wc = w & 1;

    const int gx = gridDim.x;
    const int nwg = gx * gridDim.y;
    const int lid = blockIdx.y * gx + blockIdx.x;
    const int swz = (lid & 7) * (nwg >> 3) + (lid >> 3);
    const int bx = swz % gx, by = swz / gx;
    const int m0 = by * 128, n0 = bx * 128;

    const short* agp0 = A + (size_t)(m0 + w * 32 + (l >> 2)) * K + (l & 3) * 8;
    const short* agp1 = agp0 + (size_t)16 * K;
    const short* bgp0 = B + (size_t)(n0 + w * 32 + (l >> 2)) * K + (l & 3) * 8;
    const short* bgp1 = bgp0 + (size_t)16 * K;
    short* ldsA = &As[w * 1024];
    short* ldsB = &Bs[w * 1024];

    int aoff[4], boff[4];
    #pragma unroll
    for (int m = 0; m < 4; ++m) aoff[m] = (wr * 64 + m * 16 + (l & 15)) * 32 + (l >> 4) * 8;
    #pragma unroll
    for (int n = 0; n < 4; ++n) boff[n] = (wc * 64 + n * 16 + (l & 15)) * 32 + (l >> 4) * 8;

    f32x4 acc[4][4] = {};

    for (int k0 = 0; k0 < K; k0 += 32) {
        __syncthreads();
        gload_lds16(agp0 + k0, ldsA);
        gload_lds16(agp1 + k0, ldsA + 512);
        gload_lds16(bgp0 + k0, ldsB);
        gload_lds16(bgp1 + k0, ldsB + 512);
        __syncthreads();
        bf16x8 af[4], bfr[4];
        #pragma unroll
        for (int m = 0; m < 4; ++m) af[m]  = *(const bf16x8*)&As[aoff[m]];
        #pragma unroll
        for (int n = 0; n < 4; ++n) bfr[n] = *(const bf16x8*)&Bs[boff[n]];
        #pragma unroll
        for (int m = 0; m < 4; ++m)
            #pragma unroll
            for (int n = 0; n < 4; ++n)
                acc[m][n] = __builtin_amdgcn_mfma_f32_16x16x32_bf16(af[m], bfr[n], acc[m][n], 0, 0, 0);
    }

    const int lr4 = (l >> 4) * 4, lc = l & 15;
    if (n0 < 2048) {
        const float sc = (n0 < 1024) ? 0.125f : 1.0f;
        #pragma unroll
        for (int m = 0; m < 4; ++m) {
            #pragma unroll
            for (int n = 0; n < 4; ++n) {
                const int col = n0 + wc * 64 + n * 16 + lc;
                #pragma unroll
                for (int r = 0; r < 4; ++r) {
                    const int row = m0 + wr * 64 + m * 16 + lr4 + r;
                    qkvb[(size_t)row * 2048 + col] = f2bf(acc[m][n][r] * sc);
                }
            }
        }
    } else {
        #pragma unroll
        for (int m = 0; m < 4; ++m) {
            const int row0 = m0 + wr * 64 + m * 16 + lr4;   // 4-aligned
            const int b = row0 >> 10, nseq = row0 & 1023;
            #pragma unroll
            for (int n = 0; n < 4; ++n) {
                const int c2 = n0 - 2048 + wc * 64 + n * 16 + lc;
                const int h = c2 >> 6, d = c2 & 63;
                short4 v4;
                v4.x = f2bf(acc[m][n][0]); v4.y = f2bf(acc[m][n][1]);
                v4.z = f2bf(acc[m][n][2]); v4.w = f2bf(acc[m][n][3]);
                *(short4*)&VT[(((size_t)(b * 16 + h) * 64 + d) * 1024) + nseq] = v4;
            }
        }
    }
}

// ---------------- MFMA flash attention ----------------
__global__ __launch_bounds__(256) void fattn(const short* __restrict__ qkvb,
                                             const short* __restrict__ VT,
                                             short* __restrict__ o) {
    const int bh = blockIdx.y;
    const int b = bh >> 4, h = bh & 15;
    const int q0 = blockIdx.x * 64;
    const int t = threadIdx.x, w = t >> 6, l = t & 63;

    __shared__ __align__(16) short Ks[2][64 * 64];
    __shared__ __align__(16) short Vs[2][64 * 64];
    __shared__ __align__(16) short Ps[4][1024];

    const size_t qrow = (size_t)(b * SEQ + q0 + w * 16 + (l & 15)) * 2048 + h * 64;
    bf16x8 qf[2];
    qf[0] = *(const bf16x8*)&qkvb[qrow + (l >> 4) * 8];
    qf[1] = *(const bf16x8*)&qkvb[qrow + 32 + (l >> 4) * 8];

    const int srow = l >> 3;
    const int sc16 = (l & 7) ^ (srow & 7);
    const short* Kg = qkvb + 1024 + h * 64;
    const short* Vg = VT + (size_t)bh * 64 * 1024;

    f32x4 acc[4] = {};
    float mrow[4] = {-1e30f, -1e30f, -1e30f, -1e30f};
    float lrow[4] = {0.f, 0.f, 0.f, 0.f};

    auto stage = [&](int kt, int buf) {
        const int kv0 = kt * 64;
        #pragma unroll
        for (int i = 0; i < 2; ++i) {
            const int r0 = w * 16 + i * 8;
            gload_lds16(Kg + (size_t)(b * SEQ + kv0 + r0 + srow) * 2048 + sc16 * 8,
                        &Ks[buf][r0 * 64]);
            gload_lds16(Vg + (size_t)(r0 + srow) * 1024 + kv0 + sc16 * 8,
                        &Vs[buf][r0 * 64]);
        }
    };

    stage(0, 0);
    for (int kt = 0; kt < 16; ++kt) {
        const int cur = kt & 1;
        __syncthreads();
        if (kt + 1 < 16) stage(kt + 1, cur ^ 1);

        f32x4 sacc[4];
        #pragma unroll
        for (int nt = 0; nt < 4; ++nt) {
            f32x4 z = {};
            #pragma unroll
            for (int ks = 0; ks < 2; ++ks) {
                const int row = nt * 16 + (l & 15);
                const int c16 = (ks * 4 + (l >> 4)) ^ (row & 7);
                const bf16x8 kf = *(const bf16x8*)&Ks[cur][row * 64 + c16 * 8];
                z = __builtin_amdgcn_mfma_f32_16x16x32_bf16(qf[ks], kf, z, 0, 0, 0);
            }
            sacc[nt] = z;
        }
        float tmax[4], tsum[4], fac[4];
        #pragma unroll
        for (int r = 0; r < 4; ++r)
            tmax[r] = fmaxf(fmaxf(sacc[0][r], sacc[1][r]), fmaxf(sacc[2][r], sacc[3][r]));
        #pragma unroll
        for (int off = 1; off <= 8; off <<= 1)
            #pragma unroll
            for (int r = 0; r < 4; ++r)
                tmax[r] = fmaxf(tmax[r], __shfl_xor(tmax[r], off));
        #pragma unroll
        for (int r = 0; r < 4; ++r) {
            const float nm = fmaxf(mrow[r], tmax[r]);
            fac[r] = __expf(mrow[r] - nm);
            mrow[r] = nm;
            tsum[r] = 0.0f;
        }
        #pragma unroll
        for (int nt = 0; nt < 4; ++nt) {
            #pragma unroll
            for (int r = 0; r < 4; ++r) {
                const float p = __expf(sacc[nt][r] - mrow[r]);
                tsum[r] += p;
                const int q = (l >> 4) * 4 + r;
                const int kv = nt * 16 + (l & 15);
                union { float f; uint32_t u; } cu; cu.f = p;
                Ps[w][q * 64 + (kv ^ ((q & 7) << 3))] = (short)((cu.u + 0x8000u) >> 16);
            }
        }
        #pragma unroll
        for (int off = 1; off <= 8; off <<= 1)
            #pragma unroll
            for (int r = 0; r < 4; ++r)
                tsum[r] += __shfl_xor(tsum[r], off);
        #pragma unroll
        for (int r = 0; r < 4; ++r) lrow[r] = lrow[r] * fac[r] + tsum[r];
        #pragma unroll
        for (int nt2 = 0; nt2 < 4; ++nt2)
            #pragma unroll
            for (int r = 0; r < 4; ++r)
                acc[nt2][r] *= fac[r];
        #pragma unroll
        for (int ks = 0; ks < 2; ++ks) {
            const int ql = l & 15;
            const bf16x8 pa = *(const bf16x8*)&Ps[w][ql * 64 + ((ks * 32 + (l >> 4) * 8) ^ ((ql & 7) << 3))];
            #pragma unroll
            for (int nt2 = 0; nt2 < 4; ++nt2) {
                const int row = nt2 * 16 + (l & 15);
                const int c16 = (ks * 4 + (l >> 4)) ^ (row & 7);
                const bf16x8 vf = *(const bf16x8*)&Vs[cur][row * 64 + c16 * 8];
                acc[nt2] = __builtin_amdgcn_mfma_f32_16x16x32_bf16(pa, vf, acc[nt2], 0, 0, 0);
            }
        }
    }
    #pragma unroll
    for (int r = 0; r < 4; ++r) {
        const float rcp = 1.0f / lrow[r];
        const int q = q0 + w * 16 + (l >> 4) * 4 + r;
        #pragma unroll
        for (int nt2 = 0; nt2 < 4; ++nt2) {
            const int d = nt2 * 16 + (l & 15);
            o[(size_t)(b * SEQ + q) * CDIM + h * 64 + d] = f2bf(acc[nt2][r] * rcp);
        }
    }
}

extern "C" void kernel_launch(void* const* d_in, const int* in_sizes, int n_in,
                              void* d_out, int out_size, void* d_ws, size_t ws_size,
                              hipStream_t stream) {
    const float* x      = (const float*)d_in[0];
    const float* ln1_w  = (const float*)d_in[1];
    const float* ln1_b  = (const float*)d_in[2];
    const float* qkv_w  = (const float*)d_in[3];
    const float* proj_w = (const float*)d_in[4];
    const float* proj_b = (const float*)d_in[5];
    const float* ln2_w  = (const float*)d_in[6];
    const float* ln2_b  = (const float*)d_in[7];
    const float* fc1_w  = (const float*)d_in[8];
    const float* fc1_b  = (const float*)d_in[9];
    const float* fc2_w  = (const float*)d_in[10];
    const float* fc2_b  = (const float*)d_in[11];
    float* out = (float*)d_out;

    short* ws16  = (short*)d_ws;
    short* wqkv  = ws16;
    short* wproj = ws16 + 3145728;
    short* wfc1  = ws16 + 4194304;
    short* wfc2  = ws16 + 8388608;
    char*  wsb   = (char*)d_ws;
    short* qkvb  = (short*)(wsb + (size_t)24 * 1024 * 1024);
    short* VT    = (short*)(wsb + (size_t)40 * 1024 * 1024);
    short* mlp1  = (short*)(wsb + (size_t)24 * 1024 * 1024);
    short* hbuf  = (short*)(wsb + (size_t)72 * 1024 * 1024);

    cvt_bf16_kernel<<<1536, 256, 0, stream>>>(qkv_w, wqkv);
    cvt_bf16_kernel<<< 512, 256, 0, stream>>>(proj_w, wproj);
    cvt_bf16_kernel<<<2048, 256, 0, stream>>>(fc1_w, wfc1);
    cvt_bf16_kernel<<<2048, 256, 0, stream>>>(fc2_w, wfc2);

    ln_kernel<<<MROWS, 256, 0, stream>>>(x, ln1_w, ln1_b, hbuf);
    qkv_gemm<<<dim3(24, 32), 256, 0, stream>>>(hbuf, wqkv, qkvb, VT, 1024);
    fattn<<<dim3(SEQ / 64, BATCH * NHEAD), 256, 0, stream>>>(qkvb, VT, hbuf);
    // proj: BN=64, grid 16x32 = 512 blocks (2/CU)
    mgemm<64,true,true,false,false><<<dim3(16, 32), 256, 0, stream>>>(
        hbuf, wproj, proj_b, x, out, MROWS, 1024, 1024);
    ln_kernel<<<MROWS, 256, 0, stream>>>(out, ln2_w, ln2_b, hbuf);
    // FC1: BN=128, grid 32x32 = 1024 blocks (4/CU)
    mgemm<128,true,false,true,true><<<dim3(32, 32), 256, 0, stream>>>(
        hbuf, wfc1, fc1_b, nullptr, mlp1, MROWS, 4096, 1024);
    // FC2: BN=64, grid 16x32 = 512 blocks (2/CU)
    mgemm<64,true,true,false,false><<<dim3(16, 32), 256, 0, stream>>>(
        mlp1, wfc2, fc2_b, out, out, MROWS, 1024, 4096);
}

// Round 6
// 261.584 us; speedup vs baseline: 8.3163x; 1.1310x over previous
//
#include <hip/hip_runtime.h>
#include <hip/hip_bf16.h>
#include <math.h>
#include <stdint.h>

#define SEQ 1024
#define CDIM 1024
#define NHEAD 16
#define HIDDEN 4096
#define BATCH 4
#define MROWS (BATCH*SEQ)   // 4096

using bf16x8 = __attribute__((ext_vector_type(8))) short;
using f32x4  = __attribute__((ext_vector_type(4))) float;

__device__ __forceinline__ short f2bf(float f) {
    union { float f; uint32_t u; } c; c.f = f;
    const uint32_t u = c.u + 0x7FFFu + ((c.u >> 16) & 1u);
    return (short)(u >> 16);
}

__device__ __forceinline__ float gelu_exact(float v) {
    return 0.5f * v * (1.0f + erff(v * 0.70710678118654752440f));
}

// async global->LDS, 16B per lane; LDS dest is wave-uniform base + lane*16
__device__ __forceinline__ void gload_lds16(const short* g, short* lds) {
    __builtin_amdgcn_global_load_lds(
        (const __attribute__((address_space(1))) void*)(uintptr_t)g,
        (__attribute__((address_space(3))) void*)(uintptr_t)lds,
        16, 0, 0);
}

// ---------------- weight fp32 -> bf16 conversion ----------------
__global__ void cvt_bf16_kernel(const float* __restrict__ in, short* __restrict__ out) {
    const size_t i = ((size_t)blockIdx.x * 256 + threadIdx.x) * 8;
    const float4 a = *(const float4*)(in + i);
    const float4 b = *(const float4*)(in + i + 4);
    bf16x8 s;
    s[0] = f2bf(a.x); s[1] = f2bf(a.y); s[2] = f2bf(a.z); s[3] = f2bf(a.w);
    s[4] = f2bf(b.x); s[5] = f2bf(b.y); s[6] = f2bf(b.z); s[7] = f2bf(b.w);
    *(bf16x8*)(out + i) = s;
}

// ---------------- LayerNorm: one block per row, bf16 output ----------------
__global__ void ln_kernel(const float* __restrict__ x, const float* __restrict__ w,
                          const float* __restrict__ b, short* __restrict__ out) {
    const int row = blockIdx.x;
    const int t = threadIdx.x;               // 256 threads
    const float4* xr = (const float4*)(x + (size_t)row * CDIM);
    float4 v = xr[t];
    float s  = v.x + v.y + v.z + v.w;
    float sq = v.x*v.x + v.y*v.y + v.z*v.z + v.w*v.w;
    #pragma unroll
    for (int off = 32; off; off >>= 1) {
        s  += __shfl_down(s, off);
        sq += __shfl_down(sq, off);
    }
    __shared__ float ss[4], ssq[4];
    const int wid = t >> 6, lane = t & 63;
    if (lane == 0) { ss[wid] = s; ssq[wid] = sq; }
    __syncthreads();
    s  = ss[0] + ss[1] + ss[2] + ss[3];
    sq = ssq[0] + ssq[1] + ssq[2] + ssq[3];
    const float mu  = s * (1.0f / CDIM);
    const float var = sq * (1.0f / CDIM) - mu * mu;
    const float rs  = rsqrtf(var + 1e-5f);
    const float4 wv = ((const float4*)w)[t];
    const float4 bv = ((const float4*)b)[t];
    short4 o;
    o.x = f2bf((v.x - mu) * rs * wv.x + bv.x);
    o.y = f2bf((v.y - mu) * rs * wv.y + bv.y);
    o.z = f2bf((v.z - mu) * rs * wv.z + bv.z);
    o.w = f2bf((v.w - mu) * rs * wv.w + bv.w);
    *(short4*)(out + (size_t)row * CDIM + t * 4) = o;
}

// ------------- bf16 MFMA GEMM, double-buffered 2-phase (stage-early/drain-late) -----
// BM=128; BN in {128, 64}. XCD-aware bijective swizzle (grids % 8 == 0).
template<int BN, bool BIAS, bool RES, bool GELU_, bool OUTBF16>
__global__ __launch_bounds__(256) void mgemm(
    const short* __restrict__ A, const short* __restrict__ B,
    const float* __restrict__ bias, const float* __restrict__ res,
    void* __restrict__ Cv, int M, int N, int K)
{
    constexpr int MF = (BN == 128) ? 4 : 2;   // M-frags per wave
    __shared__ __align__(16) short As[2][128 * 32];
    __shared__ __align__(16) short Bs[2][BN * 32];
    const int t = threadIdx.x;
    const int w = t >> 6, l = t & 63;

    // XCD-aware bijective swizzle
    const int gx = gridDim.x;
    const int nwg = gx * gridDim.y;
    const int lid = blockIdx.y * gx + blockIdx.x;
    const int swz = (lid & 7) * (nwg >> 3) + (lid >> 3);
    const int bx = swz % gx, by = swz / gx;
    const int m0 = by * 128, n0 = bx * BN;

    const int wrow = (BN == 128) ? (w >> 1) * 64 : w * 32;
    const int wcol = (BN == 128) ? (w & 1) * 64 : 0;

    const short* agp0 = A + (size_t)(m0 + w * 32 + (l >> 2)) * K + (l & 3) * 8;
    const short* agp1 = agp0 + (size_t)16 * K;
    const short* bgp0;
    const short* bgp1 = nullptr;
    if (BN == 128) {
        bgp0 = B + (size_t)(n0 + w * 32 + (l >> 2)) * K + (l & 3) * 8;
        bgp1 = bgp0 + (size_t)16 * K;
    } else {
        bgp0 = B + (size_t)(n0 + w * 16 + (l >> 2)) * K + (l & 3) * 8;
    }

    int aoff[MF], boff[4];
    #pragma unroll
    for (int m = 0; m < MF; ++m) aoff[m] = (wrow + m * 16 + (l & 15)) * 32 + (l >> 4) * 8;
    #pragma unroll
    for (int n = 0; n < 4; ++n)  boff[n] = (wcol + n * 16 + (l & 15)) * 32 + (l >> 4) * 8;

    auto stage = [&](int k0, int buf) {
        short* ldsA = &As[buf][w * 1024];
        gload_lds16(agp0 + k0, ldsA);
        gload_lds16(agp1 + k0, ldsA + 512);
        if (BN == 128) {
            short* ldsB = &Bs[buf][w * 1024];
            gload_lds16(bgp0 + k0, ldsB);
            gload_lds16(bgp1 + k0, ldsB + 512);
        } else {
            gload_lds16(bgp0 + k0, &Bs[buf][w * 512]);
        }
    };

    f32x4 acc[MF][4] = {};
    stage(0, 0);
    int cur = 0;
    for (int k0 = 0; k0 < K; k0 += 32) {
        __syncthreads();                       // drains prefetch of buf[cur]
        if (k0 + 32 < K) stage(k0 + 32, cur ^ 1);   // issue next; lands during MFMA
        bf16x8 af[MF], bfr[4];
        #pragma unroll
        for (int m = 0; m < MF; ++m) af[m]  = *(const bf16x8*)&As[cur][aoff[m]];
        #pragma unroll
        for (int n = 0; n < 4; ++n)  bfr[n] = *(const bf16x8*)&Bs[cur][boff[n]];
        #pragma unroll
        for (int m = 0; m < MF; ++m)
            #pragma unroll
            for (int n = 0; n < 4; ++n)
                acc[m][n] = __builtin_amdgcn_mfma_f32_16x16x32_bf16(af[m], bfr[n], acc[m][n], 0, 0, 0);
        cur ^= 1;
    }

    const int lr4 = (l >> 4) * 4, lc = l & 15;
    #pragma unroll
    for (int m = 0; m < MF; ++m) {
        #pragma unroll
        for (int n = 0; n < 4; ++n) {
            const int col = n0 + wcol + n * 16 + lc;
            const float bv = BIAS ? bias[col] : 0.0f;
            #pragma unroll
            for (int r = 0; r < 4; ++r) {
                const int row = m0 + wrow + m * 16 + lr4 + r;
                float v = acc[m][n][r] + bv;
                if (GELU_) v = gelu_exact(v);
                if (RES)   v += res[(size_t)row * N + col];
                if (OUTBF16) ((short*)Cv)[(size_t)row * N + col] = f2bf(v);
                else         ((float*)Cv)[(size_t)row * N + col] = v;
            }
        }
    }
}

// ------------- QKV GEMM (dbuf 2-phase) with custom epilogue -------------
// cols [0,1024): Q*0.125 -> qkvb; [1024,2048): K -> qkvb; [2048,3072): V -> VT.
__global__ __launch_bounds__(256) void qkv_gemm(
    const short* __restrict__ A, const short* __restrict__ B,
    short* __restrict__ qkvb, short* __restrict__ VT, int K)
{
    __shared__ __align__(16) short As[2][128 * 32];
    __shared__ __align__(16) short Bs[2][128 * 32];
    const int t = threadIdx.x;
    const int w = t >> 6, l = t & 63;
    const int wr = w >> 1, wc = w & 1;

    const int gx = gridDim.x;
    const int nwg = gx * gridDim.y;
    const int lid = blockIdx.y * gx + blockIdx.x;
    const int swz = (lid & 7) * (nwg >> 3) + (lid >> 3);
    const int bx = swz % gx, by = swz / gx;
    const int m0 = by * 128, n0 = bx * 128;

    const short* agp0 = A + (size_t)(m0 + w * 32 + (l >> 2)) * K + (l & 3) * 8;
    const short* agp1 = agp0 + (size_t)16 * K;
    const short* bgp0 = B + (size_t)(n0 + w * 32 + (l >> 2)) * K + (l & 3) * 8;
    const short* bgp1 = bgp0 + (size_t)16 * K;

    int aoff[4], boff[4];
    #pragma unroll
    for (int m = 0; m < 4; ++m) aoff[m] = (wr * 64 + m * 16 + (l & 15)) * 32 + (l >> 4) * 8;
    #pragma unroll
    for (int n = 0; n < 4; ++n) boff[n] = (wc * 64 + n * 16 + (l & 15)) * 32 + (l >> 4) * 8;

    auto stage = [&](int k0, int buf) {
        short* ldsA = &As[buf][w * 1024];
        short* ldsB = &Bs[buf][w * 1024];
        gload_lds16(agp0 + k0, ldsA);
        gload_lds16(agp1 + k0, ldsA + 512);
        gload_lds16(bgp0 + k0, ldsB);
        gload_lds16(bgp1 + k0, ldsB + 512);
    };

    f32x4 acc[4][4] = {};
    stage(0, 0);
    int cur = 0;
    for (int k0 = 0; k0 < K; k0 += 32) {
        __syncthreads();
        if (k0 + 32 < K) stage(k0 + 32, cur ^ 1);
        bf16x8 af[4], bfr[4];
        #pragma unroll
        for (int m = 0; m < 4; ++m) af[m]  = *(const bf16x8*)&As[cur][aoff[m]];
        #pragma unroll
        for (int n = 0; n < 4; ++n) bfr[n] = *(const bf16x8*)&Bs[cur][boff[n]];
        #pragma unroll
        for (int m = 0; m < 4; ++m)
            #pragma unroll
            for (int n = 0; n < 4; ++n)
                acc[m][n] = __builtin_amdgcn_mfma_f32_16x16x32_bf16(af[m], bfr[n], acc[m][n], 0, 0, 0);
        cur ^= 1;
    }

    const int lr4 = (l >> 4) * 4, lc = l & 15;
    if (n0 < 2048) {
        const float sc = (n0 < 1024) ? 0.125f : 1.0f;
        #pragma unroll
        for (int m = 0; m < 4; ++m) {
            #pragma unroll
            for (int n = 0; n < 4; ++n) {
                const int col = n0 + wc * 64 + n * 16 + lc;
                #pragma unroll
                for (int r = 0; r < 4; ++r) {
                    const int row = m0 + wr * 64 + m * 16 + lr4 + r;
                    qkvb[(size_t)row * 2048 + col] = f2bf(acc[m][n][r] * sc);
                }
            }
        }
    } else {
        #pragma unroll
        for (int m = 0; m < 4; ++m) {
            const int row0 = m0 + wr * 64 + m * 16 + lr4;   // 4-aligned
            const int b = row0 >> 10, nseq = row0 & 1023;
            #pragma unroll
            for (int n = 0; n < 4; ++n) {
                const int c2 = n0 - 2048 + wc * 64 + n * 16 + lc;
                const int h = c2 >> 6, d = c2 & 63;
                short4 v4;
                v4.x = f2bf(acc[m][n][0]); v4.y = f2bf(acc[m][n][1]);
                v4.z = f2bf(acc[m][n][2]); v4.w = f2bf(acc[m][n][3]);
                *(short4*)&VT[(((size_t)(b * 16 + h) * 64 + d) * 1024) + nseq] = v4;
            }
        }
    }
}

// ---------------- MFMA flash attention ----------------
__global__ __launch_bounds__(256) void fattn(const short* __restrict__ qkvb,
                                             const short* __restrict__ VT,
                                             short* __restrict__ o) {
    const int bh = blockIdx.y;
    const int b = bh >> 4, h = bh & 15;
    const int q0 = blockIdx.x * 64;
    const int t = threadIdx.x, w = t >> 6, l = t & 63;

    __shared__ __align__(16) short Ks[2][64 * 64];
    __shared__ __align__(16) short Vs[2][64 * 64];
    __shared__ __align__(16) short Ps[4][1024];

    const size_t qrow = (size_t)(b * SEQ + q0 + w * 16 + (l & 15)) * 2048 + h * 64;
    bf16x8 qf[2];
    qf[0] = *(const bf16x8*)&qkvb[qrow + (l >> 4) * 8];
    qf[1] = *(const bf16x8*)&qkvb[qrow + 32 + (l >> 4) * 8];

    const int srow = l >> 3;
    const int sc16 = (l & 7) ^ (srow & 7);
    const short* Kg = qkvb + 1024 + h * 64;
    const short* Vg = VT + (size_t)bh * 64 * 1024;

    f32x4 acc[4] = {};
    float mrow[4] = {-1e30f, -1e30f, -1e30f, -1e30f};
    float lrow[4] = {0.f, 0.f, 0.f, 0.f};

    auto stage = [&](int kt, int buf) {
        const int kv0 = kt * 64;
        #pragma unroll
        for (int i = 0; i < 2; ++i) {
            const int r0 = w * 16 + i * 8;
            gload_lds16(Kg + (size_t)(b * SEQ + kv0 + r0 + srow) * 2048 + sc16 * 8,
                        &Ks[buf][r0 * 64]);
            gload_lds16(Vg + (size_t)(r0 + srow) * 1024 + kv0 + sc16 * 8,
                        &Vs[buf][r0 * 64]);
        }
    };

    stage(0, 0);
    for (int kt = 0; kt < 16; ++kt) {
        const int cur = kt & 1;
        __syncthreads();
        if (kt + 1 < 16) stage(kt + 1, cur ^ 1);

        f32x4 sacc[4];
        #pragma unroll
        for (int nt = 0; nt < 4; ++nt) {
            f32x4 z = {};
            #pragma unroll
            for (int ks = 0; ks < 2; ++ks) {
                const int row = nt * 16 + (l & 15);
                const int c16 = (ks * 4 + (l >> 4)) ^ (row & 7);
                const bf16x8 kf = *(const bf16x8*)&Ks[cur][row * 64 + c16 * 8];
                z = __builtin_amdgcn_mfma_f32_16x16x32_bf16(qf[ks], kf, z, 0, 0, 0);
            }
            sacc[nt] = z;
        }
        float tmax[4], tsum[4], fac[4];
        #pragma unroll
        for (int r = 0; r < 4; ++r)
            tmax[r] = fmaxf(fmaxf(sacc[0][r], sacc[1][r]), fmaxf(sacc[2][r], sacc[3][r]));
        #pragma unroll
        for (int off = 1; off <= 8; off <<= 1)
            #pragma unroll
            for (int r = 0; r < 4; ++r)
                tmax[r] = fmaxf(tmax[r], __shfl_xor(tmax[r], off));
        #pragma unroll
        for (int r = 0; r < 4; ++r) {
            const float nm = fmaxf(mrow[r], tmax[r]);
            fac[r] = __expf(mrow[r] - nm);
            mrow[r] = nm;
            tsum[r] = 0.0f;
        }
        #pragma unroll
        for (int nt = 0; nt < 4; ++nt) {
            #pragma unroll
            for (int r = 0; r < 4; ++r) {
                const float p = __expf(sacc[nt][r] - mrow[r]);
                tsum[r] += p;
                const int q = (l >> 4) * 4 + r;
                const int kv = nt * 16 + (l & 15);
                union { float f; uint32_t u; } cu; cu.f = p;
                Ps[w][q * 64 + (kv ^ ((q & 7) << 3))] = (short)((cu.u + 0x8000u) >> 16);
            }
        }
        #pragma unroll
        for (int off = 1; off <= 8; off <<= 1)
            #pragma unroll
            for (int r = 0; r < 4; ++r)
                tsum[r] += __shfl_xor(tsum[r], off);
        #pragma unroll
        for (int r = 0; r < 4; ++r) lrow[r] = lrow[r] * fac[r] + tsum[r];
        #pragma unroll
        for (int nt2 = 0; nt2 < 4; ++nt2)
            #pragma unroll
            for (int r = 0; r < 4; ++r)
                acc[nt2][r] *= fac[r];
        #pragma unroll
        for (int ks = 0; ks < 2; ++ks) {
            const int ql = l & 15;
            const bf16x8 pa = *(const bf16x8*)&Ps[w][ql * 64 + ((ks * 32 + (l >> 4) * 8) ^ ((ql & 7) << 3))];
            #pragma unroll
            for (int nt2 = 0; nt2 < 4; ++nt2) {
                const int row = nt2 * 16 + (l & 15);
                const int c16 = (ks * 4 + (l >> 4)) ^ (row & 7);
                const bf16x8 vf = *(const bf16x8*)&Vs[cur][row * 64 + c16 * 8];
                acc[nt2] = __builtin_amdgcn_mfma_f32_16x16x32_bf16(pa, vf, acc[nt2], 0, 0, 0);
            }
        }
    }
    #pragma unroll
    for (int r = 0; r < 4; ++r) {
        const float rcp = 1.0f / lrow[r];
        const int q = q0 + w * 16 + (l >> 4) * 4 + r;
        #pragma unroll
        for (int nt2 = 0; nt2 < 4; ++nt2) {
            const int d = nt2 * 16 + (l & 15);
            o[(size_t)(b * SEQ + q) * CDIM + h * 64 + d] = f2bf(acc[nt2][r] * rcp);
        }
    }
}

extern "C" void kernel_launch(void* const* d_in, const int* in_sizes, int n_in,
                              void* d_out, int out_size, void* d_ws, size_t ws_size,
                              hipStream_t stream) {
    const float* x      = (const float*)d_in[0];
    const float* ln1_w  = (const float*)d_in[1];
    const float* ln1_b  = (const float*)d_in[2];
    const float* qkv_w  = (const float*)d_in[3];
    const float* proj_w = (const float*)d_in[4];
    const float* proj_b = (const float*)d_in[5];
    const float* ln2_w  = (const float*)d_in[6];
    const float* ln2_b  = (const float*)d_in[7];
    const float* fc1_w  = (const float*)d_in[8];
    const float* fc1_b  = (const float*)d_in[9];
    const float* fc2_w  = (const float*)d_in[10];
    const float* fc2_b  = (const float*)d_in[11];
    float* out = (float*)d_out;

    short* ws16  = (short*)d_ws;
    short* wqkv  = ws16;
    short* wproj = ws16 + 3145728;
    short* wfc1  = ws16 + 4194304;
    short* wfc2  = ws16 + 8388608;
    char*  wsb   = (char*)d_ws;
    short* qkvb  = (short*)(wsb + (size_t)24 * 1024 * 1024);
    short* VT    = (short*)(wsb + (size_t)40 * 1024 * 1024);
    short* mlp1  = (short*)(wsb + (size_t)24 * 1024 * 1024);
    short* hbuf  = (short*)(wsb + (size_t)72 * 1024 * 1024);

    cvt_bf16_kernel<<<1536, 256, 0, stream>>>(qkv_w, wqkv);
    cvt_bf16_kernel<<< 512, 256, 0, stream>>>(proj_w, wproj);
    cvt_bf16_kernel<<<2048, 256, 0, stream>>>(fc1_w, wfc1);
    cvt_bf16_kernel<<<2048, 256, 0, stream>>>(fc2_w, wfc2);

    ln_kernel<<<MROWS, 256, 0, stream>>>(x, ln1_w, ln1_b, hbuf);
    qkv_gemm<<<dim3(24, 32), 256, 0, stream>>>(hbuf, wqkv, qkvb, VT, 1024);
    fattn<<<dim3(SEQ / 64, BATCH * NHEAD), 256, 0, stream>>>(qkvb, VT, hbuf);
    // proj: BN=64, grid 16x32 = 512 blocks
    mgemm<64,true,true,false,false><<<dim3(16, 32), 256, 0, stream>>>(
        hbuf, wproj, proj_b, x, out, MROWS, 1024, 1024);
    ln_kernel<<<MROWS, 256, 0, stream>>>(out, ln2_w, ln2_b, hbuf);
    // FC1: BN=128, grid 32x32 = 1024 blocks
    mgemm<128,true,false,true,true><<<dim3(32, 32), 256, 0, stream>>>(
        hbuf, wfc1, fc1_b, nullptr, mlp1, MROWS, 4096, 1024);
    // FC2: BN=64, grid 16x32 = 512 blocks
    mgemm<64,true,true,false,false><<<dim3(16, 32), 256, 0, stream>>>(
        mlp1, wfc2, fc2_b, out, out, MROWS, 1024, 4096);
}

// Round 7
// 252.096 us; speedup vs baseline: 8.6293x; 1.0376x over previous
//
#include <hip/hip_runtime.h>
#include <hip/hip_bf16.h>
#include <math.h>
#include <stdint.h>

#define SEQ 1024
#define CDIM 1024
#define NHEAD 16
#define HIDDEN 4096
#define BATCH 4
#define MROWS (BATCH*SEQ)   // 4096

using bf16x8 = __attribute__((ext_vector_type(8))) short;
using f32x4  = __attribute__((ext_vector_type(4))) float;

__device__ __forceinline__ short f2bf(float f) {
    union { float f; uint32_t u; } c; c.f = f;
    const uint32_t u = c.u + 0x7FFFu + ((c.u >> 16) & 1u);
    return (short)(u >> 16);
}

__device__ __forceinline__ float gelu_exact(float v) {
    return 0.5f * v * (1.0f + erff(v * 0.70710678118654752440f));
}

// async global->LDS, 16B per lane; LDS dest is wave-uniform base + lane*16
__device__ __forceinline__ void gload_lds16(const short* g, short* lds) {
    __builtin_amdgcn_global_load_lds(
        (const __attribute__((address_space(1))) void*)(uintptr_t)g,
        (__attribute__((address_space(3))) void*)(uintptr_t)lds,
        16, 0, 0);
}

// ---------------- weight fp32 -> bf16 conversion ----------------
__global__ void cvt_bf16_kernel(const float* __restrict__ in, short* __restrict__ out) {
    const size_t i = ((size_t)blockIdx.x * 256 + threadIdx.x) * 8;
    const float4 a = *(const float4*)(in + i);
    const float4 b = *(const float4*)(in + i + 4);
    bf16x8 s;
    s[0] = f2bf(a.x); s[1] = f2bf(a.y); s[2] = f2bf(a.z); s[3] = f2bf(a.w);
    s[4] = f2bf(b.x); s[5] = f2bf(b.y); s[6] = f2bf(b.z); s[7] = f2bf(b.w);
    *(bf16x8*)(out + i) = s;
}

// ---------------- LayerNorm: one block per row, bf16 output ----------------
__global__ void ln_kernel(const float* __restrict__ x, const float* __restrict__ w,
                          const float* __restrict__ b, short* __restrict__ out) {
    const int row = blockIdx.x;
    const int t = threadIdx.x;               // 256 threads
    const float4* xr = (const float4*)(x + (size_t)row * CDIM);
    float4 v = xr[t];
    float s  = v.x + v.y + v.z + v.w;
    float sq = v.x*v.x + v.y*v.y + v.z*v.z + v.w*v.w;
    #pragma unroll
    for (int off = 32; off; off >>= 1) {
        s  += __shfl_down(s, off);
        sq += __shfl_down(sq, off);
    }
    __shared__ float ss[4], ssq[4];
    const int wid = t >> 6, lane = t & 63;
    if (lane == 0) { ss[wid] = s; ssq[wid] = sq; }
    __syncthreads();
    s  = ss[0] + ss[1] + ss[2] + ss[3];
    sq = ssq[0] + ssq[1] + ssq[2] + ssq[3];
    const float mu  = s * (1.0f / CDIM);
    const float var = sq * (1.0f / CDIM) - mu * mu;
    const float rs  = rsqrtf(var + 1e-5f);
    const float4 wv = ((const float4*)w)[t];
    const float4 bv = ((const float4*)b)[t];
    short4 o;
    o.x = f2bf((v.x - mu) * rs * wv.x + bv.x);
    o.y = f2bf((v.y - mu) * rs * wv.y + bv.y);
    o.z = f2bf((v.z - mu) * rs * wv.z + bv.z);
    o.w = f2bf((v.w - mu) * rs * wv.w + bv.w);
    *(short4*)(out + (size_t)row * CDIM + t * 4) = o;
}

// ------------- bf16 MFMA GEMM, 3-buffer stage-2-ahead, counted vmcnt -----
// Per iter: vmcnt(L) [certify ktile t; newest stage may stay in flight] ->
// sched_barrier -> s_barrier -> sched_barrier -> stage(ktile t+2) ->
// ds_read buf[t%3] -> MFMA. vmcnt never drains to 0 until the last iter.
// WAR safe: stage overwrites buf last read at iter t-1; all waves' t-1 reads
// retired before they pass barrier(t) (lgkm in-order + sched_barrier pin).
template<int BN, bool BIAS, bool RES, bool GELU_, bool OUTBF16>
__global__ __launch_bounds__(256) void mgemm(
    const short* __restrict__ A, const short* __restrict__ B,
    const float* __restrict__ bias, const float* __restrict__ res,
    void* __restrict__ Cv, int M, int N, int K)
{
    constexpr int MF = (BN == 128) ? 4 : 2;   // M-frags per wave
    __shared__ __align__(16) short As[3][128 * 32];
    __shared__ __align__(16) short Bs[3][BN * 32];
    const int t = threadIdx.x;
    const int w = t >> 6, l = t & 63;

    // XCD-aware bijective swizzle
    const int gx = gridDim.x;
    const int nwg = gx * gridDim.y;
    const int lid = blockIdx.y * gx + blockIdx.x;
    const int swz = (lid & 7) * (nwg >> 3) + (lid >> 3);
    const int bx = swz % gx, by = swz / gx;
    const int m0 = by * 128, n0 = bx * BN;

    const int wrow = (BN == 128) ? (w >> 1) * 64 : w * 32;
    const int wcol = (BN == 128) ? (w & 1) * 64 : 0;

    const short* agp0 = A + (size_t)(m0 + w * 32 + (l >> 2)) * K + (l & 3) * 8;
    const short* agp1 = agp0 + (size_t)16 * K;
    const short* bgp0;
    const short* bgp1 = nullptr;
    if (BN == 128) {
        bgp0 = B + (size_t)(n0 + w * 32 + (l >> 2)) * K + (l & 3) * 8;
        bgp1 = bgp0 + (size_t)16 * K;
    } else {
        bgp0 = B + (size_t)(n0 + w * 16 + (l >> 2)) * K + (l & 3) * 8;
    }

    int aoff[MF], boff[4];
    #pragma unroll
    for (int m = 0; m < MF; ++m) aoff[m] = (wrow + m * 16 + (l & 15)) * 32 + (l >> 4) * 8;
    #pragma unroll
    for (int n = 0; n < 4; ++n)  boff[n] = (wcol + n * 16 + (l & 15)) * 32 + (l >> 4) * 8;

    auto stage = [&](int k0, int buf) {
        short* ldsA = &As[buf][w * 1024];
        gload_lds16(agp0 + k0, ldsA);
        gload_lds16(agp1 + k0, ldsA + 512);
        if (BN == 128) {
            short* ldsB = &Bs[buf][w * 1024];
            gload_lds16(bgp0 + k0, ldsB);
            gload_lds16(bgp1 + k0, ldsB + 512);
        } else {
            gload_lds16(bgp0 + k0, &Bs[buf][w * 512]);
        }
    };

    f32x4 acc[MF][4] = {};
    const int T = K / 32;
    stage(0, 0);
    stage(32, 1);
    int cur = 0;
    for (int kt = 0; kt < T; ++kt) {
        if (kt < T - 1) {
            if constexpr (BN == 128) asm volatile("s_waitcnt vmcnt(4)" ::: "memory");
            else                     asm volatile("s_waitcnt vmcnt(3)" ::: "memory");
        } else {
            asm volatile("s_waitcnt vmcnt(0)" ::: "memory");
        }
        __builtin_amdgcn_sched_barrier(0);
        __builtin_amdgcn_s_barrier();
        __builtin_amdgcn_sched_barrier(0);
        if (kt + 2 < T) {
            int nb = kt + 2; nb -= (nb >= 3) ? ((nb / 3) * 3) : 0;  // (kt+2)%3
            stage((kt + 2) * 32, nb);
        }
        bf16x8 af[MF], bfr[4];
        #pragma unroll
        for (int m = 0; m < MF; ++m) af[m]  = *(const bf16x8*)&As[cur][aoff[m]];
        #pragma unroll
        for (int n = 0; n < 4; ++n)  bfr[n] = *(const bf16x8*)&Bs[cur][boff[n]];
        #pragma unroll
        for (int m = 0; m < MF; ++m)
            #pragma unroll
            for (int n = 0; n < 4; ++n)
                acc[m][n] = __builtin_amdgcn_mfma_f32_16x16x32_bf16(af[m], bfr[n], acc[m][n], 0, 0, 0);
        cur = (cur == 2) ? 0 : cur + 1;
    }

    const int lr4 = (l >> 4) * 4, lc = l & 15;
    #pragma unroll
    for (int m = 0; m < MF; ++m) {
        #pragma unroll
        for (int n = 0; n < 4; ++n) {
            const int col = n0 + wcol + n * 16 + lc;
            const float bv = BIAS ? bias[col] : 0.0f;
            #pragma unroll
            for (int r = 0; r < 4; ++r) {
                const int row = m0 + wrow + m * 16 + lr4 + r;
                float v = acc[m][n][r] + bv;
                if (GELU_) v = gelu_exact(v);
                if (RES)   v += res[(size_t)row * N + col];
                if (OUTBF16) ((short*)Cv)[(size_t)row * N + col] = f2bf(v);
                else         ((float*)Cv)[(size_t)row * N + col] = v;
            }
        }
    }
}

// ------------- QKV GEMM (3-buffer counted-vmcnt) with custom epilogue -------------
// cols [0,1024): Q*0.125 -> qkvb; [1024,2048): K -> qkvb; [2048,3072): V -> VT.
__global__ __launch_bounds__(256) void qkv_gemm(
    const short* __restrict__ A, const short* __restrict__ B,
    short* __restrict__ qkvb, short* __restrict__ VT, int K)
{
    __shared__ __align__(16) short As[3][128 * 32];
    __shared__ __align__(16) short Bs[3][128 * 32];
    const int t = threadIdx.x;
    const int w = t >> 6, l = t & 63;
    const int wr = w >> 1, wc = w & 1;

    const int gx = gridDim.x;
    const int nwg = gx * gridDim.y;
    const int lid = blockIdx.y * gx + blockIdx.x;
    const int swz = (lid & 7) * (nwg >> 3) + (lid >> 3);
    const int bx = swz % gx, by = swz / gx;
    const int m0 = by * 128, n0 = bx * 128;

    const short* agp0 = A + (size_t)(m0 + w * 32 + (l >> 2)) * K + (l & 3) * 8;
    const short* agp1 = agp0 + (size_t)16 * K;
    const short* bgp0 = B + (size_t)(n0 + w * 32 + (l >> 2)) * K + (l & 3) * 8;
    const short* bgp1 = bgp0 + (size_t)16 * K;

    int aoff[4], boff[4];
    #pragma unroll
    for (int m = 0; m < 4; ++m) aoff[m] = (wr * 64 + m * 16 + (l & 15)) * 32 + (l >> 4) * 8;
    #pragma unroll
    for (int n = 0; n < 4; ++n) boff[n] = (wc * 64 + n * 16 + (l & 15)) * 32 + (l >> 4) * 8;

    auto stage = [&](int k0, int buf) {
        short* ldsA = &As[buf][w * 1024];
        short* ldsB = &Bs[buf][w * 1024];
        gload_lds16(agp0 + k0, ldsA);
        gload_lds16(agp1 + k0, ldsA + 512);
        gload_lds16(bgp0 + k0, ldsB);
        gload_lds16(bgp1 + k0, ldsB + 512);
    };

    f32x4 acc[4][4] = {};
    const int T = K / 32;
    stage(0, 0);
    stage(32, 1);
    int cur = 0;
    for (int kt = 0; kt < T; ++kt) {
        if (kt < T - 1) asm volatile("s_waitcnt vmcnt(4)" ::: "memory");
        else            asm volatile("s_waitcnt vmcnt(0)" ::: "memory");
        __builtin_amdgcn_sched_barrier(0);
        __builtin_amdgcn_s_barrier();
        __builtin_amdgcn_sched_barrier(0);
        if (kt + 2 < T) {
            int nb = kt + 2; nb -= (nb >= 3) ? ((nb / 3) * 3) : 0;
            stage((kt + 2) * 32, nb);
        }
        bf16x8 af[4], bfr[4];
        #pragma unroll
        for (int m = 0; m < 4; ++m) af[m]  = *(const bf16x8*)&As[cur][aoff[m]];
        #pragma unroll
        for (int n = 0; n < 4; ++n) bfr[n] = *(const bf16x8*)&Bs[cur][boff[n]];
        #pragma unroll
        for (int m = 0; m < 4; ++m)
            #pragma unroll
            for (int n = 0; n < 4; ++n)
                acc[m][n] = __builtin_amdgcn_mfma_f32_16x16x32_bf16(af[m], bfr[n], acc[m][n], 0, 0, 0);
        cur = (cur == 2) ? 0 : cur + 1;
    }

    const int lr4 = (l >> 4) * 4, lc = l & 15;
    if (n0 < 2048) {
        const float sc = (n0 < 1024) ? 0.125f : 1.0f;
        #pragma unroll
        for (int m = 0; m < 4; ++m) {
            #pragma unroll
            for (int n = 0; n < 4; ++n) {
                const int col = n0 + wc * 64 + n * 16 + lc;
                #pragma unroll
                for (int r = 0; r < 4; ++r) {
                    const int row = m0 + wr * 64 + m * 16 + lr4 + r;
                    qkvb[(size_t)row * 2048 + col] = f2bf(acc[m][n][r] * sc);
                }
            }
        }
    } else {
        #pragma unroll
        for (int m = 0; m < 4; ++m) {
            const int row0 = m0 + wr * 64 + m * 16 + lr4;   // 4-aligned
            const int b = row0 >> 10, nseq = row0 & 1023;
            #pragma unroll
            for (int n = 0; n < 4; ++n) {
                const int c2 = n0 - 2048 + wc * 64 + n * 16 + lc;
                const int h = c2 >> 6, d = c2 & 63;
                short4 v4;
                v4.x = f2bf(acc[m][n][0]); v4.y = f2bf(acc[m][n][1]);
                v4.z = f2bf(acc[m][n][2]); v4.w = f2bf(acc[m][n][3]);
                *(short4*)&VT[(((size_t)(b * 16 + h) * 64 + d) * 1024) + nseq] = v4;
            }
        }
    }
}

// ---------------- MFMA flash attention ----------------
__global__ __launch_bounds__(256) void fattn(const short* __restrict__ qkvb,
                                             const short* __restrict__ VT,
                                             short* __restrict__ o) {
    const int bh = blockIdx.y;
    const int b = bh >> 4, h = bh & 15;
    const int q0 = blockIdx.x * 64;
    const int t = threadIdx.x, w = t >> 6, l = t & 63;

    __shared__ __align__(16) short Ks[2][64 * 64];
    __shared__ __align__(16) short Vs[2][64 * 64];
    __shared__ __align__(16) short Ps[4][1024];

    const size_t qrow = (size_t)(b * SEQ + q0 + w * 16 + (l & 15)) * 2048 + h * 64;
    bf16x8 qf[2];
    qf[0] = *(const bf16x8*)&qkvb[qrow + (l >> 4) * 8];
    qf[1] = *(const bf16x8*)&qkvb[qrow + 32 + (l >> 4) * 8];

    const int srow = l >> 3;
    const int sc16 = (l & 7) ^ (srow & 7);
    const short* Kg = qkvb + 1024 + h * 64;
    const short* Vg = VT + (size_t)bh * 64 * 1024;

    f32x4 acc[4] = {};
    float mrow[4] = {-1e30f, -1e30f, -1e30f, -1e30f};
    float lrow[4] = {0.f, 0.f, 0.f, 0.f};

    auto stage = [&](int kt, int buf) {
        const int kv0 = kt * 64;
        #pragma unroll
        for (int i = 0; i < 2; ++i) {
            const int r0 = w * 16 + i * 8;
            gload_lds16(Kg + (size_t)(b * SEQ + kv0 + r0 + srow) * 2048 + sc16 * 8,
                        &Ks[buf][r0 * 64]);
            gload_lds16(Vg + (size_t)(r0 + srow) * 1024 + kv0 + sc16 * 8,
                        &Vs[buf][r0 * 64]);
        }
    };

    stage(0, 0);
    for (int kt = 0; kt < 16; ++kt) {
        const int cur = kt & 1;
        __syncthreads();
        if (kt + 1 < 16) stage(kt + 1, cur ^ 1);

        f32x4 sacc[4];
        #pragma unroll
        for (int nt = 0; nt < 4; ++nt) {
            f32x4 z = {};
            #pragma unroll
            for (int ks = 0; ks < 2; ++ks) {
                const int row = nt * 16 + (l & 15);
                const int c16 = (ks * 4 + (l >> 4)) ^ (row & 7);
                const bf16x8 kf = *(const bf16x8*)&Ks[cur][row * 64 + c16 * 8];
                z = __builtin_amdgcn_mfma_f32_16x16x32_bf16(qf[ks], kf, z, 0, 0, 0);
            }
            sacc[nt] = z;
        }
        float tmax[4], tsum[4], fac[4];
        #pragma unroll
        for (int r = 0; r < 4; ++r)
            tmax[r] = fmaxf(fmaxf(sacc[0][r], sacc[1][r]), fmaxf(sacc[2][r], sacc[3][r]));
        #pragma unroll
        for (int off = 1; off <= 8; off <<= 1)
            #pragma unroll
            for (int r = 0; r < 4; ++r)
                tmax[r] = fmaxf(tmax[r], __shfl_xor(tmax[r], off));
        #pragma unroll
        for (int r = 0; r < 4; ++r) {
            const float nm = fmaxf(mrow[r], tmax[r]);
            fac[r] = __expf(mrow[r] - nm);
            mrow[r] = nm;
            tsum[r] = 0.0f;
        }
        #pragma unroll
        for (int nt = 0; nt < 4; ++nt) {
            #pragma unroll
            for (int r = 0; r < 4; ++r) {
                const float p = __expf(sacc[nt][r] - mrow[r]);
                tsum[r] += p;
                const int q = (l >> 4) * 4 + r;
                const int kv = nt * 16 + (l & 15);
                union { float f; uint32_t u; } cu; cu.f = p;
                Ps[w][q * 64 + (kv ^ ((q & 7) << 3))] = (short)((cu.u + 0x8000u) >> 16);
            }
        }
        #pragma unroll
        for (int off = 1; off <= 8; off <<= 1)
            #pragma unroll
            for (int r = 0; r < 4; ++r)
                tsum[r] += __shfl_xor(tsum[r], off);
        #pragma unroll
        for (int r = 0; r < 4; ++r) lrow[r] = lrow[r] * fac[r] + tsum[r];
        #pragma unroll
        for (int nt2 = 0; nt2 < 4; ++nt2)
            #pragma unroll
            for (int r = 0; r < 4; ++r)
                acc[nt2][r] *= fac[r];
        #pragma unroll
        for (int ks = 0; ks < 2; ++ks) {
            const int ql = l & 15;
            const bf16x8 pa = *(const bf16x8*)&Ps[w][ql * 64 + ((ks * 32 + (l >> 4) * 8) ^ ((ql & 7) << 3))];
            #pragma unroll
            for (int nt2 = 0; nt2 < 4; ++nt2) {
                const int row = nt2 * 16 + (l & 15);
                const int c16 = (ks * 4 + (l >> 4)) ^ (row & 7);
                const bf16x8 vf = *(const bf16x8*)&Vs[cur][row * 64 + c16 * 8];
                acc[nt2] = __builtin_amdgcn_mfma_f32_16x16x32_bf16(pa, vf, acc[nt2], 0, 0, 0);
            }
        }
    }
    #pragma unroll
    for (int r = 0; r < 4; ++r) {
        const float rcp = 1.0f / lrow[r];
        const int q = q0 + w * 16 + (l >> 4) * 4 + r;
        #pragma unroll
        for (int nt2 = 0; nt2 < 4; ++nt2) {
            const int d = nt2 * 16 + (l & 15);
            o[(size_t)(b * SEQ + q) * CDIM + h * 64 + d] = f2bf(acc[nt2][r] * rcp);
        }
    }
}

extern "C" void kernel_launch(void* const* d_in, const int* in_sizes, int n_in,
                              void* d_out, int out_size, void* d_ws, size_t ws_size,
                              hipStream_t stream) {
    const float* x      = (const float*)d_in[0];
    const float* ln1_w  = (const float*)d_in[1];
    const float* ln1_b  = (const float*)d_in[2];
    const float* qkv_w  = (const float*)d_in[3];
    const float* proj_w = (const float*)d_in[4];
    const float* proj_b = (const float*)d_in[5];
    const float* ln2_w  = (const float*)d_in[6];
    const float* ln2_b  = (const float*)d_in[7];
    const float* fc1_w  = (const float*)d_in[8];
    const float* fc1_b  = (const float*)d_in[9];
    const float* fc2_w  = (const float*)d_in[10];
    const float* fc2_b  = (const float*)d_in[11];
    float* out = (float*)d_out;

    short* ws16  = (short*)d_ws;
    short* wqkv  = ws16;
    short* wproj = ws16 + 3145728;
    short* wfc1  = ws16 + 4194304;
    short* wfc2  = ws16 + 8388608;
    char*  wsb   = (char*)d_ws;
    short* qkvb  = (short*)(wsb + (size_t)24 * 1024 * 1024);
    short* VT    = (short*)(wsb + (size_t)40 * 1024 * 1024);
    short* mlp1  = (short*)(wsb + (size_t)24 * 1024 * 1024);
    short* hbuf  = (short*)(wsb + (size_t)72 * 1024 * 1024);

    cvt_bf16_kernel<<<1536, 256, 0, stream>>>(qkv_w, wqkv);
    cvt_bf16_kernel<<< 512, 256, 0, stream>>>(proj_w, wproj);
    cvt_bf16_kernel<<<2048, 256, 0, stream>>>(fc1_w, wfc1);
    cvt_bf16_kernel<<<2048, 256, 0, stream>>>(fc2_w, wfc2);

    ln_kernel<<<MROWS, 256, 0, stream>>>(x, ln1_w, ln1_b, hbuf);
    qkv_gemm<<<dim3(24, 32), 256, 0, stream>>>(hbuf, wqkv, qkvb, VT, 1024);
    fattn<<<dim3(SEQ / 64, BATCH * NHEAD), 256, 0, stream>>>(qkvb, VT, hbuf);
    // proj: BN=64, grid 16x32 = 512 blocks
    mgemm<64,true,true,false,false><<<dim3(16, 32), 256, 0, stream>>>(
        hbuf, wproj, proj_b, x, out, MROWS, 1024, 1024);
    ln_kernel<<<MROWS, 256, 0, stream>>>(out, ln2_w, ln2_b, hbuf);
    // FC1: BN=128, grid 32x32 = 1024 blocks
    mgemm<128,true,false,true,true><<<dim3(32, 32), 256, 0, stream>>>(
        hbuf, wfc1, fc1_b, nullptr, mlp1, MROWS, 4096, 1024);
    // FC2: BN=64, grid 16x32 = 512 blocks
    mgemm<64,true,true,false,false><<<dim3(16, 32), 256, 0, stream>>>(
        mlp1, wfc2, fc2_b, out, out, MROWS, 1024, 4096);
}

// Round 8
// 247.294 us; speedup vs baseline: 8.7969x; 1.0194x over previous
//
#include <hip/hip_runtime.h>
#include <hip/hip_bf16.h>
#include <math.h>
#include <stdint.h>

#define SEQ 1024
#define CDIM 1024
#define NHEAD 16
#define HIDDEN 4096
#define BATCH 4
#define MROWS (BATCH*SEQ)   // 4096

using bf16x8 = __attribute__((ext_vector_type(8))) short;
using f32x4  = __attribute__((ext_vector_type(4))) float;

__device__ __forceinline__ short f2bf(float f) {
    union { float f; uint32_t u; } c; c.f = f;
    const uint32_t u = c.u + 0x7FFFu + ((c.u >> 16) & 1u);
    return (short)(u >> 16);
}

__device__ __forceinline__ float gelu_exact(float v) {
    return 0.5f * v * (1.0f + erff(v * 0.70710678118654752440f));
}

// async global->LDS, 16B per lane; LDS dest is wave-uniform base + lane*16
__device__ __forceinline__ void gload_lds16(const short* g, short* lds) {
    __builtin_amdgcn_global_load_lds(
        (const __attribute__((address_space(1))) void*)(uintptr_t)g,
        (__attribute__((address_space(3))) void*)(uintptr_t)lds,
        16, 0, 0);
}

// ---------------- weight fp32 -> bf16 conversion ----------------
__global__ void cvt_bf16_kernel(const float* __restrict__ in, short* __restrict__ out) {
    const size_t i = ((size_t)blockIdx.x * 256 + threadIdx.x) * 8;
    const float4 a = *(const float4*)(in + i);
    const float4 b = *(const float4*)(in + i + 4);
    bf16x8 s;
    s[0] = f2bf(a.x); s[1] = f2bf(a.y); s[2] = f2bf(a.z); s[3] = f2bf(a.w);
    s[4] = f2bf(b.x); s[5] = f2bf(b.y); s[6] = f2bf(b.z); s[7] = f2bf(b.w);
    *(bf16x8*)(out + i) = s;
}

// ---------------- LayerNorm: one block per row, bf16 output ----------------
__global__ void ln_kernel(const float* __restrict__ x, const float* __restrict__ w,
                          const float* __restrict__ b, short* __restrict__ out) {
    const int row = blockIdx.x;
    const int t = threadIdx.x;               // 256 threads
    const float4* xr = (const float4*)(x + (size_t)row * CDIM);
    float4 v = xr[t];
    float s  = v.x + v.y + v.z + v.w;
    float sq = v.x*v.x + v.y*v.y + v.z*v.z + v.w*v.w;
    #pragma unroll
    for (int off = 32; off; off >>= 1) {
        s  += __shfl_down(s, off);
        sq += __shfl_down(sq, off);
    }
    __shared__ float ss[4], ssq[4];
    const int wid = t >> 6, lane = t & 63;
    if (lane == 0) { ss[wid] = s; ssq[wid] = sq; }
    __syncthreads();
    s  = ss[0] + ss[1] + ss[2] + ss[3];
    sq = ssq[0] + ssq[1] + ssq[2] + ssq[3];
    const float mu  = s * (1.0f / CDIM);
    const float var = sq * (1.0f / CDIM) - mu * mu;
    const float rs  = rsqrtf(var + 1e-5f);
    const float4 wv = ((const float4*)w)[t];
    const float4 bv = ((const float4*)b)[t];
    short4 o;
    o.x = f2bf((v.x - mu) * rs * wv.x + bv.x);
    o.y = f2bf((v.y - mu) * rs * wv.y + bv.y);
    o.z = f2bf((v.z - mu) * rs * wv.z + bv.z);
    o.w = f2bf((v.w - mu) * rs * wv.w + bv.w);
    *(short4*)(out + (size_t)row * CDIM + t * 4) = o;
}

// ============ 256x256 8-phase MFMA GEMM (T2+T3+T4+T5), 512 threads ============
// C[M,N] = A[M,K] B[N,K]^T. Grid must be 16x16 (M=N=4096). BK=64, 8 waves 2Mx4N,
// wave output 128x64 (8x4 frags). LDS 128KB: As/Bs[2][256*64] bf16, swizzle
// k8 ^= (row&7) on both write-source and read (rule 21; 2-way conflicts max).
// Per K-tile, 4 phases: {stage 1 half-tile | ds_read quad | bar | 16 MFMA | bar};
// tile-boundary vmcnt(0) certifies next tile after a full tile of overlap.
template<bool BIAS, bool RES, bool GELU_, bool OUTBF16>
__global__ __launch_bounds__(512) void gemm8p(
    const short* __restrict__ A, const short* __restrict__ B,
    const float* __restrict__ bias, const float* __restrict__ res,
    void* __restrict__ Cv, int M, int N, int K)
{
    __shared__ __align__(16) short As[2][256 * 64];
    __shared__ __align__(16) short Bs[2][256 * 64];
    const int t = threadIdx.x;
    const int w = t >> 6, l = t & 63;
    const int wm = w >> 2, wn = w & 3;

    // 2D XCD chunking for 16x16 grid: XCD gets a 4(by) x 8(bx) tile block.
    const int lid = blockIdx.y * gridDim.x + blockIdx.x;
    const int xcd = lid & 7, c = lid >> 3;
    const int by = (xcd >> 1) * 4 + (c >> 3);
    const int bx = (xcd & 1) * 8 + (c & 7);
    const int m0 = by * 256, n0 = bx * 256;

    // staging: thread t covers row (h*128 + j*64 + (t>>3)), k8 slot t&7,
    // source pre-swizzled: k8src = (t&7) ^ (row&7); row&7 == (t>>3)&7.
    const int trow = t >> 3;
    const int k8s = ((t & 7) ^ (trow & 7)) * 8;
    const short* Ag = A + (size_t)(m0 + trow) * K + k8s;
    const short* Bg = B + (size_t)(n0 + trow) * K + k8s;

    // frag read offsets (swizzled): addr = row*64 + ((ks*4+g)^(row&7))*8
    const int fr = l & 15, g = l >> 4;
    const int sw = fr & 7;
    const int ak0 = (g ^ sw) * 8;
    const int ak1 = ((4 + g) ^ sw) * 8;
    int aoff[8], boff[4];
    #pragma unroll
    for (int mf = 0; mf < 8; ++mf) aoff[mf] = (wm * 128 + mf * 16 + fr) * 64;
    #pragma unroll
    for (int nf = 0; nf < 4; ++nf) boff[nf] = (wn * 64 + nf * 16 + fr) * 64;

    f32x4 acc[8][4] = {};

#define STAGE8(Gb, LDSb, kt, h)                                             \
    {                                                                       \
        gload_lds16((Gb) + (size_t)((h) * 128) * K + (kt) * 64,             \
                    (LDSb) + ((h) * 128 + w * 8) * 64);                     \
        gload_lds16((Gb) + (size_t)((h) * 128 + 64) * K + (kt) * 64,        \
                    (LDSb) + ((h) * 128 + 64 + w * 8) * 64);                \
    }

    // prologue: stage tile 0 fully, drain, barrier
    STAGE8(Ag, As[0], 0, 0); STAGE8(Ag, As[0], 0, 1);
    STAGE8(Bg, Bs[0], 0, 0); STAGE8(Bg, Bs[0], 0, 1);
    asm volatile("s_waitcnt vmcnt(0)" ::: "memory");
    __builtin_amdgcn_s_barrier();

    const int T = K / 64;
    for (int kt = 0; kt < T; ++kt) {
        short* curA = &As[kt & 1][0];
        short* curB = &Bs[kt & 1][0];
        short* nxtA = &As[(kt & 1) ^ 1][0];
        short* nxtB = &Bs[(kt & 1) ^ 1][0];
        const bool pre = (kt + 1 < T);
        bf16x8 bfr[4], af[4];

        // ---- phase 1: stage A-h0(next); read B(ks0)+A[0-3](ks0); MFMA ----
        if (pre) STAGE8(Ag, nxtA, kt + 1, 0);
        #pragma unroll
        for (int nf = 0; nf < 4; ++nf) bfr[nf] = *(const bf16x8*)&curB[boff[nf] + ak0];
        #pragma unroll
        for (int mf = 0; mf < 4; ++mf) af[mf] = *(const bf16x8*)&curA[aoff[mf] + ak0];
        __builtin_amdgcn_s_barrier();
        __builtin_amdgcn_s_setprio(1);
        #pragma unroll
        for (int mf = 0; mf < 4; ++mf)
            #pragma unroll
            for (int nf = 0; nf < 4; ++nf)
                acc[mf][nf] = __builtin_amdgcn_mfma_f32_16x16x32_bf16(af[mf], bfr[nf], acc[mf][nf], 0, 0, 0);
        __builtin_amdgcn_s_setprio(0);
        __builtin_amdgcn_s_barrier();

        // ---- phase 2: stage A-h1(next); read A[4-7](ks0); MFMA ----
        if (pre) STAGE8(Ag, nxtA, kt + 1, 1);
        #pragma unroll
        for (int mf = 0; mf < 4; ++mf) af[mf] = *(const bf16x8*)&curA[aoff[4 + mf] + ak0];
        __builtin_amdgcn_s_barrier();
        __builtin_amdgcn_s_setprio(1);
        #pragma unroll
        for (int mf = 0; mf < 4; ++mf)
            #pragma unroll
            for (int nf = 0; nf < 4; ++nf)
                acc[4 + mf][nf] = __builtin_amdgcn_mfma_f32_16x16x32_bf16(af[mf], bfr[nf], acc[4 + mf][nf], 0, 0, 0);
        __builtin_amdgcn_s_setprio(0);
        __builtin_amdgcn_s_barrier();

        // ---- phase 3: stage B-h0(next); read B(ks1)+A[0-3](ks1); MFMA ----
        if (pre) STAGE8(Bg, nxtB, kt + 1, 0);
        #pragma unroll
        for (int nf = 0; nf < 4; ++nf) bfr[nf] = *(const bf16x8*)&curB[boff[nf] + ak1];
        #pragma unroll
        for (int mf = 0; mf < 4; ++mf) af[mf] = *(const bf16x8*)&curA[aoff[mf] + ak1];
        __builtin_amdgcn_s_barrier();
        __builtin_amdgcn_s_setprio(1);
        #pragma unroll
        for (int mf = 0; mf < 4; ++mf)
            #pragma unroll
            for (int nf = 0; nf < 4; ++nf)
                acc[mf][nf] = __builtin_amdgcn_mfma_f32_16x16x32_bf16(af[mf], bfr[nf], acc[mf][nf], 0, 0, 0);
        __builtin_amdgcn_s_setprio(0);
        __builtin_amdgcn_s_barrier();

        // ---- phase 4: stage B-h1(next); read A[4-7](ks1); MFMA; vmcnt(0); bar ----
        if (pre) STAGE8(Bg, nxtB, kt + 1, 1);
        #pragma unroll
        for (int mf = 0; mf < 4; ++mf) af[mf] = *(const bf16x8*)&curA[aoff[4 + mf] + ak1];
        __builtin_amdgcn_s_barrier();
        __builtin_amdgcn_s_setprio(1);
        #pragma unroll
        for (int mf = 0; mf < 4; ++mf)
            #pragma unroll
            for (int nf = 0; nf < 4; ++nf)
                acc[4 + mf][nf] = __builtin_amdgcn_mfma_f32_16x16x32_bf16(af[mf], bfr[nf], acc[4 + mf][nf], 0, 0, 0);
        __builtin_amdgcn_s_setprio(0);
        asm volatile("s_waitcnt vmcnt(0)" ::: "memory");   // next tile fully landed
        __builtin_amdgcn_s_barrier();
    }
#undef STAGE8

    const int lr4 = (l >> 4) * 4, lc = l & 15;
    #pragma unroll
    for (int mf = 0; mf < 8; ++mf) {
        #pragma unroll
        for (int nf = 0; nf < 4; ++nf) {
            const int col = n0 + wn * 64 + nf * 16 + lc;
            const float bv = BIAS ? bias[col] : 0.0f;
            #pragma unroll
            for (int r = 0; r < 4; ++r) {
                const int row = m0 + wm * 128 + mf * 16 + lr4 + r;
                float v = acc[mf][nf][r] + bv;
                if (GELU_) v = gelu_exact(v);
                if (RES)   v += res[(size_t)row * N + col];
                if (OUTBF16) ((short*)Cv)[(size_t)row * N + col] = f2bf(v);
                else         ((float*)Cv)[(size_t)row * N + col] = v;
            }
        }
    }
}

// ------------- bf16 MFMA GEMM, 3-buffer stage-2-ahead, counted vmcnt -----
// Now with LDS swizzle: k8' = k8 ^ ((row>>1)&3) (2-way max on 64B rows).
template<int BN, bool BIAS, bool RES, bool GELU_, bool OUTBF16>
__global__ __launch_bounds__(256) void mgemm(
    const short* __restrict__ A, const short* __restrict__ B,
    const float* __restrict__ bias, const float* __restrict__ res,
    void* __restrict__ Cv, int M, int N, int K)
{
    constexpr int MF = (BN == 128) ? 4 : 2;   // M-frags per wave
    __shared__ __align__(16) short As[3][128 * 32];
    __shared__ __align__(16) short Bs[3][BN * 32];
    const int t = threadIdx.x;
    const int w = t >> 6, l = t & 63;

    // XCD-aware bijective swizzle
    const int gx = gridDim.x;
    const int nwg = gx * gridDim.y;
    const int lid = blockIdx.y * gx + blockIdx.x;
    const int swzb = (lid & 7) * (nwg >> 3) + (lid >> 3);
    const int bx = swzb % gx, by = swzb / gx;
    const int m0 = by * 128, n0 = bx * BN;

    const int wrow = (BN == 128) ? (w >> 1) * 64 : w * 32;
    const int wcol = (BN == 128) ? (w & 1) * 64 : 0;

    // staging source pre-swizzle: k8src = (l&3) ^ ((l>>3)&3)  (row = l>>2)
    const int sk8 = ((l & 3) ^ ((l >> 3) & 3)) * 8;
    const short* agp0 = A + (size_t)(m0 + w * 32 + (l >> 2)) * K + sk8;
    const short* agp1 = agp0 + (size_t)16 * K;
    const short* bgp0;
    const short* bgp1 = nullptr;
    if (BN == 128) {
        bgp0 = B + (size_t)(n0 + w * 32 + (l >> 2)) * K + sk8;
        bgp1 = bgp0 + (size_t)16 * K;
    } else {
        bgp0 = B + (size_t)(n0 + w * 16 + (l >> 2)) * K + sk8;
    }

    const int fr = l & 15;
    const int rsw = (fr >> 1) & 3;
    int aoff[MF], boff[4];
    #pragma unroll
    for (int m = 0; m < MF; ++m) aoff[m] = (wrow + m * 16 + fr) * 32 + ((l >> 4) ^ rsw) * 8;
    #pragma unroll
    for (int n = 0; n < 4; ++n)  boff[n] = (wcol + n * 16 + fr) * 32 + ((l >> 4) ^ rsw) * 8;

    auto stage = [&](int k0, int buf) {
        short* ldsA = &As[buf][w * 1024];
        gload_lds16(agp0 + k0, ldsA);
        gload_lds16(agp1 + k0, ldsA + 512);
        if (BN == 128) {
            short* ldsB = &Bs[buf][w * 1024];
            gload_lds16(bgp0 + k0, ldsB);
            gload_lds16(bgp1 + k0, ldsB + 512);
        } else {
            gload_lds16(bgp0 + k0, &Bs[buf][w * 512]);
        }
    };

    f32x4 acc[MF][4] = {};
    const int T = K / 32;
    stage(0, 0);
    stage(32, 1);
    int cur = 0;
    for (int kt = 0; kt < T; ++kt) {
        if (kt < T - 1) {
            if constexpr (BN == 128) asm volatile("s_waitcnt vmcnt(4)" ::: "memory");
            else                     asm volatile("s_waitcnt vmcnt(3)" ::: "memory");
        } else {
            asm volatile("s_waitcnt vmcnt(0)" ::: "memory");
        }
        __builtin_amdgcn_sched_barrier(0);
        __builtin_amdgcn_s_barrier();
        __builtin_amdgcn_sched_barrier(0);
        if (kt + 2 < T) {
            int nb = kt + 2; nb -= (nb >= 3) ? ((nb / 3) * 3) : 0;  // (kt+2)%3
            stage((kt + 2) * 32, nb);
        }
        bf16x8 af[MF], bfr[4];
        #pragma unroll
        for (int m = 0; m < MF; ++m) af[m]  = *(const bf16x8*)&As[cur][aoff[m]];
        #pragma unroll
        for (int n = 0; n < 4; ++n)  bfr[n] = *(const bf16x8*)&Bs[cur][boff[n]];
        #pragma unroll
        for (int m = 0; m < MF; ++m)
            #pragma unroll
            for (int n = 0; n < 4; ++n)
                acc[m][n] = __builtin_amdgcn_mfma_f32_16x16x32_bf16(af[m], bfr[n], acc[m][n], 0, 0, 0);
        cur = (cur == 2) ? 0 : cur + 1;
    }

    const int lr4 = (l >> 4) * 4, lc = l & 15;
    #pragma unroll
    for (int m = 0; m < MF; ++m) {
        #pragma unroll
        for (int n = 0; n < 4; ++n) {
            const int col = n0 + wcol + n * 16 + lc;
            const float bv = BIAS ? bias[col] : 0.0f;
            #pragma unroll
            for (int r = 0; r < 4; ++r) {
                const int row = m0 + wrow + m * 16 + lr4 + r;
                float v = acc[m][n][r] + bv;
                if (GELU_) v = gelu_exact(v);
                if (RES)   v += res[(size_t)row * N + col];
                if (OUTBF16) ((short*)Cv)[(size_t)row * N + col] = f2bf(v);
                else         ((float*)Cv)[(size_t)row * N + col] = v;
            }
        }
    }
}

// ------------- QKV GEMM (3-buffer counted-vmcnt, swizzled LDS) -------------
// cols [0,1024): Q*0.125 -> qkvb; [1024,2048): K -> qkvb; [2048,3072): V -> VT.
__global__ __launch_bounds__(256) void qkv_gemm(
    const short* __restrict__ A, const short* __restrict__ B,
    short* __restrict__ qkvb, short* __restrict__ VT, int K)
{
    __shared__ __align__(16) short As[3][128 * 32];
    __shared__ __align__(16) short Bs[3][128 * 32];
    const int t = threadIdx.x;
    const int w = t >> 6, l = t & 63;
    const int wr = w >> 1, wc = w & 1;

    const int gx = gridDim.x;
    const int nwg = gx * gridDim.y;
    const int lid = blockIdx.y * gx + blockIdx.x;
    const int swzb = (lid & 7) * (nwg >> 3) + (lid >> 3);
    const int bx = swzb % gx, by = swzb / gx;
    const int m0 = by * 128, n0 = bx * 128;

    const int sk8 = ((l & 3) ^ ((l >> 3) & 3)) * 8;
    const short* agp0 = A + (size_t)(m0 + w * 32 + (l >> 2)) * K + sk8;
    const short* agp1 = agp0 + (size_t)16 * K;
    const short* bgp0 = B + (size_t)(n0 + w * 32 + (l >> 2)) * K + sk8;
    const short* bgp1 = bgp0 + (size_t)16 * K;

    const int fr = l & 15;
    const int rsw = (fr >> 1) & 3;
    int aoff[4], boff[4];
    #pragma unroll
    for (int m = 0; m < 4; ++m) aoff[m] = (wr * 64 + m * 16 + fr) * 32 + ((l >> 4) ^ rsw) * 8;
    #pragma unroll
    for (int n = 0; n < 4; ++n) boff[n] = (wc * 64 + n * 16 + fr) * 32 + ((l >> 4) ^ rsw) * 8;

    auto stage = [&](int k0, int buf) {
        short* ldsA = &As[buf][w * 1024];
        short* ldsB = &Bs[buf][w * 1024];
        gload_lds16(agp0 + k0, ldsA);
        gload_lds16(agp1 + k0, ldsA + 512);
        gload_lds16(bgp0 + k0, ldsB);
        gload_lds16(bgp1 + k0, ldsB + 512);
    };

    f32x4 acc[4][4] = {};
    const int T = K / 32;
    stage(0, 0);
    stage(32, 1);
    int cur = 0;
    for (int kt = 0; kt < T; ++kt) {
        if (kt < T - 1) asm volatile("s_waitcnt vmcnt(4)" ::: "memory");
        else            asm volatile("s_waitcnt vmcnt(0)" ::: "memory");
        __builtin_amdgcn_sched_barrier(0);
        __builtin_amdgcn_s_barrier();
        __builtin_amdgcn_sched_barrier(0);
        if (kt + 2 < T) {
            int nb = kt + 2; nb -= (nb >= 3) ? ((nb / 3) * 3) : 0;
            stage((kt + 2) * 32, nb);
        }
        bf16x8 af[4], bfr[4];
        #pragma unroll
        for (int m = 0; m < 4; ++m) af[m]  = *(const bf16x8*)&As[cur][aoff[m]];
        #pragma unroll
        for (int n = 0; n < 4; ++n) bfr[n] = *(const bf16x8*)&Bs[cur][boff[n]];
        #pragma unroll
        for (int m = 0; m < 4; ++m)
            #pragma unroll
            for (int n = 0; n < 4; ++n)
                acc[m][n] = __builtin_amdgcn_mfma_f32_16x16x32_bf16(af[m], bfr[n], acc[m][n], 0, 0, 0);
        cur = (cur == 2) ? 0 : cur + 1;
    }

    const int lr4 = (l >> 4) * 4, lc = l & 15;
    if (n0 < 2048) {
        const float sc = (n0 < 1024) ? 0.125f : 1.0f;
        #pragma unroll
        for (int m = 0; m < 4; ++m) {
            #pragma unroll
            for (int n = 0; n < 4; ++n) {
                const int col = n0 + wc * 64 + n * 16 + lc;
                #pragma unroll
                for (int r = 0; r < 4; ++r) {
                    const int row = m0 + wr * 64 + m * 16 + lr4 + r;
                    qkvb[(size_t)row * 2048 + col] = f2bf(acc[m][n][r] * sc);
                }
            }
        }
    } else {
        #pragma unroll
        for (int m = 0; m < 4; ++m) {
            const int row0 = m0 + wr * 64 + m * 16 + lr4;   // 4-aligned
            const int b = row0 >> 10, nseq = row0 & 1023;
            #pragma unroll
            for (int n = 0; n < 4; ++n) {
                const int c2 = n0 - 2048 + wc * 64 + n * 16 + lc;
                const int h = c2 >> 6, d = c2 & 63;
                short4 v4;
                v4.x = f2bf(acc[m][n][0]); v4.y = f2bf(acc[m][n][1]);
                v4.z = f2bf(acc[m][n][2]); v4.w = f2bf(acc[m][n][3]);
                *(short4*)&VT[(((size_t)(b * 16 + h) * 64 + d) * 1024) + nseq] = v4;
            }
        }
    }
}

// ---------------- MFMA flash attention ----------------
__global__ __launch_bounds__(256) void fattn(const short* __restrict__ qkvb,
                                             const short* __restrict__ VT,
                                             short* __restrict__ o) {
    const int bh = blockIdx.y;
    const int b = bh >> 4, h = bh & 15;
    const int q0 = blockIdx.x * 64;
    const int t = threadIdx.x, w = t >> 6, l = t & 63;

    __shared__ __align__(16) short Ks[2][64 * 64];
    __shared__ __align__(16) short Vs[2][64 * 64];
    __shared__ __align__(16) short Ps[4][1024];

    const size_t qrow = (size_t)(b * SEQ + q0 + w * 16 + (l & 15)) * 2048 + h * 64;
    bf16x8 qf[2];
    qf[0] = *(const bf16x8*)&qkvb[qrow + (l >> 4) * 8];
    qf[1] = *(const bf16x8*)&qkvb[qrow + 32 + (l >> 4) * 8];

    const int srow = l >> 3;
    const int sc16 = (l & 7) ^ (srow & 7);
    const short* Kg = qkvb + 1024 + h * 64;
    const short* Vg = VT + (size_t)bh * 64 * 1024;

    f32x4 acc[4] = {};
    float mrow[4] = {-1e30f, -1e30f, -1e30f, -1e30f};
    float lrow[4] = {0.f, 0.f, 0.f, 0.f};

    auto stage = [&](int kt, int buf) {
        const int kv0 = kt * 64;
        #pragma unroll
        for (int i = 0; i < 2; ++i) {
            const int r0 = w * 16 + i * 8;
            gload_lds16(Kg + (size_t)(b * SEQ + kv0 + r0 + srow) * 2048 + sc16 * 8,
                        &Ks[buf][r0 * 64]);
            gload_lds16(Vg + (size_t)(r0 + srow) * 1024 + kv0 + sc16 * 8,
                        &Vs[buf][r0 * 64]);
        }
    };

    stage(0, 0);
    for (int kt = 0; kt < 16; ++kt) {
        const int cur = kt & 1;
        __syncthreads();
        if (kt + 1 < 16) stage(kt + 1, cur ^ 1);

        f32x4 sacc[4];
        #pragma unroll
        for (int nt = 0; nt < 4; ++nt) {
            f32x4 z = {};
            #pragma unroll
            for (int ks = 0; ks < 2; ++ks) {
                const int row = nt * 16 + (l & 15);
                const int c16 = (ks * 4 + (l >> 4)) ^ (row & 7);
                const bf16x8 kf = *(const bf16x8*)&Ks[cur][row * 64 + c16 * 8];
                z = __builtin_amdgcn_mfma_f32_16x16x32_bf16(qf[ks], kf, z, 0, 0, 0);
            }
            sacc[nt] = z;
        }
        float tmax[4], tsum[4], fac[4];
        #pragma unroll
        for (int r = 0; r < 4; ++r)
            tmax[r] = fmaxf(fmaxf(sacc[0][r], sacc[1][r]), fmaxf(sacc[2][r], sacc[3][r]));
        #pragma unroll
        for (int off = 1; off <= 8; off <<= 1)
            #pragma unroll
            for (int r = 0; r < 4; ++r)
                tmax[r] = fmaxf(tmax[r], __shfl_xor(tmax[r], off));
        #pragma unroll
        for (int r = 0; r < 4; ++r) {
            const float nm = fmaxf(mrow[r], tmax[r]);
            fac[r] = __expf(mrow[r] - nm);
            mrow[r] = nm;
            tsum[r] = 0.0f;
        }
        #pragma unroll
        for (int nt = 0; nt < 4; ++nt) {
            #pragma unroll
            for (int r = 0; r < 4; ++r) {
                const float p = __expf(sacc[nt][r] - mrow[r]);
                tsum[r] += p;
                const int q = (l >> 4) * 4 + r;
                const int kv = nt * 16 + (l & 15);
                union { float f; uint32_t u; } cu; cu.f = p;
                Ps[w][q * 64 + (kv ^ ((q & 7) << 3))] = (short)((cu.u + 0x8000u) >> 16);
            }
        }
        #pragma unroll
        for (int off = 1; off <= 8; off <<= 1)
            #pragma unroll
            for (int r = 0; r < 4; ++r)
                tsum[r] += __shfl_xor(tsum[r], off);
        #pragma unroll
        for (int r = 0; r < 4; ++r) lrow[r] = lrow[r] * fac[r] + tsum[r];
        #pragma unroll
        for (int nt2 = 0; nt2 < 4; ++nt2)
            #pragma unroll
            for (int r = 0; r < 4; ++r)
                acc[nt2][r] *= fac[r];
        #pragma unroll
        for (int ks = 0; ks < 2; ++ks) {
            const int ql = l & 15;
            const bf16x8 pa = *(const bf16x8*)&Ps[w][ql * 64 + ((ks * 32 + (l >> 4) * 8) ^ ((ql & 7) << 3))];
            #pragma unroll
            for (int nt2 = 0; nt2 < 4; ++nt2) {
                const int row = nt2 * 16 + (l & 15);
                const int c16 = (ks * 4 + (l >> 4)) ^ (row & 7);
                const bf16x8 vf = *(const bf16x8*)&Vs[cur][row * 64 + c16 * 8];
                acc[nt2] = __builtin_amdgcn_mfma_f32_16x16x32_bf16(pa, vf, acc[nt2], 0, 0, 0);
            }
        }
    }
    #pragma unroll
    for (int r = 0; r < 4; ++r) {
        const float rcp = 1.0f / lrow[r];
        const int q = q0 + w * 16 + (l >> 4) * 4 + r;
        #pragma unroll
        for (int nt2 = 0; nt2 < 4; ++nt2) {
            const int d = nt2 * 16 + (l & 15);
            o[(size_t)(b * SEQ + q) * CDIM + h * 64 + d] = f2bf(acc[nt2][r] * rcp);
        }
    }
}

extern "C" void kernel_launch(void* const* d_in, const int* in_sizes, int n_in,
                              void* d_out, int out_size, void* d_ws, size_t ws_size,
                              hipStream_t stream) {
    const float* x      = (const float*)d_in[0];
    const float* ln1_w  = (const float*)d_in[1];
    const float* ln1_b  = (const float*)d_in[2];
    const float* qkv_w  = (const float*)d_in[3];
    const float* proj_w = (const float*)d_in[4];
    const float* proj_b = (const float*)d_in[5];
    const float* ln2_w  = (const float*)d_in[6];
    const float* ln2_b  = (const float*)d_in[7];
    const float* fc1_w  = (const float*)d_in[8];
    const float* fc1_b  = (const float*)d_in[9];
    const float* fc2_w  = (const float*)d_in[10];
    const float* fc2_b  = (const float*)d_in[11];
    float* out = (float*)d_out;

    short* ws16  = (short*)d_ws;
    short* wqkv  = ws16;
    short* wproj = ws16 + 3145728;
    short* wfc1  = ws16 + 4194304;
    short* wfc2  = ws16 + 8388608;
    char*  wsb   = (char*)d_ws;
    short* qkvb  = (short*)(wsb + (size_t)24 * 1024 * 1024);
    short* VT    = (short*)(wsb + (size_t)40 * 1024 * 1024);
    short* mlp1  = (short*)(wsb + (size_t)24 * 1024 * 1024);
    short* hbuf  = (short*)(wsb + (size_t)72 * 1024 * 1024);

    cvt_bf16_kernel<<<1536, 256, 0, stream>>>(qkv_w, wqkv);
    cvt_bf16_kernel<<< 512, 256, 0, stream>>>(proj_w, wproj);
    cvt_bf16_kernel<<<2048, 256, 0, stream>>>(fc1_w, wfc1);
    cvt_bf16_kernel<<<2048, 256, 0, stream>>>(fc2_w, wfc2);

    ln_kernel<<<MROWS, 256, 0, stream>>>(x, ln1_w, ln1_b, hbuf);
    qkv_gemm<<<dim3(24, 32), 256, 0, stream>>>(hbuf, wqkv, qkvb, VT, 1024);
    fattn<<<dim3(SEQ / 64, BATCH * NHEAD), 256, 0, stream>>>(qkvb, VT, hbuf);
    // proj: BN=64, grid 16x32 = 512 blocks
    mgemm<64,true,true,false,false><<<dim3(16, 32), 256, 0, stream>>>(
        hbuf, wproj, proj_b, x, out, MROWS, 1024, 1024);
    ln_kernel<<<MROWS, 256, 0, stream>>>(out, ln2_w, ln2_b, hbuf);
    // FC1: 256x256 8-phase, grid 16x16 = 256 blocks (1/CU, 8 waves)
    gemm8p<true,false,true,true><<<dim3(16, 16), 512, 0, stream>>>(
        hbuf, wfc1, fc1_b, nullptr, mlp1, MROWS, 4096, 1024);
    // FC2: BN=64, grid 16x32 = 512 blocks
    mgemm<64,true,true,false,false><<<dim3(16, 32), 256, 0, stream>>>(
        mlp1, wfc2, fc2_b, out, out, MROWS, 1024, 4096);
}

// Round 9
// 230.015 us; speedup vs baseline: 9.4577x; 1.0751x over previous
//
#include <hip/hip_runtime.h>
#include <hip/hip_bf16.h>
#include <math.h>
#include <stdint.h>

#define SEQ 1024
#define CDIM 1024
#define NHEAD 16
#define HIDDEN 4096
#define BATCH 4
#define MROWS (BATCH*SEQ)   // 4096

using bf16x8 = __attribute__((ext_vector_type(8))) short;
using f32x4  = __attribute__((ext_vector_type(4))) float;

__device__ __forceinline__ short f2bf(float f) {
    union { float f; uint32_t u; } c; c.f = f;
    const uint32_t u = c.u + 0x7FFFu + ((c.u >> 16) & 1u);
    return (short)(u >> 16);
}

__device__ __forceinline__ float gelu_exact(float v) {
    return 0.5f * v * (1.0f + erff(v * 0.70710678118654752440f));
}

__device__ __forceinline__ void gload_lds16(const short* g, short* lds) {
    __builtin_amdgcn_global_load_lds(
        (const __attribute__((address_space(1))) void*)(uintptr_t)g,
        (__attribute__((address_space(3))) void*)(uintptr_t)lds,
        16, 0, 0);
}

// ---------------- weight fp32 -> bf16 conversion ----------------
__global__ void cvt_bf16_kernel(const float* __restrict__ in, short* __restrict__ out) {
    const size_t i = ((size_t)blockIdx.x * 256 + threadIdx.x) * 8;
    const float4 a = *(const float4*)(in + i);
    const float4 b = *(const float4*)(in + i + 4);
    bf16x8 s;
    s[0] = f2bf(a.x); s[1] = f2bf(a.y); s[2] = f2bf(a.z); s[3] = f2bf(a.w);
    s[4] = f2bf(b.x); s[5] = f2bf(b.y); s[6] = f2bf(b.z); s[7] = f2bf(b.w);
    *(bf16x8*)(out + i) = s;
}

// ---------------- LayerNorm ----------------
__global__ void ln_kernel(const float* __restrict__ x, const float* __restrict__ w,
                          const float* __restrict__ b, short* __restrict__ out) {
    const int row = blockIdx.x;
    const int t = threadIdx.x;
    const float4* xr = (const float4*)(x + (size_t)row * CDIM);
    float4 v = xr[t];
    float s  = v.x + v.y + v.z + v.w;
    float sq = v.x*v.x + v.y*v.y + v.z*v.z + v.w*v.w;
    #pragma unroll
    for (int off = 32; off; off >>= 1) {
        s  += __shfl_down(s, off);
        sq += __shfl_down(sq, off);
    }
    __shared__ float ss[4], ssq[4];
    const int wid = t >> 6, lane = t & 63;
    if (lane == 0) { ss[wid] = s; ssq[wid] = sq; }
    __syncthreads();
    s  = ss[0] + ss[1] + ss[2] + ss[3];
    sq = ssq[0] + ssq[1] + ssq[2] + ssq[3];
    const float mu  = s * (1.0f / CDIM);
    const float var = sq * (1.0f / CDIM) - mu * mu;
    const float rs  = rsqrtf(var + 1e-5f);
    const float4 wv = ((const float4*)w)[t];
    const float4 bv = ((const float4*)b)[t];
    short4 o;
    o.x = f2bf((v.x - mu) * rs * wv.x + bv.x);
    o.y = f2bf((v.y - mu) * rs * wv.y + bv.y);
    o.z = f2bf((v.z - mu) * rs * wv.z + bv.z);
    o.w = f2bf((v.w - mu) * rs * wv.w + bv.w);
    *(short4*)(out + (size_t)row * CDIM + t * 4) = o;
}

// ============ 256x256 8-phase MFMA GEMM (T2+T3+T4+T5), 512 threads ============
template<bool BIAS, bool RES, bool GELU_, bool OUTBF16>
__global__ __launch_bounds__(512) void gemm8p(
    const short* __restrict__ A, const short* __restrict__ B,
    const float* __restrict__ bias, const float* __restrict__ res,
    void* __restrict__ Cv, int M, int N, int K)
{
    __shared__ __align__(16) short As[2][256 * 64];
    __shared__ __align__(16) short Bs[2][256 * 64];
    const int t = threadIdx.x;
    const int w = t >> 6, l = t & 63;
    const int wm = w >> 2, wn = w & 3;

    const int lid = blockIdx.y * gridDim.x + blockIdx.x;
    const int xcd = lid & 7, c = lid >> 3;
    const int by = (xcd >> 1) * 4 + (c >> 3);
    const int bx = (xcd & 1) * 8 + (c & 7);
    const int m0 = by * 256, n0 = bx * 256;

    const int trow = t >> 3;
    const int k8s = ((t & 7) ^ (trow & 7)) * 8;
    const short* Ag = A + (size_t)(m0 + trow) * K + k8s;
    const short* Bg = B + (size_t)(n0 + trow) * K + k8s;

    const int fr = l & 15, g = l >> 4;
    const int sw = fr & 7;
    const int ak0 = (g ^ sw) * 8;
    const int ak1 = ((4 + g) ^ sw) * 8;
    int aoff[8], boff[4];
    #pragma unroll
    for (int mf = 0; mf < 8; ++mf) aoff[mf] = (wm * 128 + mf * 16 + fr) * 64;
    #pragma unroll
    for (int nf = 0; nf < 4; ++nf) boff[nf] = (wn * 64 + nf * 16 + fr) * 64;

    f32x4 acc[8][4] = {};

#define STAGE8(Gb, LDSb, kt, h)                                             \
    {                                                                       \
        gload_lds16((Gb) + (size_t)((h) * 128) * K + (kt) * 64,             \
                    (LDSb) + ((h) * 128 + w * 8) * 64);                     \
        gload_lds16((Gb) + (size_t)((h) * 128 + 64) * K + (kt) * 64,        \
                    (LDSb) + ((h) * 128 + 64 + w * 8) * 64);                \
    }

    STAGE8(Ag, As[0], 0, 0); STAGE8(Ag, As[0], 0, 1);
    STAGE8(Bg, Bs[0], 0, 0); STAGE8(Bg, Bs[0], 0, 1);
    asm volatile("s_waitcnt vmcnt(0)" ::: "memory");
    __builtin_amdgcn_s_barrier();

    const int T = K / 64;
    for (int kt = 0; kt < T; ++kt) {
        short* curA = &As[kt & 1][0];
        short* curB = &Bs[kt & 1][0];
        short* nxtA = &As[(kt & 1) ^ 1][0];
        short* nxtB = &Bs[(kt & 1) ^ 1][0];
        const bool pre = (kt + 1 < T);
        bf16x8 bfr[4], af[4];

        if (pre) STAGE8(Ag, nxtA, kt + 1, 0);
        #pragma unroll
        for (int nf = 0; nf < 4; ++nf) bfr[nf] = *(const bf16x8*)&curB[boff[nf] + ak0];
        #pragma unroll
        for (int mf = 0; mf < 4; ++mf) af[mf] = *(const bf16x8*)&curA[aoff[mf] + ak0];
        __builtin_amdgcn_s_barrier();
        __builtin_amdgcn_s_setprio(1);
        #pragma unroll
        for (int mf = 0; mf < 4; ++mf)
            #pragma unroll
            for (int nf = 0; nf < 4; ++nf)
                acc[mf][nf] = __builtin_amdgcn_mfma_f32_16x16x32_bf16(af[mf], bfr[nf], acc[mf][nf], 0, 0, 0);
        __builtin_amdgcn_s_setprio(0);
        __builtin_amdgcn_s_barrier();

        if (pre) STAGE8(Ag, nxtA, kt + 1, 1);
        #pragma unroll
        for (int mf = 0; mf < 4; ++mf) af[mf] = *(const bf16x8*)&curA[aoff[4 + mf] + ak0];
        __builtin_amdgcn_s_barrier();
        __builtin_amdgcn_s_setprio(1);
        #pragma unroll
        for (int mf = 0; mf < 4; ++mf)
            #pragma unroll
            for (int nf = 0; nf < 4; ++nf)
                acc[4 + mf][nf] = __builtin_amdgcn_mfma_f32_16x16x32_bf16(af[mf], bfr[nf], acc[4 + mf][nf], 0, 0, 0);
        __builtin_amdgcn_s_setprio(0);
        __builtin_amdgcn_s_barrier();

        if (pre) STAGE8(Bg, nxtB, kt + 1, 0);
        #pragma unroll
        for (int nf = 0; nf < 4; ++nf) bfr[nf] = *(const bf16x8*)&curB[boff[nf] + ak1];
        #pragma unroll
        for (int mf = 0; mf < 4; ++mf) af[mf] = *(const bf16x8*)&curA[aoff[mf] + ak1];
        __builtin_amdgcn_s_barrier();
        __builtin_amdgcn_s_setprio(1);
        #pragma unroll
        for (int mf = 0; mf < 4; ++mf)
            #pragma unroll
            for (int nf = 0; nf < 4; ++nf)
                acc[mf][nf] = __builtin_amdgcn_mfma_f32_16x16x32_bf16(af[mf], bfr[nf], acc[mf][nf], 0, 0, 0);
        __builtin_amdgcn_s_setprio(0);
        __builtin_amdgcn_s_barrier();

        if (pre) STAGE8(Bg, nxtB, kt + 1, 1);
        #pragma unroll
        for (int mf = 0; mf < 4; ++mf) af[mf] = *(const bf16x8*)&curA[aoff[4 + mf] + ak1];
        __builtin_amdgcn_s_barrier();
        __builtin_amdgcn_s_setprio(1);
        #pragma unroll
        for (int mf = 0; mf < 4; ++mf)
            #pragma unroll
            for (int nf = 0; nf < 4; ++nf)
                acc[4 + mf][nf] = __builtin_amdgcn_mfma_f32_16x16x32_bf16(af[mf], bfr[nf], acc[4 + mf][nf], 0, 0, 0);
        __builtin_amdgcn_s_setprio(0);
        asm volatile("s_waitcnt vmcnt(0)" ::: "memory");
        __builtin_amdgcn_s_barrier();
    }
#undef STAGE8

    const int lr4 = (l >> 4) * 4, lc = l & 15;
    #pragma unroll
    for (int mf = 0; mf < 8; ++mf) {
        #pragma unroll
        for (int nf = 0; nf < 4; ++nf) {
            const int col = n0 + wn * 64 + nf * 16 + lc;
            const float bv = BIAS ? bias[col] : 0.0f;
            #pragma unroll
            for (int r = 0; r < 4; ++r) {
                const int row = m0 + wm * 128 + mf * 16 + lr4 + r;
                float v = acc[mf][nf][r] + bv;
                if (GELU_) v = gelu_exact(v);
                if (RES)   v += res[(size_t)row * N + col];
                if (OUTBF16) ((short*)Cv)[(size_t)row * N + col] = f2bf(v);
                else         ((float*)Cv)[(size_t)row * N + col] = v;
            }
        }
    }
}

// ============ QKV GEMM: 256x256 8-phase with Q/K/V epilogue ============
// N=3072 grid (12,16). cols [0,1024): Q*0.125 -> qkvb; [1024,2048): K -> qkvb;
// [2048,3072): V -> VT[b][h][d][n]. 256-wide tiles never straddle regions.
__global__ __launch_bounds__(512) void qkv8p(
    const short* __restrict__ A, const short* __restrict__ B,
    short* __restrict__ qkvb, short* __restrict__ VT, int K)
{
    __shared__ __align__(16) short As[2][256 * 64];
    __shared__ __align__(16) short Bs[2][256 * 64];
    const int t = threadIdx.x;
    const int w = t >> 6, l = t & 63;
    const int wm = w >> 2, wn = w & 3;

    const int lid = blockIdx.y * gridDim.x + blockIdx.x;   // nwg = 192
    const int swz = (lid & 7) * 24 + (lid >> 3);
    const int bx = swz % 12, by = swz / 12;
    const int m0 = by * 256, n0 = bx * 256;

    const int trow = t >> 3;
    const int k8s = ((t & 7) ^ (trow & 7)) * 8;
    const short* Ag = A + (size_t)(m0 + trow) * K + k8s;
    const short* Bg = B + (size_t)(n0 + trow) * K + k8s;

    const int fr = l & 15, g = l >> 4;
    const int sw = fr & 7;
    const int ak0 = (g ^ sw) * 8;
    const int ak1 = ((4 + g) ^ sw) * 8;
    int aoff[8], boff[4];
    #pragma unroll
    for (int mf = 0; mf < 8; ++mf) aoff[mf] = (wm * 128 + mf * 16 + fr) * 64;
    #pragma unroll
    for (int nf = 0; nf < 4; ++nf) boff[nf] = (wn * 64 + nf * 16 + fr) * 64;

    f32x4 acc[8][4] = {};

#define STAGE8(Gb, LDSb, kt, h)                                             \
    {                                                                       \
        gload_lds16((Gb) + (size_t)((h) * 128) * K + (kt) * 64,             \
                    (LDSb) + ((h) * 128 + w * 8) * 64);                     \
        gload_lds16((Gb) + (size_t)((h) * 128 + 64) * K + (kt) * 64,        \
                    (LDSb) + ((h) * 128 + 64 + w * 8) * 64);                \
    }

    STAGE8(Ag, As[0], 0, 0); STAGE8(Ag, As[0], 0, 1);
    STAGE8(Bg, Bs[0], 0, 0); STAGE8(Bg, Bs[0], 0, 1);
    asm volatile("s_waitcnt vmcnt(0)" ::: "memory");
    __builtin_amdgcn_s_barrier();

    const int T = K / 64;
    for (int kt = 0; kt < T; ++kt) {
        short* curA = &As[kt & 1][0];
        short* curB = &Bs[kt & 1][0];
        short* nxtA = &As[(kt & 1) ^ 1][0];
        short* nxtB = &Bs[(kt & 1) ^ 1][0];
        const bool pre = (kt + 1 < T);
        bf16x8 bfr[4], af[4];

        if (pre) STAGE8(Ag, nxtA, kt + 1, 0);
        #pragma unroll
        for (int nf = 0; nf < 4; ++nf) bfr[nf] = *(const bf16x8*)&curB[boff[nf] + ak0];
        #pragma unroll
        for (int mf = 0; mf < 4; ++mf) af[mf] = *(const bf16x8*)&curA[aoff[mf] + ak0];
        __builtin_amdgcn_s_barrier();
        __builtin_amdgcn_s_setprio(1);
        #pragma unroll
        for (int mf = 0; mf < 4; ++mf)
            #pragma unroll
            for (int nf = 0; nf < 4; ++nf)
                acc[mf][nf] = __builtin_amdgcn_mfma_f32_16x16x32_bf16(af[mf], bfr[nf], acc[mf][nf], 0, 0, 0);
        __builtin_amdgcn_s_setprio(0);
        __builtin_amdgcn_s_barrier();

        if (pre) STAGE8(Ag, nxtA, kt + 1, 1);
        #pragma unroll
        for (int mf = 0; mf < 4; ++mf) af[mf] = *(const bf16x8*)&curA[aoff[4 + mf] + ak0];
        __builtin_amdgcn_s_barrier();
        __builtin_amdgcn_s_setprio(1);
        #pragma unroll
        for (int mf = 0; mf < 4; ++mf)
            #pragma unroll
            for (int nf = 0; nf < 4; ++nf)
                acc[4 + mf][nf] = __builtin_amdgcn_mfma_f32_16x16x32_bf16(af[mf], bfr[nf], acc[4 + mf][nf], 0, 0, 0);
        __builtin_amdgcn_s_setprio(0);
        __builtin_amdgcn_s_barrier();

        if (pre) STAGE8(Bg, nxtB, kt + 1, 0);
        #pragma unroll
        for (int nf = 0; nf < 4; ++nf) bfr[nf] = *(const bf16x8*)&curB[boff[nf] + ak1];
        #pragma unroll
        for (int mf = 0; mf < 4; ++mf) af[mf] = *(const bf16x8*)&curA[aoff[mf] + ak1];
        __builtin_amdgcn_s_barrier();
        __builtin_amdgcn_s_setprio(1);
        #pragma unroll
        for (int mf = 0; mf < 4; ++mf)
            #pragma unroll
            for (int nf = 0; nf < 4; ++nf)
                acc[mf][nf] = __builtin_amdgcn_mfma_f32_16x16x32_bf16(af[mf], bfr[nf], acc[mf][nf], 0, 0, 0);
        __builtin_amdgcn_s_setprio(0);
        __builtin_amdgcn_s_barrier();

        if (pre) STAGE8(Bg, nxtB, kt + 1, 1);
        #pragma unroll
        for (int mf = 0; mf < 4; ++mf) af[mf] = *(const bf16x8*)&curA[aoff[4 + mf] + ak1];
        __builtin_amdgcn_s_barrier();
        __builtin_amdgcn_s_setprio(1);
        #pragma unroll
        for (int mf = 0; mf < 4; ++mf)
            #pragma unroll
            for (int nf = 0; nf < 4; ++nf)
                acc[4 + mf][nf] = __builtin_amdgcn_mfma_f32_16x16x32_bf16(af[mf], bfr[nf], acc[4 + mf][nf], 0, 0, 0);
        __builtin_amdgcn_s_setprio(0);
        asm volatile("s_waitcnt vmcnt(0)" ::: "memory");
        __builtin_amdgcn_s_barrier();
    }
#undef STAGE8

    const int lr4 = (l >> 4) * 4, lc = l & 15;
    if (n0 < 2048) {
        const float sc = (n0 < 1024) ? 0.125f : 1.0f;
        #pragma unroll
        for (int mf = 0; mf < 8; ++mf) {
            #pragma unroll
            for (int nf = 0; nf < 4; ++nf) {
                const int col = n0 + wn * 64 + nf * 16 + lc;
                #pragma unroll
                for (int r = 0; r < 4; ++r) {
                    const int row = m0 + wm * 128 + mf * 16 + lr4 + r;
                    qkvb[(size_t)row * 2048 + col] = f2bf(acc[mf][nf][r] * sc);
                }
            }
        }
    } else {
        #pragma unroll
        for (int mf = 0; mf < 8; ++mf) {
            const int row0 = m0 + wm * 128 + mf * 16 + lr4;   // 4-aligned
            const int b = row0 >> 10, nseq = row0 & 1023;
            #pragma unroll
            for (int nf = 0; nf < 4; ++nf) {
                const int c2 = n0 - 2048 + wn * 64 + nf * 16 + lc;
                const int h = c2 >> 6, d = c2 & 63;
                short4 v4;
                v4.x = f2bf(acc[mf][nf][0]); v4.y = f2bf(acc[mf][nf][1]);
                v4.z = f2bf(acc[mf][nf][2]); v4.w = f2bf(acc[mf][nf][3]);
                *(short4*)&VT[(((size_t)(b * 16 + h) * 64 + d) * 1024) + nseq] = v4;
            }
        }
    }
}

// ------------- bf16 MFMA GEMM, 3-buffer counted vmcnt (proj / FC2) -----
template<int BN, bool BIAS, bool RES, bool GELU_, bool OUTBF16>
__global__ __launch_bounds__(256) void mgemm(
    const short* __restrict__ A, const short* __restrict__ B,
    const float* __restrict__ bias, const float* __restrict__ res,
    void* __restrict__ Cv, int M, int N, int K)
{
    constexpr int MF = (BN == 128) ? 4 : 2;
    __shared__ __align__(16) short As[3][128 * 32];
    __shared__ __align__(16) short Bs[3][BN * 32];
    const int t = threadIdx.x;
    const int w = t >> 6, l = t & 63;

    const int gx = gridDim.x;
    const int nwg = gx * gridDim.y;
    const int lid = blockIdx.y * gx + blockIdx.x;
    const int swzb = (lid & 7) * (nwg >> 3) + (lid >> 3);
    const int bx = swzb % gx, by = swzb / gx;
    const int m0 = by * 128, n0 = bx * BN;

    const int wrow = (BN == 128) ? (w >> 1) * 64 : w * 32;
    const int wcol = (BN == 128) ? (w & 1) * 64 : 0;

    const int sk8 = ((l & 3) ^ ((l >> 3) & 3)) * 8;
    const short* agp0 = A + (size_t)(m0 + w * 32 + (l >> 2)) * K + sk8;
    const short* agp1 = agp0 + (size_t)16 * K;
    const short* bgp0;
    const short* bgp1 = nullptr;
    if (BN == 128) {
        bgp0 = B + (size_t)(n0 + w * 32 + (l >> 2)) * K + sk8;
        bgp1 = bgp0 + (size_t)16 * K;
    } else {
        bgp0 = B + (size_t)(n0 + w * 16 + (l >> 2)) * K + sk8;
    }

    const int fr = l & 15;
    const int rsw = (fr >> 1) & 3;
    int aoff[MF], boff[4];
    #pragma unroll
    for (int m = 0; m < MF; ++m) aoff[m] = (wrow + m * 16 + fr) * 32 + ((l >> 4) ^ rsw) * 8;
    #pragma unroll
    for (int n = 0; n < 4; ++n)  boff[n] = (wcol + n * 16 + fr) * 32 + ((l >> 4) ^ rsw) * 8;

    auto stage = [&](int k0, int buf) {
        short* ldsA = &As[buf][w * 1024];
        gload_lds16(agp0 + k0, ldsA);
        gload_lds16(agp1 + k0, ldsA + 512);
        if (BN == 128) {
            short* ldsB = &Bs[buf][w * 1024];
            gload_lds16(bgp0 + k0, ldsB);
            gload_lds16(bgp1 + k0, ldsB + 512);
        } else {
            gload_lds16(bgp0 + k0, &Bs[buf][w * 512]);
        }
    };

    f32x4 acc[MF][4] = {};
    const int T = K / 32;
    stage(0, 0);
    stage(32, 1);
    int cur = 0;
    for (int kt = 0; kt < T; ++kt) {
        if (kt < T - 1) {
            if constexpr (BN == 128) asm volatile("s_waitcnt vmcnt(4)" ::: "memory");
            else                     asm volatile("s_waitcnt vmcnt(3)" ::: "memory");
        } else {
            asm volatile("s_waitcnt vmcnt(0)" ::: "memory");
        }
        __builtin_amdgcn_sched_barrier(0);
        __builtin_amdgcn_s_barrier();
        __builtin_amdgcn_sched_barrier(0);
        if (kt + 2 < T) {
            int nb = kt + 2; nb -= (nb >= 3) ? ((nb / 3) * 3) : 0;
            stage((kt + 2) * 32, nb);
        }
        bf16x8 af[MF], bfr[4];
        #pragma unroll
        for (int m = 0; m < MF; ++m) af[m]  = *(const bf16x8*)&As[cur][aoff[m]];
        #pragma unroll
        for (int n = 0; n < 4; ++n)  bfr[n] = *(const bf16x8*)&Bs[cur][boff[n]];
        #pragma unroll
        for (int m = 0; m < MF; ++m)
            #pragma unroll
            for (int n = 0; n < 4; ++n)
                acc[m][n] = __builtin_amdgcn_mfma_f32_16x16x32_bf16(af[m], bfr[n], acc[m][n], 0, 0, 0);
        cur = (cur == 2) ? 0 : cur + 1;
    }

    const int lr4 = (l >> 4) * 4, lc = l & 15;
    #pragma unroll
    for (int m = 0; m < MF; ++m) {
        #pragma unroll
        for (int n = 0; n < 4; ++n) {
            const int col = n0 + wcol + n * 16 + lc;
            const float bv = BIAS ? bias[col] : 0.0f;
            #pragma unroll
            for (int r = 0; r < 4; ++r) {
                const int row = m0 + wrow + m * 16 + lr4 + r;
                float v = acc[m][n][r] + bv;
                if (GELU_) v = gelu_exact(v);
                if (RES)   v += res[(size_t)row * N + col];
                if (OUTBF16) ((short*)Cv)[(size_t)row * N + col] = f2bf(v);
                else         ((float*)Cv)[(size_t)row * N + col] = v;
            }
        }
    }
}

// ---------------- MFMA flash attention (swapped QK^T, per-lane softmax) ----------------
// Lane softmax state is for q = l&15. S^T: lane holds kv = nt*16+(l>>4)*4+r.
// P packed to bf16 via v_cvt_pk_bf16_f32, stored as b64 (swizzle-compatible with PV read).
__global__ __launch_bounds__(256) void fattn(const short* __restrict__ qkvb,
                                             const short* __restrict__ VT,
                                             short* __restrict__ o) {
    // bh-grouped XCD swizzle: all 16 q-tiles of a bh share d&7 (same XCD).
    const int lid = blockIdx.y * gridDim.x + blockIdx.x;   // grid (16,64)
    const int bh = ((lid >> 7) << 3) | (lid & 7);
    const int q0 = ((lid >> 3) & 15) * 64;
    const int b = bh >> 4, h = bh & 15;
    const int t = threadIdx.x, w = t >> 6, l = t & 63;

    __shared__ __align__(16) short Ks[2][64 * 64];
    __shared__ __align__(16) short Vs[2][64 * 64];
    __shared__ __align__(16) short Ps[4][1024];

    const size_t qrow = (size_t)(b * SEQ + q0 + w * 16 + (l & 15)) * 2048 + h * 64;
    bf16x8 qf[2];
    qf[0] = *(const bf16x8*)&qkvb[qrow + (l >> 4) * 8];
    qf[1] = *(const bf16x8*)&qkvb[qrow + 32 + (l >> 4) * 8];

    const int srow = l >> 3;
    const int sc16 = (l & 7) ^ (srow & 7);
    const short* Kg = qkvb + 1024 + h * 64;
    const short* Vg = VT + (size_t)bh * 64 * 1024;

    f32x4 acc[4] = {};                 // O[q'=(l>>4)*4+r][d=nt2*16+(l&15)]
    float mr = -1e30f, lr = 0.0f;      // softmax state for q = l&15
    const int q = l & 15;
    const int g4 = (l >> 4) & 3;

    auto stage = [&](int kt, int buf) {
        const int kv0 = kt * 64;
        #pragma unroll
        for (int i = 0; i < 2; ++i) {
            const int r0 = w * 16 + i * 8;
            gload_lds16(Kg + (size_t)(b * SEQ + kv0 + r0 + srow) * 2048 + sc16 * 8,
                        &Ks[buf][r0 * 64]);
            gload_lds16(Vg + (size_t)(r0 + srow) * 1024 + kv0 + sc16 * 8,
                        &Vs[buf][r0 * 64]);
        }
    };

    stage(0, 0);
    for (int kt = 0; kt < 16; ++kt) {
        const int cur = kt & 1;
        __syncthreads();
        if (kt + 1 < 16) stage(kt + 1, cur ^ 1);

        // S^T = K Q^T: lane holds S[kv=nt*16+g4*4+r][q]
        f32x4 sacc[4];
        #pragma unroll
        for (int nt = 0; nt < 4; ++nt) {
            f32x4 z = {};
            #pragma unroll
            for (int ks = 0; ks < 2; ++ks) {
                const int row = nt * 16 + (l & 15);
                const int c16 = (ks * 4 + (l >> 4)) ^ (row & 7);
                const bf16x8 kf = *(const bf16x8*)&Ks[cur][row * 64 + c16 * 8];
                z = __builtin_amdgcn_mfma_f32_16x16x32_bf16(kf, qf[ks], z, 0, 0, 0);
            }
            sacc[nt] = z;
        }
        // tile max over kv: in-lane 16 + cross-group shfl
        float tm = sacc[0][0];
        #pragma unroll
        for (int nt = 0; nt < 4; ++nt)
            #pragma unroll
            for (int r = 0; r < 4; ++r) tm = fmaxf(tm, sacc[nt][r]);
        tm = fmaxf(tm, __shfl_xor(tm, 16));
        tm = fmaxf(tm, __shfl_xor(tm, 32));
        // defer-max (T13): skip rescale when growth <= 8
        const bool norescale = __all(tm <= mr + 8.0f);
        float fac = 1.0f;
        if (!norescale) {
            const float nm = fmaxf(mr, tm);
            fac = __expf(mr - nm);
            mr = nm;
        }
        float p[4][4];
        float ts = 0.0f;
        #pragma unroll
        for (int nt = 0; nt < 4; ++nt)
            #pragma unroll
            for (int r = 0; r < 4; ++r) {
                p[nt][r] = __expf(sacc[nt][r] - mr);
                ts += p[nt][r];
            }
        ts += __shfl_xor(ts, 16);
        ts += __shfl_xor(ts, 32);
        lr = lr * fac + ts;
        if (!norescale) {
            float facv[4];
            #pragma unroll
            for (int r = 0; r < 4; ++r)
                facv[r] = __shfl(fac, (l & 48) + g4 * 4 + r);
            #pragma unroll
            for (int nt2 = 0; nt2 < 4; ++nt2)
                #pragma unroll
                for (int r = 0; r < 4; ++r)
                    acc[nt2][r] *= facv[r];
        }
        // pack P -> bf16 b64 stores (4 consecutive kv per lane)
        #pragma unroll
        for (int nt = 0; nt < 4; ++nt) {
            uint32_t lo, hi;
            asm("v_cvt_pk_bf16_f32 %0, %1, %2" : "=v"(lo) : "v"(p[nt][0]), "v"(p[nt][1]));
            asm("v_cvt_pk_bf16_f32 %0, %1, %2" : "=v"(hi) : "v"(p[nt][2]), "v"(p[nt][3]));
            const int kvb = nt * 16 + g4 * 4;
            const int addr = q * 64 + (((kvb >> 3) ^ (q & 7)) << 3) + (kvb & 7);
            *(uint2*)&Ps[w][addr] = make_uint2(lo, hi);
        }
        __builtin_amdgcn_s_waitcnt(0);  // lgkm drain for own-wave P stores (per-wave buffer)
        // PV: O += P V (unswapped; reads match write swizzle)
        #pragma unroll
        for (int ks = 0; ks < 2; ++ks) {
            const int ql = l & 15;
            const bf16x8 pa = *(const bf16x8*)&Ps[w][ql * 64 + ((ks * 32 + (l >> 4) * 8) ^ ((ql & 7) << 3))];
            #pragma unroll
            for (int nt2 = 0; nt2 < 4; ++nt2) {
                const int row = nt2 * 16 + (l & 15);
                const int c16 = (ks * 4 + (l >> 4)) ^ (row & 7);
                const bf16x8 vf = *(const bf16x8*)&Vs[cur][row * 64 + c16 * 8];
                acc[nt2] = __builtin_amdgcn_mfma_f32_16x16x32_bf16(pa, vf, acc[nt2], 0, 0, 0);
            }
        }
    }
    // normalize + write: O row q' = (l>>4)*4+r needs lr of that q (shuffle)
    float rcpl = 1.0f / lr;
    #pragma unroll
    for (int r = 0; r < 4; ++r) {
        const float rcp = __shfl(rcpl, (l & 48) + g4 * 4 + r);
        const int qq = q0 + w * 16 + g4 * 4 + r;
        #pragma unroll
        for (int nt2 = 0; nt2 < 4; ++nt2) {
            const int d = nt2 * 16 + (l & 15);
            o[(size_t)(b * SEQ + qq) * CDIM + h * 64 + d] = f2bf(acc[nt2][r] * rcp);
        }
    }
}

extern "C" void kernel_launch(void* const* d_in, const int* in_sizes, int n_in,
                              void* d_out, int out_size, void* d_ws, size_t ws_size,
                              hipStream_t stream) {
    const float* x      = (const float*)d_in[0];
    const float* ln1_w  = (const float*)d_in[1];
    const float* ln1_b  = (const float*)d_in[2];
    const float* qkv_w  = (const float*)d_in[3];
    const float* proj_w = (const float*)d_in[4];
    const float* proj_b = (const float*)d_in[5];
    const float* ln2_w  = (const float*)d_in[6];
    const float* ln2_b  = (const float*)d_in[7];
    const float* fc1_w  = (const float*)d_in[8];
    const float* fc1_b  = (const float*)d_in[9];
    const float* fc2_w  = (const float*)d_in[10];
    const float* fc2_b  = (const float*)d_in[11];
    float* out = (float*)d_out;

    short* ws16  = (short*)d_ws;
    short* wqkv  = ws16;
    short* wproj = ws16 + 3145728;
    short* wfc1  = ws16 + 4194304;
    short* wfc2  = ws16 + 8388608;
    char*  wsb   = (char*)d_ws;
    short* qkvb  = (short*)(wsb + (size_t)24 * 1024 * 1024);
    short* VT    = (short*)(wsb + (size_t)40 * 1024 * 1024);
    short* mlp1  = (short*)(wsb + (size_t)24 * 1024 * 1024);
    short* hbuf  = (short*)(wsb + (size_t)72 * 1024 * 1024);

    cvt_bf16_kernel<<<1536, 256, 0, stream>>>(qkv_w, wqkv);
    cvt_bf16_kernel<<< 512, 256, 0, stream>>>(proj_w, wproj);
    cvt_bf16_kernel<<<2048, 256, 0, stream>>>(fc1_w, wfc1);
    cvt_bf16_kernel<<<2048, 256, 0, stream>>>(fc2_w, wfc2);

    ln_kernel<<<MROWS, 256, 0, stream>>>(x, ln1_w, ln1_b, hbuf);
    // QKV: 256x256 8-phase, grid 12x16 = 192 blocks
    qkv8p<<<dim3(12, 16), 512, 0, stream>>>(hbuf, wqkv, qkvb, VT, 1024);
    fattn<<<dim3(16, 64), 256, 0, stream>>>(qkvb, VT, hbuf);
    // proj: BN=64, grid 16x32 = 512 blocks
    mgemm<64,true,true,false,false><<<dim3(16, 32), 256, 0, stream>>>(
        hbuf, wproj, proj_b, x, out, MROWS, 1024, 1024);
    ln_kernel<<<MROWS, 256, 0, stream>>>(out, ln2_w, ln2_b, hbuf);
    // FC1: 256x256 8-phase, grid 16x16 = 256 blocks
    gemm8p<true,false,true,true><<<dim3(16, 16), 512, 0, stream>>>(
        hbuf, wfc1, fc1_b, nullptr, mlp1, MROWS, 4096, 1024);
    // FC2: BN=64, grid 16x32 = 512 blocks
    mgemm<64,true,true,false,false><<<dim3(16, 32), 256, 0, stream>>>(
        mlp1, wfc2, fc2_b, out, out, MROWS, 1024, 4096);
}

// Round 10
// 225.459 us; speedup vs baseline: 9.6488x; 1.0202x over previous
//
#include <hip/hip_runtime.h>
#include <hip/hip_bf16.h>
#include <math.h>
#include <stdint.h>

#define SEQ 1024
#define CDIM 1024
#define NHEAD 16
#define HIDDEN 4096
#define BATCH 4
#define MROWS (BATCH*SEQ)   // 4096

using bf16x8 = __attribute__((ext_vector_type(8))) short;
using f32x4  = __attribute__((ext_vector_type(4))) float;

__device__ __forceinline__ short f2bf(float f) {
    union { float f; uint32_t u; } c; c.f = f;
    const uint32_t u = c.u + 0x7FFFu + ((c.u >> 16) & 1u);
    return (short)(u >> 16);
}

__device__ __forceinline__ float gelu_exact(float v) {
    return 0.5f * v * (1.0f + erff(v * 0.70710678118654752440f));
}

__device__ __forceinline__ void gload_lds16(const short* g, short* lds) {
    __builtin_amdgcn_global_load_lds(
        (const __attribute__((address_space(1))) void*)(uintptr_t)g,
        (__attribute__((address_space(3))) void*)(uintptr_t)lds,
        16, 0, 0);
}

// ---------------- weight fp32 -> bf16 conversion ----------------
__global__ void cvt_bf16_kernel(const float* __restrict__ in, short* __restrict__ out) {
    const size_t i = ((size_t)blockIdx.x * 256 + threadIdx.x) * 8;
    const float4 a = *(const float4*)(in + i);
    const float4 b = *(const float4*)(in + i + 4);
    bf16x8 s;
    s[0] = f2bf(a.x); s[1] = f2bf(a.y); s[2] = f2bf(a.z); s[3] = f2bf(a.w);
    s[4] = f2bf(b.x); s[5] = f2bf(b.y); s[6] = f2bf(b.z); s[7] = f2bf(b.w);
    *(bf16x8*)(out + i) = s;
}

// ---------------- LayerNorm ----------------
__global__ void ln_kernel(const float* __restrict__ x, const float* __restrict__ w,
                          const float* __restrict__ b, short* __restrict__ out) {
    const int row = blockIdx.x;
    const int t = threadIdx.x;
    const float4* xr = (const float4*)(x + (size_t)row * CDIM);
    float4 v = xr[t];
    float s  = v.x + v.y + v.z + v.w;
    float sq = v.x*v.x + v.y*v.y + v.z*v.z + v.w*v.w;
    #pragma unroll
    for (int off = 32; off; off >>= 1) {
        s  += __shfl_down(s, off);
        sq += __shfl_down(sq, off);
    }
    __shared__ float ss[4], ssq[4];
    const int wid = t >> 6, lane = t & 63;
    if (lane == 0) { ss[wid] = s; ssq[wid] = sq; }
    __syncthreads();
    s  = ss[0] + ss[1] + ss[2] + ss[3];
    sq = ssq[0] + ssq[1] + ssq[2] + ssq[3];
    const float mu  = s * (1.0f / CDIM);
    const float var = sq * (1.0f / CDIM) - mu * mu;
    const float rs  = rsqrtf(var + 1e-5f);
    const float4 wv = ((const float4*)w)[t];
    const float4 bv = ((const float4*)b)[t];
    short4 o;
    o.x = f2bf((v.x - mu) * rs * wv.x + bv.x);
    o.y = f2bf((v.y - mu) * rs * wv.y + bv.y);
    o.z = f2bf((v.z - mu) * rs * wv.z + bv.z);
    o.w = f2bf((v.w - mu) * rs * wv.w + bv.w);
    *(short4*)(out + (size_t)row * CDIM + t * 4) = o;
}

// ===== 256x256 MFMA GEMM, BK=32, 3-buffer stage-2-ahead counted vmcnt =====
// 512 threads, 8 waves (2M x 4N), wave tile 128x64 (8x4 frags), 32 MFMA/tile.
// LDS 96KB. Swizzle: k8 ^= (row>>1)&3 on stage source AND read (2-way max).
// Per tile: vmcnt(4) -> SB -> s_barrier -> SB -> stage(t+2) -> 2 MFMA clusters.
template<bool BIAS, bool RES, bool GELU_, bool OUTBF16>
__global__ __launch_bounds__(512) void gemm8k(
    const short* __restrict__ A, const short* __restrict__ B,
    const float* __restrict__ bias, const float* __restrict__ res,
    void* __restrict__ Cv, int M, int N, int K)
{
    __shared__ __align__(16) short As[3][256 * 32];
    __shared__ __align__(16) short Bs[3][256 * 32];
    const int t = threadIdx.x;
    const int w = t >> 6, l = t & 63;
    const int wm = w >> 2, wn = w & 3;

    const int gx = gridDim.x;
    const int nwg = gx * gridDim.y;
    const int lid = blockIdx.y * gx + blockIdx.x;
    const int swz = (lid & 7) * (nwg >> 3) + (lid >> 3);
    const int bx = swz % gx, by = swz / gx;
    const int m0 = by * 256, n0 = bx * 256;

    // staging: trow = w*16 + (l>>2); slot = l&3; source pre-swizzled
    const int trow = w * 16 + (l >> 2);
    const int k8s = ((l & 3) ^ ((l >> 3) & 3)) * 8;   // (slot ^ ((trow>>1)&3)) * 8
    const short* Ag = A + (size_t)(m0 + trow) * K + k8s;
    const short* Bg = B + (size_t)(n0 + trow) * K + k8s;

    const int fr = l & 15, g = l >> 4;
    const int ak = (g ^ ((fr >> 1) & 3)) * 8;
    int aoff[8], boff[4];
    #pragma unroll
    for (int mf = 0; mf < 8; ++mf) aoff[mf] = (wm * 128 + mf * 16 + fr) * 32 + ak;
    #pragma unroll
    for (int nf = 0; nf < 4; ++nf) boff[nf] = (wn * 64 + nf * 16 + fr) * 32 + ak;

    auto stage = [&](int kt, int buf) {
        gload_lds16(Ag + (size_t)kt * 32,           &As[buf][w * 512]);
        gload_lds16(Ag + (size_t)128 * K + kt * 32, &As[buf][128 * 32 + w * 512]);
        gload_lds16(Bg + (size_t)kt * 32,           &Bs[buf][w * 512]);
        gload_lds16(Bg + (size_t)128 * K + kt * 32, &Bs[buf][128 * 32 + w * 512]);
    };

    f32x4 acc[8][4] = {};
    const int T = K / 32;
    stage(0, 0);
    stage(1, 1);
    int cur = 0;
    for (int kt = 0; kt < T; ++kt) {
        if (kt < T - 1) asm volatile("s_waitcnt vmcnt(4)" ::: "memory");
        else            asm volatile("s_waitcnt vmcnt(0)" ::: "memory");
        __builtin_amdgcn_sched_barrier(0);
        __builtin_amdgcn_s_barrier();
        __builtin_amdgcn_sched_barrier(0);
        if (kt + 2 < T) {
            int nb = kt + 2; nb -= (nb >= 3) ? ((nb / 3) * 3) : 0;   // (kt+2)%3
            stage(kt + 2, nb);
        }
        bf16x8 bfr[4], af[4];
        #pragma unroll
        for (int nf = 0; nf < 4; ++nf) bfr[nf] = *(const bf16x8*)&Bs[cur][boff[nf]];
        #pragma unroll
        for (int mf = 0; mf < 4; ++mf) af[mf] = *(const bf16x8*)&As[cur][aoff[mf]];
        __builtin_amdgcn_s_setprio(1);
        #pragma unroll
        for (int mf = 0; mf < 4; ++mf)
            #pragma unroll
            for (int nf = 0; nf < 4; ++nf)
                acc[mf][nf] = __builtin_amdgcn_mfma_f32_16x16x32_bf16(af[mf], bfr[nf], acc[mf][nf], 0, 0, 0);
        __builtin_amdgcn_s_setprio(0);
        #pragma unroll
        for (int mf = 0; mf < 4; ++mf) af[mf] = *(const bf16x8*)&As[cur][aoff[4 + mf]];
        __builtin_amdgcn_s_setprio(1);
        #pragma unroll
        for (int mf = 0; mf < 4; ++mf)
            #pragma unroll
            for (int nf = 0; nf < 4; ++nf)
                acc[4 + mf][nf] = __builtin_amdgcn_mfma_f32_16x16x32_bf16(af[mf], bfr[nf], acc[4 + mf][nf], 0, 0, 0);
        __builtin_amdgcn_s_setprio(0);
        cur = (cur == 2) ? 0 : cur + 1;
    }

    const int lr4 = (l >> 4) * 4, lc = l & 15;
    #pragma unroll
    for (int mf = 0; mf < 8; ++mf) {
        #pragma unroll
        for (int nf = 0; nf < 4; ++nf) {
            const int col = n0 + wn * 64 + nf * 16 + lc;
            const float bv = BIAS ? bias[col] : 0.0f;
            #pragma unroll
            for (int r = 0; r < 4; ++r) {
                const int row = m0 + wm * 128 + mf * 16 + lr4 + r;
                float v = acc[mf][nf][r] + bv;
                if (GELU_) v = gelu_exact(v);
                if (RES)   v += res[(size_t)row * N + col];
                if (OUTBF16) ((short*)Cv)[(size_t)row * N + col] = f2bf(v);
                else         ((float*)Cv)[(size_t)row * N + col] = v;
            }
        }
    }
}

// ===== QKV GEMM on the same 256x256/BK32/3-buf schedule, Q/K/V epilogue =====
__global__ __launch_bounds__(512) void qkv8k(
    const short* __restrict__ A, const short* __restrict__ B,
    short* __restrict__ qkvb, short* __restrict__ VT, int K)
{
    __shared__ __align__(16) short As[3][256 * 32];
    __shared__ __align__(16) short Bs[3][256 * 32];
    const int t = threadIdx.x;
    const int w = t >> 6, l = t & 63;
    const int wm = w >> 2, wn = w & 3;

    const int gx = gridDim.x;                 // 12
    const int nwg = gx * gridDim.y;           // 192
    const int lid = blockIdx.y * gx + blockIdx.x;
    const int swz = (lid & 7) * (nwg >> 3) + (lid >> 3);
    const int bx = swz % gx, by = swz / gx;
    const int m0 = by * 256, n0 = bx * 256;

    const int trow = w * 16 + (l >> 2);
    const int k8s = ((l & 3) ^ ((l >> 3) & 3)) * 8;
    const short* Ag = A + (size_t)(m0 + trow) * K + k8s;
    const short* Bg = B + (size_t)(n0 + trow) * K + k8s;

    const int fr = l & 15, g = l >> 4;
    const int ak = (g ^ ((fr >> 1) & 3)) * 8;
    int aoff[8], boff[4];
    #pragma unroll
    for (int mf = 0; mf < 8; ++mf) aoff[mf] = (wm * 128 + mf * 16 + fr) * 32 + ak;
    #pragma unroll
    for (int nf = 0; nf < 4; ++nf) boff[nf] = (wn * 64 + nf * 16 + fr) * 32 + ak;

    auto stage = [&](int kt, int buf) {
        gload_lds16(Ag + (size_t)kt * 32,           &As[buf][w * 512]);
        gload_lds16(Ag + (size_t)128 * K + kt * 32, &As[buf][128 * 32 + w * 512]);
        gload_lds16(Bg + (size_t)kt * 32,           &Bs[buf][w * 512]);
        gload_lds16(Bg + (size_t)128 * K + kt * 32, &Bs[buf][128 * 32 + w * 512]);
    };

    f32x4 acc[8][4] = {};
    const int T = K / 32;
    stage(0, 0);
    stage(1, 1);
    int cur = 0;
    for (int kt = 0; kt < T; ++kt) {
        if (kt < T - 1) asm volatile("s_waitcnt vmcnt(4)" ::: "memory");
        else            asm volatile("s_waitcnt vmcnt(0)" ::: "memory");
        __builtin_amdgcn_sched_barrier(0);
        __builtin_amdgcn_s_barrier();
        __builtin_amdgcn_sched_barrier(0);
        if (kt + 2 < T) {
            int nb = kt + 2; nb -= (nb >= 3) ? ((nb / 3) * 3) : 0;
            stage(kt + 2, nb);
        }
        bf16x8 bfr[4], af[4];
        #pragma unroll
        for (int nf = 0; nf < 4; ++nf) bfr[nf] = *(const bf16x8*)&Bs[cur][boff[nf]];
        #pragma unroll
        for (int mf = 0; mf < 4; ++mf) af[mf] = *(const bf16x8*)&As[cur][aoff[mf]];
        __builtin_amdgcn_s_setprio(1);
        #pragma unroll
        for (int mf = 0; mf < 4; ++mf)
            #pragma unroll
            for (int nf = 0; nf < 4; ++nf)
                acc[mf][nf] = __builtin_amdgcn_mfma_f32_16x16x32_bf16(af[mf], bfr[nf], acc[mf][nf], 0, 0, 0);
        __builtin_amdgcn_s_setprio(0);
        #pragma unroll
        for (int mf = 0; mf < 4; ++mf) af[mf] = *(const bf16x8*)&As[cur][aoff[4 + mf]];
        __builtin_amdgcn_s_setprio(1);
        #pragma unroll
        for (int mf = 0; mf < 4; ++mf)
            #pragma unroll
            for (int nf = 0; nf < 4; ++nf)
                acc[4 + mf][nf] = __builtin_amdgcn_mfma_f32_16x16x32_bf16(af[mf], bfr[nf], acc[4 + mf][nf], 0, 0, 0);
        __builtin_amdgcn_s_setprio(0);
        cur = (cur == 2) ? 0 : cur + 1;
    }

    const int lr4 = (l >> 4) * 4, lc = l & 15;
    if (n0 < 2048) {
        const float sc = (n0 < 1024) ? 0.125f : 1.0f;
        #pragma unroll
        for (int mf = 0; mf < 8; ++mf) {
            #pragma unroll
            for (int nf = 0; nf < 4; ++nf) {
                const int col = n0 + wn * 64 + nf * 16 + lc;
                #pragma unroll
                for (int r = 0; r < 4; ++r) {
                    const int row = m0 + wm * 128 + mf * 16 + lr4 + r;
                    qkvb[(size_t)row * 2048 + col] = f2bf(acc[mf][nf][r] * sc);
                }
            }
        }
    } else {
        #pragma unroll
        for (int mf = 0; mf < 8; ++mf) {
            const int row0 = m0 + wm * 128 + mf * 16 + lr4;   // 4-aligned
            const int b = row0 >> 10, nseq = row0 & 1023;
            #pragma unroll
            for (int nf = 0; nf < 4; ++nf) {
                const int c2 = n0 - 2048 + wn * 64 + nf * 16 + lc;
                const int h = c2 >> 6, d = c2 & 63;
                short4 v4;
                v4.x = f2bf(acc[mf][nf][0]); v4.y = f2bf(acc[mf][nf][1]);
                v4.z = f2bf(acc[mf][nf][2]); v4.w = f2bf(acc[mf][nf][3]);
                *(short4*)&VT[(((size_t)(b * 16 + h) * 64 + d) * 1024) + nseq] = v4;
            }
        }
    }
}

// ------------- bf16 MFMA GEMM, 3-buffer counted vmcnt (proj / FC2) -----
template<int BN, bool BIAS, bool RES, bool GELU_, bool OUTBF16>
__global__ __launch_bounds__(256) void mgemm(
    const short* __restrict__ A, const short* __restrict__ B,
    const float* __restrict__ bias, const float* __restrict__ res,
    void* __restrict__ Cv, int M, int N, int K)
{
    constexpr int MF = (BN == 128) ? 4 : 2;
    __shared__ __align__(16) short As[3][128 * 32];
    __shared__ __align__(16) short Bs[3][BN * 32];
    const int t = threadIdx.x;
    const int w = t >> 6, l = t & 63;

    const int gx = gridDim.x;
    const int nwg = gx * gridDim.y;
    const int lid = blockIdx.y * gx + blockIdx.x;
    const int swzb = (lid & 7) * (nwg >> 3) + (lid >> 3);
    const int bx = swzb % gx, by = swzb / gx;
    const int m0 = by * 128, n0 = bx * BN;

    const int wrow = (BN == 128) ? (w >> 1) * 64 : w * 32;
    const int wcol = (BN == 128) ? (w & 1) * 64 : 0;

    const int sk8 = ((l & 3) ^ ((l >> 3) & 3)) * 8;
    const short* agp0 = A + (size_t)(m0 + w * 32 + (l >> 2)) * K + sk8;
    const short* agp1 = agp0 + (size_t)16 * K;
    const short* bgp0;
    const short* bgp1 = nullptr;
    if (BN == 128) {
        bgp0 = B + (size_t)(n0 + w * 32 + (l >> 2)) * K + sk8;
        bgp1 = bgp0 + (size_t)16 * K;
    } else {
        bgp0 = B + (size_t)(n0 + w * 16 + (l >> 2)) * K + sk8;
    }

    const int fr = l & 15;
    const int rsw = (fr >> 1) & 3;
    int aoff[MF], boff[4];
    #pragma unroll
    for (int m = 0; m < MF; ++m) aoff[m] = (wrow + m * 16 + fr) * 32 + ((l >> 4) ^ rsw) * 8;
    #pragma unroll
    for (int n = 0; n < 4; ++n)  boff[n] = (wcol + n * 16 + fr) * 32 + ((l >> 4) ^ rsw) * 8;

    auto stage = [&](int k0, int buf) {
        short* ldsA = &As[buf][w * 1024];
        gload_lds16(agp0 + k0, ldsA);
        gload_lds16(agp1 + k0, ldsA + 512);
        if (BN == 128) {
            short* ldsB = &Bs[buf][w * 1024];
            gload_lds16(bgp0 + k0, ldsB);
            gload_lds16(bgp1 + k0, ldsB + 512);
        } else {
            gload_lds16(bgp0 + k0, &Bs[buf][w * 512]);
        }
    };

    f32x4 acc[MF][4] = {};
    const int T = K / 32;
    stage(0, 0);
    stage(32, 1);
    int cur = 0;
    for (int kt = 0; kt < T; ++kt) {
        if (kt < T - 1) {
            if constexpr (BN == 128) asm volatile("s_waitcnt vmcnt(4)" ::: "memory");
            else                     asm volatile("s_waitcnt vmcnt(3)" ::: "memory");
        } else {
            asm volatile("s_waitcnt vmcnt(0)" ::: "memory");
        }
        __builtin_amdgcn_sched_barrier(0);
        __builtin_amdgcn_s_barrier();
        __builtin_amdgcn_sched_barrier(0);
        if (kt + 2 < T) {
            int nb = kt + 2; nb -= (nb >= 3) ? ((nb / 3) * 3) : 0;
            stage((kt + 2) * 32, nb);
        }
        bf16x8 af[MF], bfr[4];
        #pragma unroll
        for (int m = 0; m < MF; ++m) af[m]  = *(const bf16x8*)&As[cur][aoff[m]];
        #pragma unroll
        for (int n = 0; n < 4; ++n)  bfr[n] = *(const bf16x8*)&Bs[cur][boff[n]];
        #pragma unroll
        for (int m = 0; m < MF; ++m)
            #pragma unroll
            for (int n = 0; n < 4; ++n)
                acc[m][n] = __builtin_amdgcn_mfma_f32_16x16x32_bf16(af[m], bfr[n], acc[m][n], 0, 0, 0);
        cur = (cur == 2) ? 0 : cur + 1;
    }

    const int lr4 = (l >> 4) * 4, lc = l & 15;
    #pragma unroll
    for (int m = 0; m < MF; ++m) {
        #pragma unroll
        for (int n = 0; n < 4; ++n) {
            const int col = n0 + wcol + n * 16 + lc;
            const float bv = BIAS ? bias[col] : 0.0f;
            #pragma unroll
            for (int r = 0; r < 4; ++r) {
                const int row = m0 + wrow + m * 16 + lr4 + r;
                float v = acc[m][n][r] + bv;
                if (GELU_) v = gelu_exact(v);
                if (RES)   v += res[(size_t)row * N + col];
                if (OUTBF16) ((short*)Cv)[(size_t)row * N + col] = f2bf(v);
                else         ((float*)Cv)[(size_t)row * N + col] = v;
            }
        }
    }
}

// ---------------- MFMA flash attention (swapped QK^T, per-lane softmax) ----------------
__global__ __launch_bounds__(256) void fattn(const short* __restrict__ qkvb,
                                             const short* __restrict__ VT,
                                             short* __restrict__ o) {
    const int lid = blockIdx.y * gridDim.x + blockIdx.x;   // grid (16,64)
    const int bh = ((lid >> 7) << 3) | (lid & 7);
    const int q0 = ((lid >> 3) & 15) * 64;
    const int b = bh >> 4, h = bh & 15;
    const int t = threadIdx.x, w = t >> 6, l = t & 63;

    __shared__ __align__(16) short Ks[2][64 * 64];
    __shared__ __align__(16) short Vs[2][64 * 64];
    __shared__ __align__(16) short Ps[4][1024];

    const size_t qrow = (size_t)(b * SEQ + q0 + w * 16 + (l & 15)) * 2048 + h * 64;
    bf16x8 qf[2];
    qf[0] = *(const bf16x8*)&qkvb[qrow + (l >> 4) * 8];
    qf[1] = *(const bf16x8*)&qkvb[qrow + 32 + (l >> 4) * 8];

    const int srow = l >> 3;
    const int sc16 = (l & 7) ^ (srow & 7);
    const short* Kg = qkvb + 1024 + h * 64;
    const short* Vg = VT + (size_t)bh * 64 * 1024;

    f32x4 acc[4] = {};
    float mr = -1e30f, lr = 0.0f;
    const int q = l & 15;
    const int g4 = (l >> 4) & 3;

    auto stage = [&](int kt, int buf) {
        const int kv0 = kt * 64;
        #pragma unroll
        for (int i = 0; i < 2; ++i) {
            const int r0 = w * 16 + i * 8;
            gload_lds16(Kg + (size_t)(b * SEQ + kv0 + r0 + srow) * 2048 + sc16 * 8,
                        &Ks[buf][r0 * 64]);
            gload_lds16(Vg + (size_t)(r0 + srow) * 1024 + kv0 + sc16 * 8,
                        &Vs[buf][r0 * 64]);
        }
    };

    stage(0, 0);
    for (int kt = 0; kt < 16; ++kt) {
        const int cur = kt & 1;
        __syncthreads();
        if (kt + 1 < 16) stage(kt + 1, cur ^ 1);

        f32x4 sacc[4];
        #pragma unroll
        for (int nt = 0; nt < 4; ++nt) {
            f32x4 z = {};
            #pragma unroll
            for (int ks = 0; ks < 2; ++ks) {
                const int row = nt * 16 + (l & 15);
                const int c16 = (ks * 4 + (l >> 4)) ^ (row & 7);
                const bf16x8 kf = *(const bf16x8*)&Ks[cur][row * 64 + c16 * 8];
                z = __builtin_amdgcn_mfma_f32_16x16x32_bf16(kf, qf[ks], z, 0, 0, 0);
            }
            sacc[nt] = z;
        }
        float tm = sacc[0][0];
        #pragma unroll
        for (int nt = 0; nt < 4; ++nt)
            #pragma unroll
            for (int r = 0; r < 4; ++r) tm = fmaxf(tm, sacc[nt][r]);
        tm = fmaxf(tm, __shfl_xor(tm, 16));
        tm = fmaxf(tm, __shfl_xor(tm, 32));
        const bool norescale = __all(tm <= mr + 8.0f);
        float fac = 1.0f;
        if (!norescale) {
            const float nm = fmaxf(mr, tm);
            fac = __expf(mr - nm);
            mr = nm;
        }
        float p[4][4];
        float ts = 0.0f;
        #pragma unroll
        for (int nt = 0; nt < 4; ++nt)
            #pragma unroll
            for (int r = 0; r < 4; ++r) {
                p[nt][r] = __expf(sacc[nt][r] - mr);
                ts += p[nt][r];
            }
        ts += __shfl_xor(ts, 16);
        ts += __shfl_xor(ts, 32);
        lr = lr * fac + ts;
        if (!norescale) {
            float facv[4];
            #pragma unroll
            for (int r = 0; r < 4; ++r)
                facv[r] = __shfl(fac, (l & 48) + g4 * 4 + r);
            #pragma unroll
            for (int nt2 = 0; nt2 < 4; ++nt2)
                #pragma unroll
                for (int r = 0; r < 4; ++r)
                    acc[nt2][r] *= facv[r];
        }
        #pragma unroll
        for (int nt = 0; nt < 4; ++nt) {
            uint32_t lo, hi;
            asm("v_cvt_pk_bf16_f32 %0, %1, %2" : "=v"(lo) : "v"(p[nt][0]), "v"(p[nt][1]));
            asm("v_cvt_pk_bf16_f32 %0, %1, %2" : "=v"(hi) : "v"(p[nt][2]), "v"(p[nt][3]));
            const int kvb = nt * 16 + g4 * 4;
            const int addr = q * 64 + (((kvb >> 3) ^ (q & 7)) << 3) + (kvb & 7);
            *(uint2*)&Ps[w][addr] = make_uint2(lo, hi);
        }
        asm volatile("s_waitcnt lgkmcnt(0)" ::: "memory");  // own-wave P stores only
        #pragma unroll
        for (int ks = 0; ks < 2; ++ks) {
            const int ql = l & 15;
            const bf16x8 pa = *(const bf16x8*)&Ps[w][ql * 64 + ((ks * 32 + (l >> 4) * 8) ^ ((ql & 7) << 3))];
            #pragma unroll
            for (int nt2 = 0; nt2 < 4; ++nt2) {
                const int row = nt2 * 16 + (l & 15);
                const int c16 = (ks * 4 + (l >> 4)) ^ (row & 7);
                const bf16x8 vf = *(const bf16x8*)&Vs[cur][row * 64 + c16 * 8];
                acc[nt2] = __builtin_amdgcn_mfma_f32_16x16x32_bf16(pa, vf, acc[nt2], 0, 0, 0);
            }
        }
    }
    float rcpl = 1.0f / lr;
    #pragma unroll
    for (int r = 0; r < 4; ++r) {
        const float rcp = __shfl(rcpl, (l & 48) + g4 * 4 + r);
        const int qq = q0 + w * 16 + g4 * 4 + r;
        #pragma unroll
        for (int nt2 = 0; nt2 < 4; ++nt2) {
            const int d = nt2 * 16 + (l & 15);
            o[(size_t)(b * SEQ + qq) * CDIM + h * 64 + d] = f2bf(acc[nt2][r] * rcp);
        }
    }
}

extern "C" void kernel_launch(void* const* d_in, const int* in_sizes, int n_in,
                              void* d_out, int out_size, void* d_ws, size_t ws_size,
                              hipStream_t stream) {
    const float* x      = (const float*)d_in[0];
    const float* ln1_w  = (const float*)d_in[1];
    const float* ln1_b  = (const float*)d_in[2];
    const float* qkv_w  = (const float*)d_in[3];
    const float* proj_w = (const float*)d_in[4];
    const float* proj_b = (const float*)d_in[5];
    const float* ln2_w  = (const float*)d_in[6];
    const float* ln2_b  = (const float*)d_in[7];
    const float* fc1_w  = (const float*)d_in[8];
    const float* fc1_b  = (const float*)d_in[9];
    const float* fc2_w  = (const float*)d_in[10];
    const float* fc2_b  = (const float*)d_in[11];
    float* out = (float*)d_out;

    short* ws16  = (short*)d_ws;
    short* wqkv  = ws16;
    short* wproj = ws16 + 3145728;
    short* wfc1  = ws16 + 4194304;
    short* wfc2  = ws16 + 8388608;
    char*  wsb   = (char*)d_ws;
    short* qkvb  = (short*)(wsb + (size_t)24 * 1024 * 1024);
    short* VT    = (short*)(wsb + (size_t)40 * 1024 * 1024);
    short* mlp1  = (short*)(wsb + (size_t)24 * 1024 * 1024);
    short* hbuf  = (short*)(wsb + (size_t)72 * 1024 * 1024);

    cvt_bf16_kernel<<<1536, 256, 0, stream>>>(qkv_w, wqkv);
    cvt_bf16_kernel<<< 512, 256, 0, stream>>>(proj_w, wproj);
    cvt_bf16_kernel<<<2048, 256, 0, stream>>>(fc1_w, wfc1);
    cvt_bf16_kernel<<<2048, 256, 0, stream>>>(fc2_w, wfc2);

    ln_kernel<<<MROWS, 256, 0, stream>>>(x, ln1_w, ln1_b, hbuf);
    // QKV: 256x256/BK32 3-buf, grid 12x16 = 192 blocks
    qkv8k<<<dim3(12, 16), 512, 0, stream>>>(hbuf, wqkv, qkvb, VT, 1024);
    fattn<<<dim3(16, 64), 256, 0, stream>>>(qkvb, VT, hbuf);
    // proj: BN=128, grid 8x32 = 256 blocks
    mgemm<128,true,true,false,false><<<dim3(8, 32), 256, 0, stream>>>(
        hbuf, wproj, proj_b, x, out, MROWS, 1024, 1024);
    ln_kernel<<<MROWS, 256, 0, stream>>>(out, ln2_w, ln2_b, hbuf);
    // FC1: 256x256/BK32 3-buf, grid 16x16 = 256 blocks
    gemm8k<true,false,true,true><<<dim3(16, 16), 512, 0, stream>>>(
        hbuf, wfc1, fc1_b, nullptr, mlp1, MROWS, 4096, 1024);
    // FC2: BN=128, grid 8x32 = 256 blocks
    mgemm<128,true,true,false,false><<<dim3(8, 32), 256, 0, stream>>>(
        mlp1, wfc2, fc2_b, out, out, MROWS, 1024, 4096);
}

// Round 12
// 223.448 us; speedup vs baseline: 9.7357x; 1.0090x over previous
//
#include <hip/hip_runtime.h>
#include <hip/hip_bf16.h>
#include <math.h>
#include <stdint.h>

#define SEQ 1024
#define CDIM 1024
#define NHEAD 16
#define HIDDEN 4096
#define BATCH 4
#define MROWS (BATCH*SEQ)   // 4096

using bf16x8 = __attribute__((ext_vector_type(8))) short;
using f32x4  = __attribute__((ext_vector_type(4))) float;

__device__ __forceinline__ short f2bf(float f) {
    union { float f; uint32_t u; } c; c.f = f;
    const uint32_t u = c.u + 0x7FFFu + ((c.u >> 16) & 1u);
    return (short)(u >> 16);
}

__device__ __forceinline__ float gelu_exact(float v) {
    return 0.5f * v * (1.0f + erff(v * 0.70710678118654752440f));
}

__device__ __forceinline__ void gload_lds16(const short* g, short* lds) {
    __builtin_amdgcn_global_load_lds(
        (const __attribute__((address_space(1))) void*)(uintptr_t)g,
        (__attribute__((address_space(3))) void*)(uintptr_t)lds,
        16, 0, 0);
}

// ---------------- merged weight fp32 -> bf16 conversion ----------------
__global__ void cvt_all_kernel(const float* __restrict__ qkv_w, const float* __restrict__ proj_w,
                               const float* __restrict__ fc1_w, const float* __restrict__ fc2_w,
                               short* __restrict__ wq, short* __restrict__ wp,
                               short* __restrict__ w1, short* __restrict__ w2) {
    const int blk = blockIdx.x;          // 6144 blocks x 256 thr x 8 elems
    const float* in; short* out; size_t base;
    if (blk < 1536)      { in = qkv_w;  out = wq; base = (size_t)blk * 2048; }
    else if (blk < 2048) { in = proj_w; out = wp; base = (size_t)(blk - 1536) * 2048; }
    else if (blk < 4096) { in = fc1_w;  out = w1; base = (size_t)(blk - 2048) * 2048; }
    else                 { in = fc2_w;  out = w2; base = (size_t)(blk - 4096) * 2048; }
    const size_t i = base + (size_t)threadIdx.x * 8;
    const float4 a = *(const float4*)(in + i);
    const float4 b = *(const float4*)(in + i + 4);
    bf16x8 s;
    s[0] = f2bf(a.x); s[1] = f2bf(a.y); s[2] = f2bf(a.z); s[3] = f2bf(a.w);
    s[4] = f2bf(b.x); s[5] = f2bf(b.y); s[6] = f2bf(b.z); s[7] = f2bf(b.w);
    *(bf16x8*)(out + i) = s;
}

// ---------------- LayerNorm ----------------
__global__ void ln_kernel(const float* __restrict__ x, const float* __restrict__ w,
                          const float* __restrict__ b, short* __restrict__ out) {
    const int row = blockIdx.x;
    const int t = threadIdx.x;
    const float4* xr = (const float4*)(x + (size_t)row * CDIM);
    float4 v = xr[t];
    float s  = v.x + v.y + v.z + v.w;
    float sq = v.x*v.x + v.y*v.y + v.z*v.z + v.w*v.w;
    #pragma unroll
    for (int off = 32; off; off >>= 1) {
        s  += __shfl_down(s, off);
        sq += __shfl_down(sq, off);
    }
    __shared__ float ss[4], ssq[4];
    const int wid = t >> 6, lane = t & 63;
    if (lane == 0) { ss[wid] = s; ssq[wid] = sq; }
    __syncthreads();
    s  = ss[0] + ss[1] + ss[2] + ss[3];
    sq = ssq[0] + ssq[1] + ssq[2] + ssq[3];
    const float mu  = s * (1.0f / CDIM);
    const float var = sq * (1.0f / CDIM) - mu * mu;
    const float rs  = rsqrtf(var + 1e-5f);
    const float4 wv = ((const float4*)w)[t];
    const float4 bv = ((const float4*)b)[t];
    short4 o;
    o.x = f2bf((v.x - mu) * rs * wv.x + bv.x);
    o.y = f2bf((v.y - mu) * rs * wv.y + bv.y);
    o.z = f2bf((v.z - mu) * rs * wv.z + bv.z);
    o.w = f2bf((v.w - mu) * rs * wv.w + bv.w);
    *(short4*)(out + (size_t)row * CDIM + t * 4) = o;
}

// ====== 256x256 MFMA GEMM — m201-style slice-ring schedule (T2+T3+T4+T5) ======
// 512 thr / 8 waves (2Mx4N), wave tile 128x64. LDS: A/B rings of 4 K32-slices
// (128KB). Per slice, 2 phases x 16 MFMA: {ds_read subtile; stage 2 loads
// (slice s+3, consumption order); barrier; lgkmcnt(0); setprio1 MFMA setprio0;
// [vmcnt(8) in phase B only]; barrier}. vmcnt NEVER drains in-loop.
// WAR: slot (s+3)&3 freed at end of slice s-1 (lgkm(0) before that barrier).
// Leaves in scope: acc, m0, n0, wm, wn, l, t, w.
#define GEMMT_BODY()                                                           \
    __shared__ __align__(16) short As[4][256 * 32];                            \
    __shared__ __align__(16) short Bs[4][256 * 32];                            \
    const int t = threadIdx.x;                                                 \
    const int w = t >> 6, l = t & 63;                                          \
    const int wm = w >> 2, wn = w & 3;                                         \
    const int gx = gridDim.x;                                                  \
    const int nwg = gx * gridDim.y;                                            \
    const int lid = blockIdx.y * gx + blockIdx.x;                              \
    const int swz = (lid & 7) * (nwg >> 3) + (lid >> 3);                       \
    const int bx = swz % gx, by = swz / gx;                                    \
    const int m0 = by * 256, n0 = bx * 256;                                    \
    const int trow = l >> 2;                                                   \
    const int k8s = ((l & 3) ^ ((l >> 3) & 3)) * 8;                            \
    const short* Ag = A + (size_t)(m0 + trow) * K + k8s;                       \
    const short* Bg = B + (size_t)(n0 + trow) * K + k8s;                       \
    const int fr = l & 15, g = l >> 4;                                         \
    const int ak = (g ^ ((fr >> 1) & 3)) * 8;                                  \
    int aoff[8], boff[4];                                                      \
    _Pragma("unroll")                                                          \
    for (int mf = 0; mf < 8; ++mf) aoff[mf] = (wm * 128 + mf * 16 + fr) * 32 + ak; \
    _Pragma("unroll")                                                          \
    for (int nf = 0; nf < 4; ++nf) boff[nf] = (wn * 64 + nf * 16 + fr) * 32 + ak;  \
    f32x4 acc[8][4] = {};                                                      \
    const int S = K / 32;                                                      \
    _Pragma("unroll")                                                          \
    for (int s = 0; s < 3; ++s) {                                              \
        _Pragma("unroll")                                                      \
        for (int part = 0; part < 2; ++part) {                                 \
            const int j = w + part * 8;                                        \
            gload_lds16(Ag + (size_t)(j * 16) * K + (size_t)s * 32, &As[s][j * 512]); \
            gload_lds16(Bg + (size_t)(j * 16) * K + (size_t)s * 32, &Bs[s][j * 512]); \
        }                                                                      \
    }                                                                          \
    asm volatile("s_waitcnt vmcnt(8)" ::: "memory");                           \
    __builtin_amdgcn_s_barrier();                                              \
    for (int s = 0; s < S; ++s) {                                              \
        const short* As_s = &As[s & 3][0];                                     \
        const short* Bs_s = &Bs[s & 3][0];                                     \
        bf16x8 bfr[4], af[4];                                                  \
        /* phase A */                                                          \
        _Pragma("unroll")                                                      \
        for (int nf = 0; nf < 4; ++nf) bfr[nf] = *(const bf16x8*)&Bs_s[boff[nf]]; \
        _Pragma("unroll")                                                      \
        for (int mf = 0; mf < 4; ++mf) af[mf] = *(const bf16x8*)&As_s[aoff[mf]];  \
        if (s + 3 < S) {                                                       \
            const int sn = s + 3, slot = sn & 3, j = w;                        \
            gload_lds16(Ag + (size_t)(j * 16) * K + (size_t)sn * 32, &As[slot][j * 512]); \
            gload_lds16(Bg + (size_t)(j * 16) * K + (size_t)sn * 32, &Bs[slot][j * 512]); \
        }                                                                      \
        __builtin_amdgcn_s_barrier();                                          \
        asm volatile("s_waitcnt lgkmcnt(0)" ::: "memory");                     \
        __builtin_amdgcn_sched_barrier(0);                                     \
        __builtin_amdgcn_s_setprio(1);                                         \
        _Pragma("unroll")                                                      \
        for (int mf = 0; mf < 4; ++mf)                                         \
            _Pragma("unroll")                                                  \
            for (int nf = 0; nf < 4; ++nf)                                     \
                acc[mf][nf] = __builtin_amdgcn_mfma_f32_16x16x32_bf16(af[mf], bfr[nf], acc[mf][nf], 0, 0, 0); \
        __builtin_amdgcn_s_setprio(0);                                         \
        __builtin_amdgcn_sched_barrier(0);                                     \
        __builtin_amdgcn_s_barrier();                                          \
        /* phase B */                                                          \
        _Pragma("unroll")                                                      \
        for (int mf = 0; mf < 4; ++mf) af[mf] = *(const bf16x8*)&As_s[aoff[4 + mf]]; \
        if (s + 3 < S) {                                                       \
            const int sn = s + 3, slot = sn & 3, j = w + 8;                    \
            gload_lds16(Ag + (size_t)(j * 16) * K + (size_t)sn * 32, &As[slot][j * 512]); \
            gload_lds16(Bg + (size_t)(j * 16) * K + (size_t)sn * 32, &Bs[slot][j * 512]); \
        }                                                                      \
        __builtin_amdgcn_s_barrier();                                          \
        asm volatile("s_waitcnt lgkmcnt(0)" ::: "memory");                     \
        __builtin_amdgcn_sched_barrier(0);                                     \
        __builtin_amdgcn_s_setprio(1);                                         \
        _Pragma("unroll")                                                      \
        for (int mf = 0; mf < 4; ++mf)                                         \
            _Pragma("unroll")                                                  \
            for (int nf = 0; nf < 4; ++nf)                                     \
                acc[4 + mf][nf] = __builtin_amdgcn_mfma_f32_16x16x32_bf16(af[mf], bfr[nf], acc[4 + mf][nf], 0, 0, 0); \
        __builtin_amdgcn_s_setprio(0);                                         \
        if (s < S - 3)       asm volatile("s_waitcnt vmcnt(8)" ::: "memory");  \
        else if (s == S - 3) asm volatile("s_waitcnt vmcnt(4)" ::: "memory");  \
        else if (s == S - 2) asm volatile("s_waitcnt vmcnt(0)" ::: "memory");  \
        __builtin_amdgcn_sched_barrier(0);                                     \
        __builtin_amdgcn_s_barrier();                                          \
    }

template<bool BIAS, bool RES, bool GELU_, bool OUTBF16>
__global__ __launch_bounds__(512) void gemmT(
    const short* __restrict__ A, const short* __restrict__ B,
    const float* __restrict__ bias, const float* __restrict__ res,
    void* __restrict__ Cv, int M, int N, int K)
{
    GEMMT_BODY()
    const int lr4 = (l >> 4) * 4, lc = l & 15;
    #pragma unroll
    for (int mf = 0; mf < 8; ++mf) {
        #pragma unroll
        for (int nf = 0; nf < 4; ++nf) {
            const int col = n0 + wn * 64 + nf * 16 + lc;
            const float bv = BIAS ? bias[col] : 0.0f;
            #pragma unroll
            for (int r = 0; r < 4; ++r) {
                const int row = m0 + wm * 128 + mf * 16 + lr4 + r;
                float v = acc[mf][nf][r] + bv;
                if (GELU_) v = gelu_exact(v);
                if (RES)   v += res[(size_t)row * N + col];
                if (OUTBF16) ((short*)Cv)[(size_t)row * N + col] = f2bf(v);
                else         ((float*)Cv)[(size_t)row * N + col] = v;
            }
        }
    }
}

__global__ __launch_bounds__(512) void qkvT(
    const short* __restrict__ A, const short* __restrict__ B,
    short* __restrict__ qkvb, short* __restrict__ VT, int K)
{
    GEMMT_BODY()
    const int lr4 = (l >> 4) * 4, lc = l & 15;
    if (n0 < 2048) {
        const float sc = (n0 < 1024) ? 0.125f : 1.0f;
        #pragma unroll
        for (int mf = 0; mf < 8; ++mf) {
            #pragma unroll
            for (int nf = 0; nf < 4; ++nf) {
                const int col = n0 + wn * 64 + nf * 16 + lc;
                #pragma unroll
                for (int r = 0; r < 4; ++r) {
                    const int row = m0 + wm * 128 + mf * 16 + lr4 + r;
                    qkvb[(size_t)row * 2048 + col] = f2bf(acc[mf][nf][r] * sc);
                }
            }
        }
    } else {
        #pragma unroll
        for (int mf = 0; mf < 8; ++mf) {
            const int row0 = m0 + wm * 128 + mf * 16 + lr4;
            const int b = row0 >> 10, nseq = row0 & 1023;
            #pragma unroll
            for (int nf = 0; nf < 4; ++nf) {
                const int c2 = n0 - 2048 + wn * 64 + nf * 16 + lc;
                const int h = c2 >> 6, d = c2 & 63;
                short4 v4;
                v4.x = f2bf(acc[mf][nf][0]); v4.y = f2bf(acc[mf][nf][1]);
                v4.z = f2bf(acc[mf][nf][2]); v4.w = f2bf(acc[mf][nf][3]);
                *(short4*)&VT[(((size_t)(b * 16 + h) * 64 + d) * 1024) + nseq] = v4;
            }
        }
    }
}

// ------------- bf16 MFMA GEMM, 3-buffer counted vmcnt (proj / FC2) -----
template<int BN, bool BIAS, bool RES, bool GELU_, bool OUTBF16>
__global__ __launch_bounds__(256) void mgemm(
    const short* __restrict__ A, const short* __restrict__ B,
    const float* __restrict__ bias, const float* __restrict__ res,
    void* __restrict__ Cv, int M, int N, int K)
{
    constexpr int MF = (BN == 128) ? 4 : 2;
    __shared__ __align__(16) short As[3][128 * 32];
    __shared__ __align__(16) short Bs[3][BN * 32];
    const int t = threadIdx.x;
    const int w = t >> 6, l = t & 63;

    const int gx = gridDim.x;
    const int nwg = gx * gridDim.y;
    const int lid = blockIdx.y * gx + blockIdx.x;
    const int swzb = (lid & 7) * (nwg >> 3) + (lid >> 3);
    const int bx = swzb % gx, by = swzb / gx;
    const int m0 = by * 128, n0 = bx * BN;

    const int wrow = (BN == 128) ? (w >> 1) * 64 : w * 32;
    const int wcol = (BN == 128) ? (w & 1) * 64 : 0;

    const int sk8 = ((l & 3) ^ ((l >> 3) & 3)) * 8;
    const short* agp0 = A + (size_t)(m0 + w * 32 + (l >> 2)) * K + sk8;
    const short* agp1 = agp0 + (size_t)16 * K;
    const short* bgp0;
    const short* bgp1 = nullptr;
    if (BN == 128) {
        bgp0 = B + (size_t)(n0 + w * 32 + (l >> 2)) * K + sk8;
        bgp1 = bgp0 + (size_t)16 * K;
    } else {
        bgp0 = B + (size_t)(n0 + w * 16 + (l >> 2)) * K + sk8;
    }

    const int fr = l & 15;
    const int rsw = (fr >> 1) & 3;
    int aoff[MF], boff[4];
    #pragma unroll
    for (int m = 0; m < MF; ++m) aoff[m] = (wrow + m * 16 + fr) * 32 + ((l >> 4) ^ rsw) * 8;
    #pragma unroll
    for (int n = 0; n < 4; ++n)  boff[n] = (wcol + n * 16 + fr) * 32 + ((l >> 4) ^ rsw) * 8;

    auto stage = [&](int k0, int buf) {
        short* ldsA = &As[buf][w * 1024];
        gload_lds16(agp0 + k0, ldsA);
        gload_lds16(agp1 + k0, ldsA + 512);
        if (BN == 128) {
            short* ldsB = &Bs[buf][w * 1024];
            gload_lds16(bgp0 + k0, ldsB);
            gload_lds16(bgp1 + k0, ldsB + 512);
        } else {
            gload_lds16(bgp0 + k0, &Bs[buf][w * 512]);
        }
    };

    f32x4 acc[MF][4] = {};
    const int T = K / 32;
    stage(0, 0);
    stage(32, 1);
    int cur = 0;
    for (int kt = 0; kt < T; ++kt) {
        if (kt < T - 1) {
            if constexpr (BN == 128) asm volatile("s_waitcnt vmcnt(4)" ::: "memory");
            else                     asm volatile("s_waitcnt vmcnt(3)" ::: "memory");
        } else {
            asm volatile("s_waitcnt vmcnt(0)" ::: "memory");
        }
        __builtin_amdgcn_sched_barrier(0);
        __builtin_amdgcn_s_barrier();
        __builtin_amdgcn_sched_barrier(0);
        if (kt + 2 < T) {
            int nb = kt + 2; nb -= (nb >= 3) ? ((nb / 3) * 3) : 0;
            stage((kt + 2) * 32, nb);
        }
        bf16x8 af[MF], bfr[4];
        #pragma unroll
        for (int m = 0; m < MF; ++m) af[m]  = *(const bf16x8*)&As[cur][aoff[m]];
        #pragma unroll
        for (int n = 0; n < 4; ++n)  bfr[n] = *(const bf16x8*)&Bs[cur][boff[n]];
        #pragma unroll
        for (int m = 0; m < MF; ++m)
            #pragma unroll
            for (int n = 0; n < 4; ++n)
                acc[m][n] = __builtin_amdgcn_mfma_f32_16x16x32_bf16(af[m], bfr[n], acc[m][n], 0, 0, 0);
        cur = (cur == 2) ? 0 : cur + 1;
    }

    const int lr4 = (l >> 4) * 4, lc = l & 15;
    #pragma unroll
    for (int m = 0; m < MF; ++m) {
        #pragma unroll
        for (int n = 0; n < 4; ++n) {
            const int col = n0 + wcol + n * 16 + lc;
            const float bv = BIAS ? bias[col] : 0.0f;
            #pragma unroll
            for (int r = 0; r < 4; ++r) {
                const int row = m0 + wrow + m * 16 + lr4 + r;
                float v = acc[m][n][r] + bv;
                if (GELU_) v = gelu_exact(v);
                if (RES)   v += res[(size_t)row * N + col];
                if (OUTBF16) ((short*)Cv)[(size_t)row * N + col] = f2bf(v);
                else         ((float*)Cv)[(size_t)row * N + col] = v;
            }
        }
    }
}

// ---------------- MFMA flash attention (swapped QK^T, per-lane softmax) ----------------
__global__ __launch_bounds__(256) void fattn(const short* __restrict__ qkvb,
                                             const short* __restrict__ VT,
                                             short* __restrict__ o) {
    const int lid = blockIdx.y * gridDim.x + blockIdx.x;   // grid (16,64)
    const int bh = ((lid >> 7) << 3) | (lid & 7);
    const int q0 = ((lid >> 3) & 15) * 64;
    const int b = bh >> 4, h = bh & 15;
    const int t = threadIdx.x, w = t >> 6, l = t & 63;

    __shared__ __align__(16) short Ks[2][64 * 64];
    __shared__ __align__(16) short Vs[2][64 * 64];
    __shared__ __align__(16) short Ps[4][1024];

    const size_t qrow = (size_t)(b * SEQ + q0 + w * 16 + (l & 15)) * 2048 + h * 64;
    bf16x8 qf[2];
    qf[0] = *(const bf16x8*)&qkvb[qrow + (l >> 4) * 8];
    qf[1] = *(const bf16x8*)&qkvb[qrow + 32 + (l >> 4) * 8];

    const int srow = l >> 3;
    const int sc16 = (l & 7) ^ (srow & 7);
    const short* Kg = qkvb + 1024 + h * 64;
    const short* Vg = VT + (size_t)bh * 64 * 1024;

    f32x4 acc[4] = {};
    float mr = -1e30f, lr = 0.0f;
    const int q = l & 15;
    const int g4 = (l >> 4) & 3;

    auto stage = [&](int kt, int buf) {
        const int kv0 = kt * 64;
        #pragma unroll
        for (int i = 0; i < 2; ++i) {
            const int r0 = w * 16 + i * 8;
            gload_lds16(Kg + (size_t)(b * SEQ + kv0 + r0 + srow) * 2048 + sc16 * 8,
                        &Ks[buf][r0 * 64]);
            gload_lds16(Vg + (size_t)(r0 + srow) * 1024 + kv0 + sc16 * 8,
                        &Vs[buf][r0 * 64]);
        }
    };

    stage(0, 0);
    for (int kt = 0; kt < 16; ++kt) {
        const int cur = kt & 1;
        __syncthreads();
        if (kt + 1 < 16) stage(kt + 1, cur ^ 1);

        f32x4 sacc[4];
        #pragma unroll
        for (int nt = 0; nt < 4; ++nt) {
            f32x4 z = {};
            #pragma unroll
            for (int ks = 0; ks < 2; ++ks) {
                const int row = nt * 16 + (l & 15);
                const int c16 = (ks * 4 + (l >> 4)) ^ (row & 7);
                const bf16x8 kf = *(const bf16x8*)&Ks[cur][row * 64 + c16 * 8];
                z = __builtin_amdgcn_mfma_f32_16x16x32_bf16(kf, qf[ks], z, 0, 0, 0);
            }
            sacc[nt] = z;
        }
        float tm = sacc[0][0];
        #pragma unroll
        for (int nt = 0; nt < 4; ++nt)
            #pragma unroll
            for (int r = 0; r < 4; ++r) tm = fmaxf(tm, sacc[nt][r]);
        tm = fmaxf(tm, __shfl_xor(tm, 16));
        tm = fmaxf(tm, __shfl_xor(tm, 32));
        const bool norescale = __all(tm <= mr + 8.0f);
        float fac = 1.0f;
        if (!norescale) {
            const float nm = fmaxf(mr, tm);
            fac = __expf(mr - nm);
            mr = nm;
        }
        float p[4][4];
        float ts = 0.0f;
        #pragma unroll
        for (int nt = 0; nt < 4; ++nt)
            #pragma unroll
            for (int r = 0; r < 4; ++r) {
                p[nt][r] = __expf(sacc[nt][r] - mr);
                ts += p[nt][r];
            }
        ts += __shfl_xor(ts, 16);
        ts += __shfl_xor(ts, 32);
        lr = lr * fac + ts;
        if (!norescale) {
            float facv[4];
            #pragma unroll
            for (int r = 0; r < 4; ++r)
                facv[r] = __shfl(fac, (l & 48) + g4 * 4 + r);
            #pragma unroll
            for (int nt2 = 0; nt2 < 4; ++nt2)
                #pragma unroll
                for (int r = 0; r < 4; ++r)
                    acc[nt2][r] *= facv[r];
        }
        #pragma unroll
        for (int nt = 0; nt < 4; ++nt) {
            uint32_t lo, hi;
            asm("v_cvt_pk_bf16_f32 %0, %1, %2" : "=v"(lo) : "v"(p[nt][0]), "v"(p[nt][1]));
            asm("v_cvt_pk_bf16_f32 %0, %1, %2" : "=v"(hi) : "v"(p[nt][2]), "v"(p[nt][3]));
            const int kvb = nt * 16 + g4 * 4;
            const int addr = q * 64 + (((kvb >> 3) ^ (q & 7)) << 3) + (kvb & 7);
            *(uint2*)&Ps[w][addr] = make_uint2(lo, hi);
        }
        asm volatile("s_waitcnt lgkmcnt(0)" ::: "memory");
        #pragma unroll
        for (int ks = 0; ks < 2; ++ks) {
            const int ql = l & 15;
            const bf16x8 pa = *(const bf16x8*)&Ps[w][ql * 64 + ((ks * 32 + (l >> 4) * 8) ^ ((ql & 7) << 3))];
            #pragma unroll
            for (int nt2 = 0; nt2 < 4; ++nt2) {
                const int row = nt2 * 16 + (l & 15);
                const int c16 = (ks * 4 + (l >> 4)) ^ (row & 7);
                const bf16x8 vf = *(const bf16x8*)&Vs[cur][row * 64 + c16 * 8];
                acc[nt2] = __builtin_amdgcn_mfma_f32_16x16x32_bf16(pa, vf, acc[nt2], 0, 0, 0);
            }
        }
    }
    float rcpl = 1.0f / lr;
    #pragma unroll
    for (int r = 0; r < 4; ++r) {
        const float rcp = __shfl(rcpl, (l & 48) + g4 * 4 + r);
        const int qq = q0 + w * 16 + g4 * 4 + r;
        #pragma unroll
        for (int nt2 = 0; nt2 < 4; ++nt2) {
            const int d = nt2 * 16 + (l & 15);
            o[(size_t)(b * SEQ + qq) * CDIM + h * 64 + d] = f2bf(acc[nt2][r] * rcp);
        }
    }
}

extern "C" void kernel_launch(void* const* d_in, const int* in_sizes, int n_in,
                              void* d_out, int out_size, void* d_ws, size_t ws_size,
                              hipStream_t stream) {
    const float* x      = (const float*)d_in[0];
    const float* ln1_w  = (const float*)d_in[1];
    const float* ln1_b  = (const float*)d_in[2];
    const float* qkv_w  = (const float*)d_in[3];
    const float* proj_w = (const float*)d_in[4];
    const float* proj_b = (const float*)d_in[5];
    const float* ln2_w  = (const float*)d_in[6];
    const float* ln2_b  = (const float*)d_in[7];
    const float* fc1_w  = (const float*)d_in[8];
    const float* fc1_b  = (const float*)d_in[9];
    const float* fc2_w  = (const float*)d_in[10];
    const float* fc2_b  = (const float*)d_in[11];
    float* out = (float*)d_out;

    short* ws16  = (short*)d_ws;
    short* wqkv  = ws16;
    short* wproj = ws16 + 3145728;
    short* wfc1  = ws16 + 4194304;
    short* wfc2  = ws16 + 8388608;
    char*  wsb   = (char*)d_ws;
    short* qkvb  = (short*)(wsb + (size_t)24 * 1024 * 1024);
    short* VT    = (short*)(wsb + (size_t)40 * 1024 * 1024);
    short* mlp1  = (short*)(wsb + (size_t)24 * 1024 * 1024);
    short* hbuf  = (short*)(wsb + (size_t)72 * 1024 * 1024);

    cvt_all_kernel<<<6144, 256, 0, stream>>>(qkv_w, proj_w, fc1_w, fc2_w,
                                             wqkv, wproj, wfc1, wfc2);

    ln_kernel<<<MROWS, 256, 0, stream>>>(x, ln1_w, ln1_b, hbuf);
    // QKV: slice-ring template, grid 12x16 = 192 blocks
    qkvT<<<dim3(12, 16), 512, 0, stream>>>(hbuf, wqkv, qkvb, VT, 1024);
    fattn<<<dim3(16, 64), 256, 0, stream>>>(qkvb, VT, hbuf);
    // proj: BN=128, grid 8x32 = 256 blocks
    mgemm<128,true,true,false,false><<<dim3(8, 32), 256, 0, stream>>>(
        hbuf, wproj, proj_b, x, out, MROWS, 1024, 1024);
    ln_kernel<<<MROWS, 256, 0, stream>>>(out, ln2_w, ln2_b, hbuf);
    // FC1: slice-ring template, grid 16x16 = 256 blocks
    gemmT<true,false,true,true><<<dim3(16, 16), 512, 0, stream>>>(
        hbuf, wfc1, fc1_b, nullptr, mlp1, MROWS, 4096, 1024);
    // FC2: BN=128, grid 8x32 = 256 blocks
    mgemm<128,true,true,false,false><<<dim3(8, 32), 256, 0, stream>>>(
        mlp1, wfc2, fc2_b, out, out, MROWS, 1024, 4096);
}